// Round 1
// baseline (1217.969 us; speedup 1.0000x reference)
//
#include <hip/hip_runtime.h>
#include <math.h>

namespace {

constexpr int kB = 8;
constexpr int kC = 128;
constexpr int kHin = 112, kWin = 112;
constexpr int kHout = 56, kWout = 56;
constexpr int kN = kHout * kWout;     // 3136
constexpr int kO = 256;
constexpr int kHd = 512;
constexpr int kQd = 16;
constexpr int kR = 32;
constexpr float kEps = 1e-5f;

__device__ __forceinline__ float gelu_exact(float x) {
  return 0.5f * x * (1.0f + erff(x * 0.70710678118654752f));
}

// ---------------- depthwise conv 3x3 stride2 pad1 + per-(b,c) sum/sumsq ----------------
__global__ __launch_bounds__(256) void dwconv_kernel(
    const float* __restrict__ x, const float* __restrict__ w,
    float* __restrict__ h0, float* __restrict__ sums, float* __restrict__ ssqs) {
  int bc = blockIdx.x;                 // b*kC + c
  int c = bc % kC;
  const float* xp = x + (size_t)bc * (kHin * kWin);
  float wr[9];
#pragma unroll
  for (int i = 0; i < 9; ++i) wr[i] = w[c * 9 + i];
  float lsum = 0.f, lssq = 0.f;
  for (int i = threadIdx.x; i < kN; i += 256) {
    int oy = i / kWout, ox = i - oy * kWout;
    int iy0 = 2 * oy - 1, ix0 = 2 * ox - 1;
    float acc = 0.f;
#pragma unroll
    for (int ky = 0; ky < 3; ++ky) {
      int iy = iy0 + ky;
      if (iy < 0 || iy >= kHin) continue;
#pragma unroll
      for (int kx = 0; kx < 3; ++kx) {
        int ix = ix0 + kx;
        if (ix < 0 || ix >= kWin) continue;
        acc += xp[iy * kWin + ix] * wr[ky * 3 + kx];
      }
    }
    h0[(size_t)bc * kN + i] = acc;
    lsum += acc;
    lssq += acc * acc;
  }
  __shared__ float rs[256], rq[256];
  rs[threadIdx.x] = lsum; rq[threadIdx.x] = lssq;
  __syncthreads();
  for (int s = 128; s > 0; s >>= 1) {
    if (threadIdx.x < s) { rs[threadIdx.x] += rs[threadIdx.x + s]; rq[threadIdx.x] += rq[threadIdx.x + s]; }
    __syncthreads();
  }
  if (threadIdx.x == 0) { sums[bc] = rs[0]; ssqs[bc] = rq[0]; }
}

// ---------------- BN1 stats + SE MLP -> per-(b,c) scale/bias ----------------
// grid = kB blocks, 128 threads (one per channel)
__global__ __launch_bounds__(128) void se_kernel(
    const float* __restrict__ sums, const float* __restrict__ ssqs,
    const float* __restrict__ bn1_g, const float* __restrict__ bn1_b,
    const float* __restrict__ se_w1, const float* __restrict__ se_b1,
    const float* __restrict__ se_w2, const float* __restrict__ se_b2,
    float* __restrict__ scale_bc, float* __restrict__ bias_bc) {
  int b = blockIdx.x, c = threadIdx.x;
  __shared__ float sin_[kC], s1[kR], alf[kC], bet[kC];
  float ts = 0.f, tq = 0.f;
  for (int bb = 0; bb < kB; ++bb) { ts += sums[bb * kC + c]; tq += ssqs[bb * kC + c]; }
  float inv = 1.0f / ((float)kB * (float)kN);
  float mean = ts * inv;
  float var = tq * inv - mean * mean;
  float a = bn1_g[c] * rsqrtf(var + kEps);
  float be = bn1_b[c] - mean * a;
  alf[c] = a; bet[c] = be;
  sin_[c] = a * (sums[b * kC + c] * (1.0f / kN)) + be;   // mean over HW of BN'd h
  __syncthreads();
  if (c < kR) {
    float acc = se_b1[c];
    for (int j = 0; j < kC; ++j) acc += se_w1[c * kC + j] * sin_[j];
    s1[c] = fmaxf(acc, 0.f);
  }
  __syncthreads();
  float acc = se_b2[c];
  for (int j = 0; j < kR; ++j) acc += se_w2[c * kR + j] * s1[j];
  float sg = 1.0f / (1.0f + expf(-acc));
  scale_bc[b * kC + c] = alf[c] * sg;
  bias_bc[b * kC + c] = bet[c] * sg;
}

// ---------------- hf = scale_bc * h0 + bias_bc ----------------
__global__ void scale_kernel(const float* __restrict__ h0, const float* __restrict__ sc,
                             const float* __restrict__ bi, float* __restrict__ hf) {
  constexpr int n4 = kN / 4;
  size_t total4 = (size_t)kB * kC * n4;
  for (size_t i = (size_t)blockIdx.x * blockDim.x + threadIdx.x; i < total4;
       i += (size_t)gridDim.x * blockDim.x) {
    int bc = (int)(i / n4);
    float s = sc[bc], t = bi[bc];
    float4 v = reinterpret_cast<const float4*>(h0)[i];
    v.x = s * v.x + t; v.y = s * v.y + t; v.z = s * v.z + t; v.w = s * v.w + t;
    reinterpret_cast<float4*>(hf)[i] = v;
  }
}

// ---------------- generic GEMM: Y[b,m,n] = sum_k W[m,k] * f(X[b,k,n]) + rowbias[m] ----------------
// f(x) = insc[k]*x + inbi[k]  (optionally followed by exact GELU)
template <bool GELU>
__global__ __launch_bounds__(256) void gemm_kernel(
    const float* __restrict__ Wm, const float* __restrict__ X, float* __restrict__ Y,
    const float* __restrict__ rowbias, const float* __restrict__ insc,
    const float* __restrict__ inbi, int M, int K) {
  constexpr int BM = 128, BN = 128, BK = 16, TM = 8, TN = 8;
  int b = blockIdx.z;
  int m0 = blockIdx.y * BM, n0 = blockIdx.x * BN;
  __shared__ float Ws[BK][BM + 4];
  __shared__ float Xs[BK][BN + 4];
  int tid = threadIdx.x;
  int tx = tid % 16, ty = tid / 16;
  float acc[TM][TN] = {};
  const float* Xb = X + (size_t)b * K * kN;
  for (int kk = 0; kk < K; kk += BK) {
    // W tile (transposed into LDS)
#pragma unroll
    for (int l = tid; l < BM * BK / 4; l += 256) {
      int mrow = l >> 2;         // 0..127
      int k4 = l & 3;            // 0..3
      float4 wv = make_float4(0.f, 0.f, 0.f, 0.f);
      if (m0 + mrow < M)
        wv = *reinterpret_cast<const float4*>(&Wm[(size_t)(m0 + mrow) * K + kk + k4 * 4]);
      Ws[k4 * 4 + 0][mrow] = wv.x;
      Ws[k4 * 4 + 1][mrow] = wv.y;
      Ws[k4 * 4 + 2][mrow] = wv.z;
      Ws[k4 * 4 + 3][mrow] = wv.w;
    }
    // X tile
#pragma unroll
    for (int l = tid; l < BK * BN / 4; l += 256) {
      int krow = l >> 5;         // /(BN/4)=32
      int n4 = l & 31;
      int gn = n0 + n4 * 4;
      float4 xv = make_float4(0.f, 0.f, 0.f, 0.f);
      if (gn < kN)
        xv = *reinterpret_cast<const float4*>(&Xb[(size_t)(kk + krow) * kN + gn]);
      if (insc) {
        float s = insc[kk + krow], t = inbi[kk + krow];
        xv.x = s * xv.x + t; xv.y = s * xv.y + t; xv.z = s * xv.z + t; xv.w = s * xv.w + t;
        if (GELU) {
          xv.x = gelu_exact(xv.x); xv.y = gelu_exact(xv.y);
          xv.z = gelu_exact(xv.z); xv.w = gelu_exact(xv.w);
        }
      }
      *reinterpret_cast<float4*>(&Xs[krow][n4 * 4]) = xv;
    }
    __syncthreads();
#pragma unroll
    for (int ki = 0; ki < BK; ++ki) {
      float4 a0 = *reinterpret_cast<const float4*>(&Ws[ki][ty * TM]);
      float4 a1 = *reinterpret_cast<const float4*>(&Ws[ki][ty * TM + 4]);
      float4 b0 = *reinterpret_cast<const float4*>(&Xs[ki][tx * TN]);
      float4 b1 = *reinterpret_cast<const float4*>(&Xs[ki][tx * TN + 4]);
      float av[8] = {a0.x, a0.y, a0.z, a0.w, a1.x, a1.y, a1.z, a1.w};
      float bv[8] = {b0.x, b0.y, b0.z, b0.w, b1.x, b1.y, b1.z, b1.w};
#pragma unroll
      for (int i = 0; i < TM; ++i)
#pragma unroll
        for (int j = 0; j < TN; ++j) acc[i][j] += av[i] * bv[j];
    }
    __syncthreads();
  }
  float* Yb = Y + (size_t)b * M * kN;
#pragma unroll
  for (int i = 0; i < TM; ++i) {
    int m = m0 + ty * TM + i;
    if (m >= M) break;
    float rb = rowbias ? rowbias[m] : 0.f;
#pragma unroll
    for (int j = 0; j < TN; j += 4) {
      int n = n0 + tx * TN + j;
      if (n < kN) {
        float4 o;
        o.x = acc[i][j] + rb; o.y = acc[i][j + 1] + rb;
        o.z = acc[i][j + 2] + rb; o.w = acc[i][j + 3] + rb;
        *reinterpret_cast<float4*>(&Yb[(size_t)m * kN + n]) = o;
      }
    }
  }
}

// ---------------- flash attention: out[b,c,m] = sum_n softmax_n(q_m . k_n) v[c,n] + hf ----------------
__global__ __launch_bounds__(256) void attn_kernel(
    const float* __restrict__ q, const float* __restrict__ k, const float* __restrict__ v,
    const float* __restrict__ hf, float* __restrict__ outp) {
  constexpr int QB = 64, KT = 32;
  int b = blockIdx.y;
  int m0 = blockIdx.x * QB;
  const float* qb = q + (size_t)b * kQd * kN;
  const float* kb = k + (size_t)b * kQd * kN;
  const float* vb = v + (size_t)b * kC * kN;

  __shared__ float qs[QB][kQd + 1];
  __shared__ float ks[KT][kQd + 1];
  __shared__ float vsT[KT][kC + 4];    // [key][channel]
  __shared__ float ps[KT][QB + 4];     // scores -> probs, [key][query]
  __shared__ float rowsc[QB];
  __shared__ float rowl[QB];

  int tid = threadIdx.x;
  for (int l = tid; l < QB * kQd; l += 256) {
    int d = l / QB, i = l % QB;
    qs[i][d] = qb[(size_t)d * kN + m0 + i];
  }
  __syncthreads();

  int qi = tid & 63, sub = tid >> 6;
  float qreg[kQd];
#pragma unroll
  for (int d = 0; d < kQd; ++d) qreg[d] = qs[qi][d];

  float mloc = -1e30f, lloc = 0.f;     // valid for tid < QB (query tid)
  float acc[8][4] = {};                // [c-sub][q-sub]
  int tc = tid % 16, tq = tid / 16;    // c0 = tc*8, q0 = tq*4

  for (int k0 = 0; k0 < kN; k0 += KT) {
    for (int l = tid; l < KT * kQd; l += 256) {
      int d = l / KT, j = l % KT;
      ks[j][d] = kb[(size_t)d * kN + k0 + j];
    }
    for (int l = tid; l < KT * kC; l += 256) {
      int c = l / KT, j = l % KT;
      vsT[j][c] = vb[(size_t)c * kN + k0 + j];
    }
    __syncthreads();
    // scores: thread (qi, sub) computes keys sub*8 .. sub*8+7
#pragma unroll
    for (int jj = 0; jj < 8; ++jj) {
      int j = sub * 8 + jj;
      float s = 0.f;
#pragma unroll
      for (int d = 0; d < kQd; ++d) s += qreg[d] * ks[j][d];
      ps[j][qi] = s;
    }
    __syncthreads();
    // online softmax update, one thread per query
    if (tid < QB) {
      float sc[KT];
      float tmax = -1e30f;
#pragma unroll
      for (int j = 0; j < KT; ++j) { sc[j] = ps[j][tid]; tmax = fmaxf(tmax, sc[j]); }
      float nm = fmaxf(mloc, tmax);
      float scl = __expf(mloc - nm);
      float sum = 0.f;
#pragma unroll
      for (int j = 0; j < KT; ++j) { float p = __expf(sc[j] - nm); ps[j][tid] = p; sum += p; }
      lloc = lloc * scl + sum;
      mloc = nm;
      rowsc[tid] = scl;
    }
    __syncthreads();
    // PV accumulate
    {
      float s4[4];
#pragma unroll
      for (int i = 0; i < 4; ++i) s4[i] = rowsc[tq * 4 + i];
#pragma unroll
      for (int cc = 0; cc < 8; ++cc)
#pragma unroll
        for (int i = 0; i < 4; ++i) acc[cc][i] *= s4[i];
#pragma unroll 4
      for (int j = 0; j < KT; ++j) {
        float4 v0 = *reinterpret_cast<const float4*>(&vsT[j][tc * 8]);
        float4 v1 = *reinterpret_cast<const float4*>(&vsT[j][tc * 8 + 4]);
        float4 pq = *reinterpret_cast<const float4*>(&ps[j][tq * 4]);
        float vv[8] = {v0.x, v0.y, v0.z, v0.w, v1.x, v1.y, v1.z, v1.w};
        float pp[4] = {pq.x, pq.y, pq.z, pq.w};
#pragma unroll
        for (int cc = 0; cc < 8; ++cc)
#pragma unroll
          for (int i = 0; i < 4; ++i) acc[cc][i] += vv[cc] * pp[i];
      }
    }
    __syncthreads();
  }
  if (tid < QB) rowl[tid] = lloc;
  __syncthreads();
  float linv[4];
#pragma unroll
  for (int i = 0; i < 4; ++i) linv[i] = 1.0f / rowl[tq * 4 + i];
  const float* hfb = hf + (size_t)b * kC * kN;
  float* ob = outp + (size_t)b * kC * kN;
#pragma unroll
  for (int cc = 0; cc < 8; ++cc) {
    int c = tc * 8 + cc;
    size_t base = (size_t)c * kN + m0 + tq * 4;
    float4 r = *reinterpret_cast<const float4*>(&hfb[base]);
    float4 o;
    o.x = acc[cc][0] * linv[0] + r.x;
    o.y = acc[cc][1] * linv[1] + r.y;
    o.z = acc[cc][2] * linv[2] + r.z;
    o.w = acc[cc][3] * linv[3] + r.w;
    *reinterpret_cast<float4*>(&ob[base]) = o;
  }
}

// ---------------- per-channel BN stats over [B, Mch, N] -> alpha/beta ----------------
__global__ __launch_bounds__(256) void stats_kernel(
    const float* __restrict__ X, int Mch, const float* __restrict__ g,
    const float* __restrict__ bt, float* __restrict__ alpha, float* __restrict__ beta) {
  int ch = blockIdx.x;
  float s = 0.f, q = 0.f;
  for (int b = 0; b < kB; ++b) {
    const float* p = X + ((size_t)b * Mch + ch) * kN;
    for (int i = threadIdx.x; i < kN; i += 256) {
      float v = p[i];
      s += v; q += v * v;
    }
  }
  __shared__ float rs[256], rq[256];
  rs[threadIdx.x] = s; rq[threadIdx.x] = q;
  __syncthreads();
  for (int st = 128; st > 0; st >>= 1) {
    if (threadIdx.x < st) { rs[threadIdx.x] += rs[threadIdx.x + st]; rq[threadIdx.x] += rq[threadIdx.x + st]; }
    __syncthreads();
  }
  if (threadIdx.x == 0) {
    float inv = 1.0f / ((float)kB * (float)kN);
    float mean = rs[0] * inv;
    float var = rq[0] * inv - mean * mean;
    float a = g[ch] * rsqrtf(var + kEps);
    alpha[ch] = a;
    beta[ch] = bt[ch] - mean * a;
  }
}

// ---------------- final BN apply -> d_out ----------------
__global__ void bnout_kernel(const float* __restrict__ X, const float* __restrict__ alpha,
                             const float* __restrict__ beta, float* __restrict__ out) {
  constexpr int n4 = kN / 4;
  size_t total4 = (size_t)kB * kO * n4;
  for (size_t i = (size_t)blockIdx.x * blockDim.x + threadIdx.x; i < total4;
       i += (size_t)gridDim.x * blockDim.x) {
    int ch = (int)((i / n4) % kO);
    float a = alpha[ch], t = beta[ch];
    float4 v = reinterpret_cast<const float4*>(X)[i];
    v.x = a * v.x + t; v.y = a * v.y + t; v.z = a * v.z + t; v.w = a * v.w + t;
    reinterpret_cast<float4*>(out)[i] = v;
  }
}

}  // namespace

extern "C" void kernel_launch(void* const* d_in, const int* in_sizes, int n_in,
                              void* d_out, int out_size, void* d_ws, size_t ws_size,
                              hipStream_t stream) {
  const float* x     = (const float*)d_in[0];
  const float* dw_w  = (const float*)d_in[1];
  const float* bn1_g = (const float*)d_in[2];
  const float* bn1_b = (const float*)d_in[3];
  const float* se_w1 = (const float*)d_in[4];
  const float* se_b1 = (const float*)d_in[5];
  const float* se_w2 = (const float*)d_in[6];
  const float* se_b2 = (const float*)d_in[7];
  const float* q_w   = (const float*)d_in[8];
  const float* q_b   = (const float*)d_in[9];
  const float* k_w   = (const float*)d_in[10];
  const float* k_b   = (const float*)d_in[11];
  const float* v_w   = (const float*)d_in[12];
  const float* v_b   = (const float*)d_in[13];
  const float* pw_w  = (const float*)d_in[14];
  const float* bn2_g = (const float*)d_in[15];
  const float* bn2_b = (const float*)d_in[16];
  const float* m1_w  = (const float*)d_in[17];
  const float* bn3_g = (const float*)d_in[18];
  const float* bn3_b = (const float*)d_in[19];
  const float* m2_w  = (const float*)d_in[20];
  const float* bn4_g = (const float*)d_in[21];
  const float* bn4_b = (const float*)d_in[22];
  float* out = (float*)d_out;
  float* ws = (float*)d_ws;

  const size_t BCN = (size_t)kB * kC * kN;   // 3,211,264
  const size_t BQN = (size_t)kB * kQd * kN;  // 401,408

  float* h0   = ws;                // [0, BCN)            ; later reused by v
  float* hfb  = ws + BCN;          // [BCN, 2BCN)
  float* att  = ws + 2 * BCN;      // [2BCN, 3BCN)
  float* m1o  = ws + 3 * BCN;      // [3BCN, 7BCN)
  float* qb   = ws + 7 * BCN;      // BQN
  float* kb   = qb + BQN;          // BQN
  float* sm   = kb + BQN;          // small arrays
  float* sums = sm;
  float* ssqs = sm + 1024;
  float* sc_bc = sm + 2048;
  float* bi_bc = sm + 3072;
  float* a2 = sm + 4096; float* b2 = a2 + kO;
  float* a3 = b2 + kO;   float* b3 = a3 + kHd;
  float* a4 = b3 + kHd;  float* b4 = a4 + kO;
  float* vbuf = h0;                // alias: h0 dead after scale_kernel
  float* p    = ws;                // [0, 2BCN): alias over h0+hf, dead after attention
  float* m2o  = ws;                // [0, 2BCN): alias over p, dead after m1 GEMM

  // 1. depthwise conv + BN1 partial stats
  dwconv_kernel<<<kB * kC, 256, 0, stream>>>(x, dw_w, h0, sums, ssqs);
  // 2. BN1 finalize + SE -> per-(b,c) affine
  se_kernel<<<kB, 128, 0, stream>>>(sums, ssqs, bn1_g, bn1_b, se_w1, se_b1, se_w2, se_b2,
                                    sc_bc, bi_bc);
  // 3. hf = scale*h0 + bias
  scale_kernel<<<1024, 256, 0, stream>>>(h0, sc_bc, bi_bc, hfb);
  // 4-6. q, k, v projections
  gemm_kernel<false><<<dim3(25, 1, kB), 256, 0, stream>>>(q_w, hfb, qb, q_b, nullptr, nullptr, kQd, kC);
  gemm_kernel<false><<<dim3(25, 1, kB), 256, 0, stream>>>(k_w, hfb, kb, k_b, nullptr, nullptr, kQd, kC);
  gemm_kernel<false><<<dim3(25, 1, kB), 256, 0, stream>>>(v_w, hfb, vbuf, v_b, nullptr, nullptr, kC, kC);
  // 7. attention + residual
  attn_kernel<<<dim3(kN / 64, kB), 256, 0, stream>>>(qb, kb, vbuf, hfb, att);
  // 8. pointwise C->O
  gemm_kernel<false><<<dim3(25, 2, kB), 256, 0, stream>>>(pw_w, att, p, nullptr, nullptr, nullptr, kO, kC);
  // 9. BN2 stats
  stats_kernel<<<kO, 256, 0, stream>>>(p, kO, bn2_g, bn2_b, a2, b2);
  // 10. m1 (BN2 folded into input transform)
  gemm_kernel<false><<<dim3(25, 4, kB), 256, 0, stream>>>(m1_w, p, m1o, nullptr, a2, b2, kHd, kO);
  // 11. BN3 stats
  stats_kernel<<<kHd, 256, 0, stream>>>(m1o, kHd, bn3_g, bn3_b, a3, b3);
  // 12. m2 (BN3 + exact GELU folded into input transform)
  gemm_kernel<true><<<dim3(25, 2, kB), 256, 0, stream>>>(m2_w, m1o, m2o, nullptr, a3, b3, kO, kHd);
  // 13. BN4 stats + apply
  stats_kernel<<<kO, 256, 0, stream>>>(m2o, kO, bn4_g, bn4_b, a4, b4);
  bnout_kernel<<<2048, 256, 0, stream>>>(m2o, a4, b4, out);
}

// Round 2
// 637.377 us; speedup vs baseline: 1.9109x; 1.9109x over previous
//
#include <hip/hip_runtime.h>
#include <math.h>

namespace {

constexpr int kB = 8;
constexpr int kC = 128;
constexpr int kHin = 112, kWin = 112;
constexpr int kHout = 56, kWout = 56;
constexpr int kN = kHout * kWout;     // 3136
constexpr int kO = 256;
constexpr int kHd = 512;
constexpr int kQd = 16;
constexpr int kR = 32;
constexpr float kEps = 1e-5f;

typedef __attribute__((ext_vector_type(8))) short short8v;
typedef __attribute__((ext_vector_type(4))) float f32x4;

__device__ __forceinline__ float gelu_exact(float x) {
  return 0.5f * x * (1.0f + erff(x * 0.70710678118654752f));
}

__device__ __forceinline__ ushort f2bf(float f) {
  uint u = __float_as_uint(f);
  uint r = (u + 0x7FFFu + ((u >> 16) & 1u)) >> 16;
  return (ushort)r;
}

// ---------------- depthwise conv 3x3 stride2 pad1 + per-(b,c) sum/sumsq ----------------
__global__ __launch_bounds__(256) void dwconv_kernel(
    const float* __restrict__ x, const float* __restrict__ w,
    float* __restrict__ h0, float* __restrict__ sums, float* __restrict__ ssqs) {
  int bc = blockIdx.x;                 // b*kC + c
  int c = bc % kC;
  const float* xp = x + (size_t)bc * (kHin * kWin);
  float wr[9];
#pragma unroll
  for (int i = 0; i < 9; ++i) wr[i] = w[c * 9 + i];
  float lsum = 0.f, lssq = 0.f;
  for (int i = threadIdx.x; i < kN; i += 256) {
    int oy = i / kWout, ox = i - oy * kWout;
    int iy0 = 2 * oy - 1, ix0 = 2 * ox - 1;
    float acc = 0.f;
#pragma unroll
    for (int ky = 0; ky < 3; ++ky) {
      int iy = iy0 + ky;
      if (iy < 0 || iy >= kHin) continue;
#pragma unroll
      for (int kx = 0; kx < 3; ++kx) {
        int ix = ix0 + kx;
        if (ix < 0 || ix >= kWin) continue;
        acc += xp[iy * kWin + ix] * wr[ky * 3 + kx];
      }
    }
    h0[(size_t)bc * kN + i] = acc;
    lsum += acc;
    lssq += acc * acc;
  }
  __shared__ float rs[256], rq[256];
  rs[threadIdx.x] = lsum; rq[threadIdx.x] = lssq;
  __syncthreads();
  for (int s = 128; s > 0; s >>= 1) {
    if (threadIdx.x < s) { rs[threadIdx.x] += rs[threadIdx.x + s]; rq[threadIdx.x] += rq[threadIdx.x + s]; }
    __syncthreads();
  }
  if (threadIdx.x == 0) { sums[bc] = rs[0]; ssqs[bc] = rq[0]; }
}

// ---------------- BN1 stats + SE MLP -> per-(b,c) scale/bias ----------------
__global__ __launch_bounds__(128) void se_kernel(
    const float* __restrict__ sums, const float* __restrict__ ssqs,
    const float* __restrict__ bn1_g, const float* __restrict__ bn1_b,
    const float* __restrict__ se_w1, const float* __restrict__ se_b1,
    const float* __restrict__ se_w2, const float* __restrict__ se_b2,
    float* __restrict__ scale_bc, float* __restrict__ bias_bc) {
  int b = blockIdx.x, c = threadIdx.x;
  __shared__ float sin_[kC], s1[kR], alf[kC], bet[kC];
  float ts = 0.f, tq = 0.f;
  for (int bb = 0; bb < kB; ++bb) { ts += sums[bb * kC + c]; tq += ssqs[bb * kC + c]; }
  float inv = 1.0f / ((float)kB * (float)kN);
  float mean = ts * inv;
  float var = tq * inv - mean * mean;
  float a = bn1_g[c] * rsqrtf(var + kEps);
  float be = bn1_b[c] - mean * a;
  alf[c] = a; bet[c] = be;
  sin_[c] = a * (sums[b * kC + c] * (1.0f / kN)) + be;
  __syncthreads();
  if (c < kR) {
    float acc = se_b1[c];
    for (int j = 0; j < kC; ++j) acc += se_w1[c * kC + j] * sin_[j];
    s1[c] = fmaxf(acc, 0.f);
  }
  __syncthreads();
  float acc = se_b2[c];
  for (int j = 0; j < kR; ++j) acc += se_w2[c * kR + j] * s1[j];
  float sg = 1.0f / (1.0f + expf(-acc));
  scale_bc[b * kC + c] = alf[c] * sg;
  bias_bc[b * kC + c] = bet[c] * sg;
}

// ---------------- hf = scale_bc * h0 + bias_bc ----------------
__global__ void scale_kernel(const float* __restrict__ h0, const float* __restrict__ sc,
                             const float* __restrict__ bi, float* __restrict__ hf) {
  constexpr int n4 = kN / 4;
  size_t total4 = (size_t)kB * kC * n4;
  for (size_t i = (size_t)blockIdx.x * blockDim.x + threadIdx.x; i < total4;
       i += (size_t)gridDim.x * blockDim.x) {
    int bc = (int)(i / n4);
    float s = sc[bc], t = bi[bc];
    float4 v = reinterpret_cast<const float4*>(h0)[i];
    v.x = s * v.x + t; v.y = s * v.y + t; v.z = s * v.z + t; v.w = s * v.w + t;
    reinterpret_cast<float4*>(hf)[i] = v;
  }
}

// ---------------- generic fp32 GEMM (unchanged) ----------------
template <bool GELU>
__global__ __launch_bounds__(256) void gemm_kernel(
    const float* __restrict__ Wm, const float* __restrict__ X, float* __restrict__ Y,
    const float* __restrict__ rowbias, const float* __restrict__ insc,
    const float* __restrict__ inbi, int M, int K) {
  constexpr int BM = 128, BN = 128, BK = 16, TM = 8, TN = 8;
  int b = blockIdx.z;
  int m0 = blockIdx.y * BM, n0 = blockIdx.x * BN;
  __shared__ float Ws[BK][BM + 4];
  __shared__ float Xs[BK][BN + 4];
  int tid = threadIdx.x;
  int tx = tid % 16, ty = tid / 16;
  float acc[TM][TN] = {};
  const float* Xb = X + (size_t)b * K * kN;
  for (int kk = 0; kk < K; kk += BK) {
#pragma unroll
    for (int l = tid; l < BM * BK / 4; l += 256) {
      int mrow = l >> 2;
      int k4 = l & 3;
      float4 wv = make_float4(0.f, 0.f, 0.f, 0.f);
      if (m0 + mrow < M)
        wv = *reinterpret_cast<const float4*>(&Wm[(size_t)(m0 + mrow) * K + kk + k4 * 4]);
      Ws[k4 * 4 + 0][mrow] = wv.x;
      Ws[k4 * 4 + 1][mrow] = wv.y;
      Ws[k4 * 4 + 2][mrow] = wv.z;
      Ws[k4 * 4 + 3][mrow] = wv.w;
    }
#pragma unroll
    for (int l = tid; l < BK * BN / 4; l += 256) {
      int krow = l >> 5;
      int n4 = l & 31;
      int gn = n0 + n4 * 4;
      float4 xv = make_float4(0.f, 0.f, 0.f, 0.f);
      if (gn < kN)
        xv = *reinterpret_cast<const float4*>(&Xb[(size_t)(kk + krow) * kN + gn]);
      if (insc) {
        float s = insc[kk + krow], t = inbi[kk + krow];
        xv.x = s * xv.x + t; xv.y = s * xv.y + t; xv.z = s * xv.z + t; xv.w = s * xv.w + t;
        if (GELU) {
          xv.x = gelu_exact(xv.x); xv.y = gelu_exact(xv.y);
          xv.z = gelu_exact(xv.z); xv.w = gelu_exact(xv.w);
        }
      }
      *reinterpret_cast<float4*>(&Xs[krow][n4 * 4]) = xv;
    }
    __syncthreads();
#pragma unroll
    for (int ki = 0; ki < BK; ++ki) {
      float4 a0 = *reinterpret_cast<const float4*>(&Ws[ki][ty * TM]);
      float4 a1 = *reinterpret_cast<const float4*>(&Ws[ki][ty * TM + 4]);
      float4 b0 = *reinterpret_cast<const float4*>(&Xs[ki][tx * TN]);
      float4 b1 = *reinterpret_cast<const float4*>(&Xs[ki][tx * TN + 4]);
      float av[8] = {a0.x, a0.y, a0.z, a0.w, a1.x, a1.y, a1.z, a1.w};
      float bv[8] = {b0.x, b0.y, b0.z, b0.w, b1.x, b1.y, b1.z, b1.w};
#pragma unroll
      for (int i = 0; i < TM; ++i)
#pragma unroll
        for (int j = 0; j < TN; ++j) acc[i][j] += av[i] * bv[j];
    }
    __syncthreads();
  }
  float* Yb = Y + (size_t)b * M * kN;
#pragma unroll
  for (int i = 0; i < TM; ++i) {
    int m = m0 + ty * TM + i;
    if (m >= M) break;
    float rb = rowbias ? rowbias[m] : 0.f;
#pragma unroll
    for (int j = 0; j < TN; j += 4) {
      int n = n0 + tx * TN + j;
      if (n < kN) {
        float4 o;
        o.x = acc[i][j] + rb; o.y = acc[i][j + 1] + rb;
        o.z = acc[i][j + 2] + rb; o.w = acc[i][j + 3] + rb;
        *reinterpret_cast<float4*>(&Yb[(size_t)m * kN + n]) = o;
      }
    }
  }
}

// ---------------- q,k fp32 [b,16,n] -> bf16 transposed [b,n,16] ----------------
__global__ __launch_bounds__(256) void qkT_kernel(
    const float* __restrict__ q, const float* __restrict__ k,
    ushort* __restrict__ qT, ushort* __restrict__ kT) {
  int b = blockIdx.y;
  int n = blockIdx.x * 256 + threadIdx.x;
  if (n >= kN) return;
  const float* qb = q + (size_t)b * kQd * kN;
  const float* kb = k + (size_t)b * kQd * kN;
  uint wq[8], wk[8];
#pragma unroll
  for (int d2 = 0; d2 < 8; ++d2) {
    ushort a0 = f2bf(qb[(size_t)(2 * d2) * kN + n]);
    ushort a1 = f2bf(qb[(size_t)(2 * d2 + 1) * kN + n]);
    wq[d2] = (uint)a0 | ((uint)a1 << 16);
    ushort b0 = f2bf(kb[(size_t)(2 * d2) * kN + n]);
    ushort b1 = f2bf(kb[(size_t)(2 * d2 + 1) * kN + n]);
    wk[d2] = (uint)b0 | ((uint)b1 << 16);
  }
  ushort* qrow = qT + ((size_t)b * kN + n) * 16;
  ushort* krow = kT + ((size_t)b * kN + n) * 16;
  reinterpret_cast<uint4*>(qrow)[0] = make_uint4(wq[0], wq[1], wq[2], wq[3]);
  reinterpret_cast<uint4*>(qrow)[1] = make_uint4(wq[4], wq[5], wq[6], wq[7]);
  reinterpret_cast<uint4*>(krow)[0] = make_uint4(wk[0], wk[1], wk[2], wk[3]);
  reinterpret_cast<uint4*>(krow)[1] = make_uint4(wk[4], wk[5], wk[6], wk[7]);
}

// ---------------- v fp32 -> bf16 elementwise ----------------
__global__ void vconv_kernel(const float* __restrict__ v, ushort* __restrict__ vb) {
  size_t total4 = (size_t)kB * kC * kN / 4;
  for (size_t i = (size_t)blockIdx.x * blockDim.x + threadIdx.x; i < total4;
       i += (size_t)gridDim.x * blockDim.x) {
    float4 f = reinterpret_cast<const float4*>(v)[i];
    uint2 o;
    o.x = (uint)f2bf(f.x) | ((uint)f2bf(f.y) << 16);
    o.y = (uint)f2bf(f.z) | ((uint)f2bf(f.w) << 16);
    reinterpret_cast<uint2*>(vb)[i] = o;
  }
}

// ---------------- MFMA flash attention ----------------
// S = mfma(K_frag, Q_frag): rows=keys, cols=queries (d zero-padded 16->32).
// Per block: 64 queries, 4 waves each own a 16-query subtile; 32-key tiles.
__global__ __launch_bounds__(256) void attn_mfma_kernel(
    const ushort* __restrict__ qT, const ushort* __restrict__ kT,
    const ushort* __restrict__ vb, const float* __restrict__ hf,
    float* __restrict__ outp) {
  constexpr int VRS = 40;   // V LDS row stride (bf16), 80B: 16B-aligned, ~2-way banks
  constexpr int PRS = 40;
  int b = blockIdx.y;
  int m0 = blockIdx.x * 64;
  int tid = threadIdx.x;
  int w = tid >> 6;
  int lane = tid & 63;
  int lg = lane >> 4, lq = lane & 15;

  __shared__ ushort vs[128 * VRS];       // 10240 B
  __shared__ ushort pt[4][16 * PRS];     // 5120 B (wave-private P tiles)

  const ushort* qTb = qT + (size_t)b * kN * 16;
  const ushort* kTb = kT + (size_t)b * kN * 16;
  const ushort* vbb = vb + (size_t)b * kC * kN;

  short8v zero8 = {0, 0, 0, 0, 0, 0, 0, 0};
  short8v qf = zero8;
  int myq = m0 + w * 16 + lq;
  if (lg < 2) qf = *reinterpret_cast<const short8v*>(&qTb[(size_t)myq * 16 + lg * 8]);

  float mrun = -1e30f, lrun = 0.f;
  f32x4 acc[8];
#pragma unroll
  for (int i = 0; i < 8; ++i) acc[i] = (f32x4){0.f, 0.f, 0.f, 0.f};

  int vc = tid >> 2, vslot = tid & 3;

  for (int k0 = 0; k0 < kN; k0 += 32) {
    // issue V loads early (T14: hide latency under prev-iter drain + barrier)
    short8v v0 = *reinterpret_cast<const short8v*>(&vbb[(size_t)vc * kN + k0 + vslot * 8]);
    short8v v1 = *reinterpret_cast<const short8v*>(&vbb[(size_t)(vc + 64) * kN + k0 + vslot * 8]);
    __syncthreads();   // prev iter's V-frag reads complete
    *reinterpret_cast<short8v*>(&vs[vc * VRS + vslot * 8]) = v0;
    *reinterpret_cast<short8v*>(&vs[(vc + 64) * VRS + vslot * 8]) = v1;

    // K frags (direct global: 16 rows x 16B, L1/L2-resident) + QK^T
    short8v kf0 = zero8, kf1 = zero8;
    if (lg < 2) {
      kf0 = *reinterpret_cast<const short8v*>(&kTb[(size_t)(k0 + lq) * 16 + lg * 8]);
      kf1 = *reinterpret_cast<const short8v*>(&kTb[(size_t)(k0 + 16 + lq) * 16 + lg * 8]);
    }
    f32x4 s0 = __builtin_amdgcn_mfma_f32_16x16x32_bf16(kf0, qf, (f32x4){0.f, 0.f, 0.f, 0.f}, 0, 0, 0);
    f32x4 s1 = __builtin_amdgcn_mfma_f32_16x16x32_bf16(kf1, qf, (f32x4){0.f, 0.f, 0.f, 0.f}, 0, 0, 0);
    __syncthreads();   // V tile staged

    // online softmax: lane holds 8 scores for query lq (keys 4lg+r, 16+4lg+r)
    float sv[8] = {s0[0], s0[1], s0[2], s0[3], s1[0], s1[1], s1[2], s1[3]};
    float tmax = sv[0];
#pragma unroll
    for (int i = 1; i < 8; ++i) tmax = fmaxf(tmax, sv[i]);
    tmax = fmaxf(tmax, __shfl_xor(tmax, 16, 64));
    tmax = fmaxf(tmax, __shfl_xor(tmax, 32, 64));
    float mnew = fmaxf(mrun, tmax);
    float scl = __expf(mrun - mnew);
    float pv[8];
    float psum = 0.f;
#pragma unroll
    for (int i = 0; i < 8; ++i) { pv[i] = __expf(sv[i] - mnew); psum += pv[i]; }
    psum += __shfl_xor(psum, 16, 64);
    psum += __shfl_xor(psum, 32, 64);
    lrun = lrun * scl + psum;
    mrun = mnew;
#pragma unroll
    for (int i = 0; i < 8; ++i) {
      acc[i][0] *= scl; acc[i][1] *= scl; acc[i][2] *= scl; acc[i][3] *= scl;
    }

    // P -> bf16 -> wave-private LDS tile pt[w][q][k]
    uint p01 = (uint)f2bf(pv[0]) | ((uint)f2bf(pv[1]) << 16);
    uint p23 = (uint)f2bf(pv[2]) | ((uint)f2bf(pv[3]) << 16);
    uint p45 = (uint)f2bf(pv[4]) | ((uint)f2bf(pv[5]) << 16);
    uint p67 = (uint)f2bf(pv[6]) | ((uint)f2bf(pv[7]) << 16);
    ushort* prow = &pt[w][lq * PRS];
    *reinterpret_cast<uint*>(&prow[4 * lg]) = p01;
    *reinterpret_cast<uint*>(&prow[4 * lg + 2]) = p23;
    *reinterpret_cast<uint*>(&prow[16 + 4 * lg]) = p45;
    *reinterpret_cast<uint*>(&prow[16 + 4 * lg + 2]) = p67;
    // B-frag read (same wave; compiler orders LDS write->read)
    short8v pf = *reinterpret_cast<const short8v*>(&pt[w][lq * PRS + 8 * lg]);

    // PV: acc[ct] += V[c,k] * P[k,q]
#pragma unroll
    for (int ct = 0; ct < 8; ++ct) {
      short8v vf = *reinterpret_cast<const short8v*>(&vs[(ct * 16 + lq) * VRS + 8 * lg]);
      acc[ct] = __builtin_amdgcn_mfma_f32_16x16x32_bf16(vf, pf, acc[ct], 0, 0, 0);
    }
  }

  float linv = 1.0f / lrun;
  const float* hfb = hf + (size_t)b * kC * kN;
  float* ob = outp + (size_t)b * kC * kN;
  int q = m0 + w * 16 + lq;
#pragma unroll
  for (int ct = 0; ct < 8; ++ct) {
#pragma unroll
    for (int r = 0; r < 4; ++r) {
      int c = ct * 16 + 4 * lg + r;
      size_t idx = (size_t)c * kN + q;
      ob[idx] = acc[ct][r] * linv + hfb[idx];
    }
  }
}

// ---------------- per-channel BN stats over [B, Mch, N] -> alpha/beta ----------------
__global__ __launch_bounds__(256) void stats_kernel(
    const float* __restrict__ X, int Mch, const float* __restrict__ g,
    const float* __restrict__ bt, float* __restrict__ alpha, float* __restrict__ beta) {
  int ch = blockIdx.x;
  float s = 0.f, q = 0.f;
  for (int b = 0; b < kB; ++b) {
    const float* p = X + ((size_t)b * Mch + ch) * kN;
    for (int i = threadIdx.x; i < kN; i += 256) {
      float v = p[i];
      s += v; q += v * v;
    }
  }
  __shared__ float rs[256], rq[256];
  rs[threadIdx.x] = s; rq[threadIdx.x] = q;
  __syncthreads();
  for (int st = 128; st > 0; st >>= 1) {
    if (threadIdx.x < st) { rs[threadIdx.x] += rs[threadIdx.x + st]; rq[threadIdx.x] += rq[threadIdx.x + st]; }
    __syncthreads();
  }
  if (threadIdx.x == 0) {
    float inv = 1.0f / ((float)kB * (float)kN);
    float mean = rs[0] * inv;
    float var = rq[0] * inv - mean * mean;
    float a = g[ch] * rsqrtf(var + kEps);
    alpha[ch] = a;
    beta[ch] = bt[ch] - mean * a;
  }
}

// ---------------- final BN apply -> d_out ----------------
__global__ void bnout_kernel(const float* __restrict__ X, const float* __restrict__ alpha,
                             const float* __restrict__ beta, float* __restrict__ out) {
  constexpr int n4 = kN / 4;
  size_t total4 = (size_t)kB * kO * n4;
  for (size_t i = (size_t)blockIdx.x * blockDim.x + threadIdx.x; i < total4;
       i += (size_t)gridDim.x * blockDim.x) {
    int ch = (int)((i / n4) % kO);
    float a = alpha[ch], t = beta[ch];
    float4 v = reinterpret_cast<const float4*>(X)[i];
    v.x = a * v.x + t; v.y = a * v.y + t; v.z = a * v.z + t; v.w = a * v.w + t;
    reinterpret_cast<float4*>(out)[i] = v;
  }
}

}  // namespace

extern "C" void kernel_launch(void* const* d_in, const int* in_sizes, int n_in,
                              void* d_out, int out_size, void* d_ws, size_t ws_size,
                              hipStream_t stream) {
  const float* x     = (const float*)d_in[0];
  const float* dw_w  = (const float*)d_in[1];
  const float* bn1_g = (const float*)d_in[2];
  const float* bn1_b = (const float*)d_in[3];
  const float* se_w1 = (const float*)d_in[4];
  const float* se_b1 = (const float*)d_in[5];
  const float* se_w2 = (const float*)d_in[6];
  const float* se_b2 = (const float*)d_in[7];
  const float* q_w   = (const float*)d_in[8];
  const float* q_b   = (const float*)d_in[9];
  const float* k_w   = (const float*)d_in[10];
  const float* k_b   = (const float*)d_in[11];
  const float* v_w   = (const float*)d_in[12];
  const float* v_b   = (const float*)d_in[13];
  const float* pw_w  = (const float*)d_in[14];
  const float* bn2_g = (const float*)d_in[15];
  const float* bn2_b = (const float*)d_in[16];
  const float* m1_w  = (const float*)d_in[17];
  const float* bn3_g = (const float*)d_in[18];
  const float* bn3_b = (const float*)d_in[19];
  const float* m2_w  = (const float*)d_in[20];
  const float* bn4_g = (const float*)d_in[21];
  const float* bn4_b = (const float*)d_in[22];
  float* out = (float*)d_out;
  float* ws = (float*)d_ws;

  const size_t BCN = (size_t)kB * kC * kN;   // 3,211,264
  const size_t BQN = (size_t)kB * kQd * kN;  // 401,408

  float* h0   = ws;                // [0, BCN)
  float* hfb  = ws + BCN;          // [BCN, 2BCN)
  float* att  = ws + 2 * BCN;      // [2BCN, 3BCN)
  float* m1o  = ws + 3 * BCN;      // [3BCN, 7BCN); early part reused by bf16 bufs pre-m1
  float* qb   = ws + 7 * BCN;      // BQN
  float* kb   = qb + BQN;          // BQN
  float* sm   = kb + BQN;          // small arrays
  float* sums = sm;
  float* ssqs = sm + 1024;
  float* sc_bc = sm + 2048;
  float* bi_bc = sm + 3072;
  float* a2 = sm + 4096; float* b2 = a2 + kO;
  float* a3 = b2 + kO;   float* b3 = a3 + kHd;
  float* a4 = b3 + kHd;  float* b4 = a4 + kO;
  float* vbuf = h0;                // alias: h0 dead after scale_kernel
  float* p    = ws;                // alias over h0+hf (dead after attention)
  float* m2o  = ws;                // alias over p (dead after m1 GEMM)
  // bf16 buffers live in the (not yet written) m1o region; dead before m1 GEMM
  ushort* vb16 = (ushort*)(ws + 3 * BCN);                 // BCN bf16
  ushort* qTb  = (ushort*)(ws + 3 * BCN + BCN / 2);       // BQN bf16
  ushort* kTb  = qTb + BQN;                               // BQN bf16

  // 1. depthwise conv + BN1 partial stats
  dwconv_kernel<<<kB * kC, 256, 0, stream>>>(x, dw_w, h0, sums, ssqs);
  // 2. BN1 finalize + SE -> per-(b,c) affine
  se_kernel<<<kB, 128, 0, stream>>>(sums, ssqs, bn1_g, bn1_b, se_w1, se_b1, se_w2, se_b2,
                                    sc_bc, bi_bc);
  // 3. hf = scale*h0 + bias
  scale_kernel<<<1024, 256, 0, stream>>>(h0, sc_bc, bi_bc, hfb);
  // 4-6. q, k, v projections (fp32)
  gemm_kernel<false><<<dim3(25, 1, kB), 256, 0, stream>>>(q_w, hfb, qb, q_b, nullptr, nullptr, kQd, kC);
  gemm_kernel<false><<<dim3(25, 1, kB), 256, 0, stream>>>(k_w, hfb, kb, k_b, nullptr, nullptr, kQd, kC);
  gemm_kernel<false><<<dim3(25, 2, kB), 256, 0, stream>>>(v_w, hfb, vbuf, v_b, nullptr, nullptr, kC, kC);
  // 6.5 bf16 conversions for attention
  qkT_kernel<<<dim3((kN + 255) / 256, kB), 256, 0, stream>>>(qb, kb, qTb, kTb);
  vconv_kernel<<<512, 256, 0, stream>>>(vbuf, vb16);
  // 7. MFMA flash attention + residual
  attn_mfma_kernel<<<dim3(kN / 64, kB), 256, 0, stream>>>(qTb, kTb, vb16, hfb, att);
  // 8. pointwise C->O
  gemm_kernel<false><<<dim3(25, 2, kB), 256, 0, stream>>>(pw_w, att, p, nullptr, nullptr, nullptr, kO, kC);
  // 9. BN2 stats
  stats_kernel<<<kO, 256, 0, stream>>>(p, kO, bn2_g, bn2_b, a2, b2);
  // 10. m1 (BN2 folded into input transform)
  gemm_kernel<false><<<dim3(25, 4, kB), 256, 0, stream>>>(m1_w, p, m1o, nullptr, a2, b2, kHd, kO);
  // 11. BN3 stats
  stats_kernel<<<kHd, 256, 0, stream>>>(m1o, kHd, bn3_g, bn3_b, a3, b3);
  // 12. m2 (BN3 + exact GELU folded into input transform)
  gemm_kernel<true><<<dim3(25, 2, kB), 256, 0, stream>>>(m2_w, m1o, m2o, nullptr, a3, b3, kO, kHd);
  // 13. BN4 stats + apply
  stats_kernel<<<kO, 256, 0, stream>>>(m2o, kO, bn4_g, bn4_b, a4, b4);
  bnout_kernel<<<2048, 256, 0, stream>>>(m2o, a4, b4, out);
}

// Round 4
// 370.358 us; speedup vs baseline: 3.2886x; 1.7210x over previous
//
#include <hip/hip_runtime.h>
#include <math.h>

namespace {

constexpr int kB = 8;
constexpr int kC = 128;
constexpr int kHin = 112, kWin = 112;
constexpr int kHout = 56, kWout = 56;
constexpr int kN = kHout * kWout;     // 3136
constexpr int kO = 256;
constexpr int kHd = 512;
constexpr int kQd = 16;
constexpr int kR = 32;
constexpr float kEps = 1e-5f;

typedef __attribute__((ext_vector_type(8))) short short8v;
typedef __attribute__((ext_vector_type(4))) float f32x4;

__device__ __forceinline__ float gelu_exact(float x) {
  return 0.5f * x * (1.0f + erff(x * 0.70710678118654752f));
}

__device__ __forceinline__ ushort f2bf(float f) {
  uint u = __float_as_uint(f);
  uint r = (u + 0x7FFFu + ((u >> 16) & 1u)) >> 16;
  return (ushort)r;
}
__device__ __forceinline__ uint pack2bf(float a, float b) {
  return (uint)f2bf(a) | ((uint)f2bf(b) << 16);
}

// ---------------- depthwise conv 3x3 stride2 pad1 + per-(b,c) sum/sumsq ----------------
__global__ __launch_bounds__(256) void dwconv_kernel(
    const float* __restrict__ x, const float* __restrict__ w,
    float* __restrict__ h0, float* __restrict__ sums, float* __restrict__ ssqs) {
  int bc = blockIdx.x;
  int c = bc % kC;
  const float* xp = x + (size_t)bc * (kHin * kWin);
  float wr[9];
#pragma unroll
  for (int i = 0; i < 9; ++i) wr[i] = w[c * 9 + i];
  float lsum = 0.f, lssq = 0.f;
  for (int i = threadIdx.x; i < kN; i += 256) {
    int oy = i / kWout, ox = i - oy * kWout;
    int iy0 = 2 * oy - 1, ix0 = 2 * ox - 1;
    float acc = 0.f;
#pragma unroll
    for (int ky = 0; ky < 3; ++ky) {
      int iy = iy0 + ky;
      if (iy < 0 || iy >= kHin) continue;
#pragma unroll
      for (int kx = 0; kx < 3; ++kx) {
        int ix = ix0 + kx;
        if (ix < 0 || ix >= kWin) continue;
        acc += xp[iy * kWin + ix] * wr[ky * 3 + kx];
      }
    }
    h0[(size_t)bc * kN + i] = acc;
    lsum += acc;
    lssq += acc * acc;
  }
  __shared__ float rs[256], rq[256];
  rs[threadIdx.x] = lsum; rq[threadIdx.x] = lssq;
  __syncthreads();
  for (int s = 128; s > 0; s >>= 1) {
    if (threadIdx.x < s) { rs[threadIdx.x] += rs[threadIdx.x + s]; rq[threadIdx.x] += rq[threadIdx.x + s]; }
    __syncthreads();
  }
  if (threadIdx.x == 0) { sums[bc] = rs[0]; ssqs[bc] = rq[0]; }
}

// ---------------- BN1 stats + SE MLP -> per-(b,c) scale/bias ----------------
__global__ __launch_bounds__(128) void se_kernel(
    const float* __restrict__ sums, const float* __restrict__ ssqs,
    const float* __restrict__ bn1_g, const float* __restrict__ bn1_b,
    const float* __restrict__ se_w1, const float* __restrict__ se_b1,
    const float* __restrict__ se_w2, const float* __restrict__ se_b2,
    float* __restrict__ scale_bc, float* __restrict__ bias_bc) {
  int b = blockIdx.x, c = threadIdx.x;
  __shared__ float sin_[kC], s1[kR], alf[kC], bet[kC];
  float ts = 0.f, tq = 0.f;
  for (int bb = 0; bb < kB; ++bb) { ts += sums[bb * kC + c]; tq += ssqs[bb * kC + c]; }
  float inv = 1.0f / ((float)kB * (float)kN);
  float mean = ts * inv;
  float var = tq * inv - mean * mean;
  float a = bn1_g[c] * rsqrtf(var + kEps);
  float be = bn1_b[c] - mean * a;
  alf[c] = a; bet[c] = be;
  sin_[c] = a * (sums[b * kC + c] * (1.0f / kN)) + be;
  __syncthreads();
  if (c < kR) {
    float acc = se_b1[c];
    for (int j = 0; j < kC; ++j) acc += se_w1[c * kC + j] * sin_[j];
    s1[c] = fmaxf(acc, 0.f);
  }
  __syncthreads();
  float acc = se_b2[c];
  for (int j = 0; j < kR; ++j) acc += se_w2[c * kR + j] * s1[j];
  float sg = 1.0f / (1.0f + expf(-acc));
  scale_bc[b * kC + c] = alf[c] * sg;
  bias_bc[b * kC + c] = bet[c] * sg;
}

// ---------------- hf = scale*h0+bias (ch-major) AND hfT (token-major fp32) ----------------
__global__ __launch_bounds__(256) void scale_tm_kernel(
    const float* __restrict__ h0, const float* __restrict__ sc,
    const float* __restrict__ bi, float* __restrict__ hf, float* __restrict__ hfT) {
  __shared__ float T[32][33];
  int b = blockIdx.z;
  int c0 = blockIdx.y * 32;
  int n0 = blockIdx.x * 32;
  int tid = threadIdx.x;
  int r = tid >> 3, seg = tid & 7;
  int c = c0 + r;
  int bc = b * kC + c;
  float s = sc[bc], t = bi[bc];
  size_t idx = (size_t)bc * kN + n0 + seg * 4;
  float4 v = *(const float4*)&h0[idx];
  v.x = s * v.x + t; v.y = s * v.y + t; v.z = s * v.z + t; v.w = s * v.w + t;
  *(float4*)&hf[idx] = v;
  T[seg * 4 + 0][r] = v.x; T[seg * 4 + 1][r] = v.y;
  T[seg * 4 + 2][r] = v.z; T[seg * 4 + 3][r] = v.w;
  __syncthreads();
  float4 o = make_float4(T[r][seg * 4], T[r][seg * 4 + 1], T[r][seg * 4 + 2], T[r][seg * 4 + 3]);
  *(float4*)&hfT[((size_t)b * kN + n0 + r) * kC + c0 + seg * 4] = o;
}

// ---------------- weights fp32 -> bf16 ----------------
__global__ void wconv_kernel(const float* __restrict__ vw, const float* __restrict__ pww,
                             const float* __restrict__ m1w, const float* __restrict__ m2w,
                             ushort* __restrict__ ov, ushort* __restrict__ opw,
                             ushort* __restrict__ om1, ushort* __restrict__ om2) {
  int stride = gridDim.x * 256;
  int i0 = blockIdx.x * 256 + threadIdx.x;
  for (int i = i0; i < 128 * 128; i += stride) ov[i] = f2bf(vw[i]);
  for (int i = i0; i < 256 * 128; i += stride) opw[i] = f2bf(pww[i]);
  for (int i = i0; i < 512 * 256; i += stride) om1[i] = f2bf(m1w[i]);
  for (int i = i0; i < 256 * 512; i += stride) om2[i] = f2bf(m2w[i]);
}

// ---------------- q,k projection -> bf16 token-major [n][32] ----------------
__global__ __launch_bounds__(256) void qk_kernel(
    const float* __restrict__ hfT, const float* __restrict__ q_w,
    const float* __restrict__ q_b, const float* __restrict__ k_w,
    const float* __restrict__ k_b, ushort* __restrict__ qkT) {
  __shared__ float Wl[32][128];
  __shared__ float Xl[64][129];
  int b = blockIdx.y;
  int n0 = blockIdx.x * 64;
  int tid = threadIdx.x;
  for (int u = tid; u < 1024; u += 256) {
    int r = u >> 5, seg = u & 31;   // FIX: 32 rows x 32 float4-segments (was >>3 / &7)
    const float* src = (r < 16) ? &q_w[r * 128 + seg * 4] : &k_w[(r - 16) * 128 + seg * 4];
    float4 v = *(const float4*)src;
    *(float4*)&Wl[r][seg * 4] = v;
  }
  const float* Xb = hfT + ((size_t)b * kN + n0) * kC;
  for (int u = tid; u < 2048; u += 256) {
    int r = u >> 5, seg = u & 31;
    float4 v = *(const float4*)&Xb[(size_t)r * kC + seg * 4];
    Xl[r][seg * 4 + 0] = v.x; Xl[r][seg * 4 + 1] = v.y;
    Xl[r][seg * 4 + 2] = v.z; Xl[r][seg * 4 + 3] = v.w;
  }
  __syncthreads();
  int tt = tid & 63, og = tid >> 6;
  float acc[8] = {};
  for (int k = 0; k < 128; ++k) {
    float xx = Xl[tt][k];
#pragma unroll
    for (int j = 0; j < 8; ++j) acc[j] += xx * Wl[og * 8 + j][k];
  }
  uint pk[4];
#pragma unroll
  for (int j2 = 0; j2 < 4; ++j2) {
    int m = og * 8 + j2 * 2;
    float b0 = (m < 16) ? q_b[m] : k_b[m - 16];
    float b1 = (m + 1 < 16) ? q_b[m + 1] : k_b[m + 1 - 16];
    pk[j2] = pack2bf(acc[j2 * 2] + b0, acc[j2 * 2 + 1] + b1);
  }
  *(uint4*)&qkT[((size_t)b * kN + n0 + tt) * 32 + og * 8] = make_uint4(pk[0], pk[1], pk[2], pk[3]);
}

// ---------------- MFMA GEMM: Y = W(bf16) . X(token-major), optional affine/GELU on X ----------------
// OUTMODE 0: fp32 token-major [n][M].  OUTMODE 1: bf16 ch-major [m][n] + bias.
template <int M, int K, int OUTMODE, bool AFFINE, bool GELU>
__global__ __launch_bounds__(256) void mfma_gemm_kernel(
    const ushort* __restrict__ Wb, const float* __restrict__ X,
    float* __restrict__ Yf, ushort* __restrict__ Yh, const float* __restrict__ bias,
    const float* __restrict__ insc, const float* __restrict__ inbi) {
  constexpr int BM = 128, BN = 128, BK = 64, LDW = 72;
  __shared__ ushort Wl[BM * LDW];
  __shared__ ushort Xl[BN * LDW];
  int b = blockIdx.z;
  int n0 = blockIdx.x * BN;
  int m0 = blockIdx.y * BM;
  int tid = threadIdx.x;
  int w = tid >> 6, lane = tid & 63;
  int wm = w >> 1, wn = w & 1;
  int lg = lane >> 4, lq = lane & 15;
  const float* Xb = X + (size_t)b * kN * K;
  f32x4 acc[4][4];
#pragma unroll
  for (int i = 0; i < 4; ++i)
#pragma unroll
    for (int j = 0; j < 4; ++j) acc[i][j] = (f32x4){0.f, 0.f, 0.f, 0.f};

  int wseg = tid & 7;    // W staging: 16B seg
  int xseg = tid & 15;   // X staging: float4 seg

  for (int kk = 0; kk < K; kk += BK) {
    __syncthreads();
    // stage W tile [128][64] bf16
#pragma unroll
    for (int u = 0; u < 4; ++u) {
      int row = (tid + u * 256) >> 3;
      short8v wv = *(const short8v*)&Wb[(size_t)(m0 + row) * K + kk + wseg * 8];
      *(short8v*)&Wl[row * LDW + wseg * 8] = wv;
    }
    // stage X tile [128][64] fp32 -> (affine/gelu) -> bf16
    float4 s4, t4;
    if (AFFINE) {
      s4 = *(const float4*)&insc[kk + xseg * 4];
      t4 = *(const float4*)&inbi[kk + xseg * 4];
    }
#pragma unroll
    for (int u = 0; u < 8; ++u) {
      int row = (tid + u * 256) >> 4;
      int n = n0 + row;
      float4 xv = make_float4(0.f, 0.f, 0.f, 0.f);
      if (n < kN) xv = *(const float4*)&Xb[(size_t)n * K + kk + xseg * 4];
      if (AFFINE) {
        xv.x = s4.x * xv.x + t4.x; xv.y = s4.y * xv.y + t4.y;
        xv.z = s4.z * xv.z + t4.z; xv.w = s4.w * xv.w + t4.w;
        if (GELU) {
          xv.x = gelu_exact(xv.x); xv.y = gelu_exact(xv.y);
          xv.z = gelu_exact(xv.z); xv.w = gelu_exact(xv.w);
        }
      }
      *(uint2*)&Xl[row * LDW + xseg * 4] =
          make_uint2(pack2bf(xv.x, xv.y), pack2bf(xv.z, xv.w));
    }
    __syncthreads();
#pragma unroll
    for (int kh = 0; kh < BK; kh += 32) {
      short8v af[4], bfr[4];
#pragma unroll
      for (int f = 0; f < 4; ++f) {
        af[f] = *(const short8v*)&Wl[(wm * 64 + f * 16 + lq) * LDW + kh + 8 * lg];
        bfr[f] = *(const short8v*)&Xl[(wn * 64 + f * 16 + lq) * LDW + kh + 8 * lg];
      }
#pragma unroll
      for (int fi = 0; fi < 4; ++fi)
#pragma unroll
        for (int fj = 0; fj < 4; ++fj)
          acc[fi][fj] = __builtin_amdgcn_mfma_f32_16x16x32_bf16(af[fi], bfr[fj], acc[fi][fj], 0, 0, 0);
    }
  }
  if (OUTMODE == 0) {
    float* Yb = Yf + (size_t)b * kN * M;
#pragma unroll
    for (int fj = 0; fj < 4; ++fj) {
      int n = n0 + wn * 64 + fj * 16 + lq;
      if (n < kN) {
#pragma unroll
        for (int fi = 0; fi < 4; ++fi)
          *(f32x4*)&Yb[(size_t)n * M + m0 + wm * 64 + fi * 16 + 4 * lg] = acc[fi][fj];
      }
    }
  } else {
    ushort* Yb = Yh + (size_t)b * M * kN;
#pragma unroll
    for (int fi = 0; fi < 4; ++fi) {
#pragma unroll
      for (int r = 0; r < 4; ++r) {
        int m = m0 + wm * 64 + fi * 16 + 4 * lg + r;
        float bv = bias ? bias[m] : 0.f;
#pragma unroll
        for (int fj = 0; fj < 4; ++fj) {
          int n = n0 + wn * 64 + fj * 16 + lq;
          if (n < kN) Yb[(size_t)m * kN + n] = f2bf(acc[fi][fj][r] + bv);
        }
      }
    }
  }
}

// ---------------- MFMA flash attention; out = token-major fp32 [n][128] with residual ----------------
__global__ __launch_bounds__(256) void attn_mfma_kernel(
    const ushort* __restrict__ qkT, const ushort* __restrict__ vb,
    const float* __restrict__ hf, float* __restrict__ attT) {
  constexpr int VRS = 40;
  constexpr int PRS = 40;
  int b = blockIdx.x;            // x = b: same-batch blocks share an XCD's L2
  int m0 = blockIdx.y * 64;
  int tid = threadIdx.x;
  int w = tid >> 6;
  int lane = tid & 63;
  int lg = lane >> 4, lq = lane & 15;

  __shared__ ushort vs[128 * VRS];
  __shared__ ushort pt[4][16 * PRS];

  const ushort* qTb = qkT + (size_t)b * kN * 32;
  const ushort* vbb = vb + (size_t)b * kC * kN;

  short8v zero8 = {0, 0, 0, 0, 0, 0, 0, 0};
  short8v qf = zero8;
  int myq = m0 + w * 16 + lq;
  if (lg < 2) qf = *(const short8v*)&qTb[(size_t)myq * 32 + lg * 8];

  float mrun = -1e30f, lrun = 0.f;
  f32x4 acc[8];
#pragma unroll
  for (int i = 0; i < 8; ++i) acc[i] = (f32x4){0.f, 0.f, 0.f, 0.f};

  int vc = tid >> 2, vslot = tid & 3;

  for (int k0 = 0; k0 < kN; k0 += 32) {
    short8v v0 = *(const short8v*)&vbb[(size_t)vc * kN + k0 + vslot * 8];
    short8v v1 = *(const short8v*)&vbb[(size_t)(vc + 64) * kN + k0 + vslot * 8];
    __syncthreads();
    *(short8v*)&vs[vc * VRS + vslot * 8] = v0;
    *(short8v*)&vs[(vc + 64) * VRS + vslot * 8] = v1;

    short8v kf0 = zero8, kf1 = zero8;
    if (lg < 2) {
      kf0 = *(const short8v*)&qTb[(size_t)(k0 + lq) * 32 + 16 + lg * 8];
      kf1 = *(const short8v*)&qTb[(size_t)(k0 + 16 + lq) * 32 + 16 + lg * 8];
    }
    f32x4 s0 = __builtin_amdgcn_mfma_f32_16x16x32_bf16(kf0, qf, (f32x4){0.f, 0.f, 0.f, 0.f}, 0, 0, 0);
    f32x4 s1 = __builtin_amdgcn_mfma_f32_16x16x32_bf16(kf1, qf, (f32x4){0.f, 0.f, 0.f, 0.f}, 0, 0, 0);
    __syncthreads();

    float sv[8] = {s0[0], s0[1], s0[2], s0[3], s1[0], s1[1], s1[2], s1[3]};
    float tmax = sv[0];
#pragma unroll
    for (int i = 1; i < 8; ++i) tmax = fmaxf(tmax, sv[i]);
    tmax = fmaxf(tmax, __shfl_xor(tmax, 16, 64));
    tmax = fmaxf(tmax, __shfl_xor(tmax, 32, 64));
    float mnew = fmaxf(mrun, tmax);
    float scl = __expf(mrun - mnew);
    float pv[8];
    float psum = 0.f;
#pragma unroll
    for (int i = 0; i < 8; ++i) { pv[i] = __expf(sv[i] - mnew); psum += pv[i]; }
    psum += __shfl_xor(psum, 16, 64);
    psum += __shfl_xor(psum, 32, 64);
    lrun = lrun * scl + psum;
    mrun = mnew;
#pragma unroll
    for (int i = 0; i < 8; ++i) {
      acc[i][0] *= scl; acc[i][1] *= scl; acc[i][2] *= scl; acc[i][3] *= scl;
    }

    uint p01 = pack2bf(pv[0], pv[1]);
    uint p23 = pack2bf(pv[2], pv[3]);
    uint p45 = pack2bf(pv[4], pv[5]);
    uint p67 = pack2bf(pv[6], pv[7]);
    ushort* prow = &pt[w][lq * PRS];
    *(uint*)&prow[4 * lg] = p01;
    *(uint*)&prow[4 * lg + 2] = p23;
    *(uint*)&prow[16 + 4 * lg] = p45;
    *(uint*)&prow[16 + 4 * lg + 2] = p67;
    short8v pf = *(const short8v*)&pt[w][lq * PRS + 8 * lg];

#pragma unroll
    for (int ct = 0; ct < 8; ++ct) {
      short8v vf = *(const short8v*)&vs[(ct * 16 + lq) * VRS + 8 * lg];
      acc[ct] = __builtin_amdgcn_mfma_f32_16x16x32_bf16(vf, pf, acc[ct], 0, 0, 0);
    }
  }

  float linv = 1.0f / lrun;
  const float* hfb = hf + (size_t)b * kC * kN;
  float* ab = attT + (size_t)b * kN * kC;
  int q = m0 + w * 16 + lq;
#pragma unroll
  for (int ct = 0; ct < 8; ++ct) {
    int c0 = ct * 16 + 4 * lg;
    float4 o;
    o.x = acc[ct][0] * linv + hfb[(size_t)(c0 + 0) * kN + q];
    o.y = acc[ct][1] * linv + hfb[(size_t)(c0 + 1) * kN + q];
    o.z = acc[ct][2] * linv + hfb[(size_t)(c0 + 2) * kN + q];
    o.w = acc[ct][3] * linv + hfb[(size_t)(c0 + 3) * kN + q];
    *(float4*)&ab[(size_t)q * kC + c0] = o;
  }
}

// ---------------- token-major BN stats: partials then finalize ----------------
template <int CH>
__global__ __launch_bounds__(256) void stats_tm_kernel(
    const float* __restrict__ X, float* __restrict__ psum, float* __restrict__ pssq) {
  constexpr int RPB = (kB * kN) / 256;  // 98
  int r0 = blockIdx.x * RPB;
  float s[CH / 256] = {}, q[CH / 256] = {};
  for (int r = r0; r < r0 + RPB; ++r) {
    const float* row = X + (size_t)r * CH;
#pragma unroll
    for (int cc = 0; cc < CH / 256; ++cc) {
      float v = row[threadIdx.x + cc * 256];
      s[cc] += v; q[cc] += v * v;
    }
  }
#pragma unroll
  for (int cc = 0; cc < CH / 256; ++cc) {
    psum[(size_t)blockIdx.x * CH + threadIdx.x + cc * 256] = s[cc];
    pssq[(size_t)blockIdx.x * CH + threadIdx.x + cc * 256] = q[cc];
  }
}

template <int CH>
__global__ __launch_bounds__(256) void bnfin_kernel(
    const float* __restrict__ psum, const float* __restrict__ pssq,
    const float* __restrict__ g, const float* __restrict__ bt,
    float* __restrict__ alpha, float* __restrict__ beta) {
  int ch = blockIdx.x * 256 + threadIdx.x;
  if (ch >= CH) return;
  float s = 0.f, q = 0.f;
  for (int p = 0; p < 256; ++p) { s += psum[(size_t)p * CH + ch]; q += pssq[(size_t)p * CH + ch]; }
  float inv = 1.0f / ((float)kB * (float)kN);
  float mean = s * inv;
  float var = q * inv - mean * mean;
  float a = g[ch] * rsqrtf(var + kEps);
  alpha[ch] = a;
  beta[ch] = bt[ch] - mean * a;
}

// ---------------- final BN apply + transpose [n][256] -> out [b][256][n] ----------------
__global__ __launch_bounds__(256) void bnout_t_kernel(
    const float* __restrict__ X, const float* __restrict__ alpha,
    const float* __restrict__ beta, float* __restrict__ out) {
  __shared__ float T[32][33];
  int b = blockIdx.z;
  int c0 = blockIdx.y * 32;
  int n0 = blockIdx.x * 32;
  int tid = threadIdx.x;
  int r = tid >> 3, seg = tid & 7;
  float4 v = *(const float4*)&X[((size_t)b * kN + n0 + r) * kO + c0 + seg * 4];
  float4 a = *(const float4*)&alpha[c0 + seg * 4];
  float4 bb = *(const float4*)&beta[c0 + seg * 4];
  v.x = a.x * v.x + bb.x; v.y = a.y * v.y + bb.y;
  v.z = a.z * v.z + bb.z; v.w = a.w * v.w + bb.w;
  T[seg * 4 + 0][r] = v.x; T[seg * 4 + 1][r] = v.y;
  T[seg * 4 + 2][r] = v.z; T[seg * 4 + 3][r] = v.w;
  __syncthreads();
  float4 o = make_float4(T[r][seg * 4], T[r][seg * 4 + 1], T[r][seg * 4 + 2], T[r][seg * 4 + 3]);
  *(float4*)&out[((size_t)b * kO + c0 + r) * kN + n0 + seg * 4] = o;
}

}  // namespace

extern "C" void kernel_launch(void* const* d_in, const int* in_sizes, int n_in,
                              void* d_out, int out_size, void* d_ws, size_t ws_size,
                              hipStream_t stream) {
  const float* x     = (const float*)d_in[0];
  const float* dw_w  = (const float*)d_in[1];
  const float* bn1_g = (const float*)d_in[2];
  const float* bn1_b = (const float*)d_in[3];
  const float* se_w1 = (const float*)d_in[4];
  const float* se_b1 = (const float*)d_in[5];
  const float* se_w2 = (const float*)d_in[6];
  const float* se_b2 = (const float*)d_in[7];
  const float* q_w   = (const float*)d_in[8];
  const float* q_b   = (const float*)d_in[9];
  const float* k_w   = (const float*)d_in[10];
  const float* k_b   = (const float*)d_in[11];
  const float* v_w   = (const float*)d_in[12];
  const float* v_b   = (const float*)d_in[13];
  const float* pw_w  = (const float*)d_in[14];
  const float* bn2_g = (const float*)d_in[15];
  const float* bn2_b = (const float*)d_in[16];
  const float* m1_w  = (const float*)d_in[17];
  const float* bn3_g = (const float*)d_in[18];
  const float* bn3_b = (const float*)d_in[19];
  const float* m2_w  = (const float*)d_in[20];
  const float* bn4_g = (const float*)d_in[21];
  const float* bn4_b = (const float*)d_in[22];
  float* out = (float*)d_out;
  float* ws = (float*)d_ws;

  const size_t BCN = (size_t)kB * kC * kN;   // 3,211,264 floats

  // fp32 buffers
  float* h0    = ws;                 // [0, BCN)      dead after scale_tm
  float* hf    = ws + BCN;           // [BCN, 2BCN)   dead after attn
  float* hfT32 = ws + 2 * BCN;       // [2BCN, 3BCN)  dead after v/qk
  float* attT  = ws + 3 * BCN;       // [3BCN, 4BCN)  dead after pw
  float* p_tm  = ws + 4 * BCN;       // [4BCN, 6BCN)  dead after m1
  float* m1o   = ws;                 // [0, 4BCN)     (all prior dead)
  float* m2o   = ws + 4 * BCN;       // [4BCN, 6BCN)  (p_tm dead)
  // bf16 buffers inside dead-h0 region
  ushort* vb16  = (ushort*)ws;                         // BCN elems
  ushort* qkT16 = (ushort*)(ws + BCN / 2);             // kB*kN*32 elems
  // weights bf16 + partials + small arrays at [6BCN, ...)
  ushort* wv16  = (ushort*)(ws + 6 * BCN);
  ushort* wpw16 = wv16 + 128 * 128;
  ushort* wm116 = wpw16 + 256 * 128;
  ushort* wm216 = wm116 + 512 * 256;                   // ends at 6BCN + 155648 floats
  float* psum = ws + 6 * BCN + 155648;                 // 256*512
  float* pssq = psum + 131072;
  float* smal = pssq + 131072;
  float* sums  = smal;
  float* ssqs  = smal + 1024;
  float* sc_bc = smal + 2048;
  float* bi_bc = smal + 3072;
  float* a2 = smal + 4096; float* b2 = a2 + kO;
  float* a3 = b2 + kO;     float* b3 = a3 + kHd;
  float* a4 = b3 + kHd;    float* b4 = a4 + kO;

  // 0. weight conversion (independent)
  wconv_kernel<<<512, 256, 0, stream>>>(v_w, pw_w, m1_w, m2_w, wv16, wpw16, wm116, wm216);
  // 1. depthwise conv + BN1 partial stats
  dwconv_kernel<<<kB * kC, 256, 0, stream>>>(x, dw_w, h0, sums, ssqs);
  // 2. BN1 finalize + SE
  se_kernel<<<kB, 128, 0, stream>>>(sums, ssqs, bn1_g, bn1_b, se_w1, se_b1, se_w2, se_b2,
                                    sc_bc, bi_bc);
  // 3. hf + hfT32
  scale_tm_kernel<<<dim3(98, 4, kB), 256, 0, stream>>>(h0, sc_bc, bi_bc, hf, hfT32);
  // 4. q,k -> bf16 token-major
  qk_kernel<<<dim3(49, kB), 256, 0, stream>>>(hfT32, q_w, q_b, k_w, k_b, qkT16);
  // 5. v -> bf16 ch-major (MFMA)
  mfma_gemm_kernel<128, 128, 1, false, false><<<dim3(25, 1, kB), 256, 0, stream>>>(
      wv16, hfT32, nullptr, vb16, v_b, nullptr, nullptr);
  // 6. attention + residual -> attT (token-major fp32)
  attn_mfma_kernel<<<dim3(kB, kN / 64), 256, 0, stream>>>(qkT16, vb16, hf, attT);
  // 7. pw -> p_tm fp32 [n][256]
  mfma_gemm_kernel<256, 128, 0, false, false><<<dim3(25, 2, kB), 256, 0, stream>>>(
      wpw16, attT, p_tm, nullptr, nullptr, nullptr, nullptr);
  // 8. BN2 stats
  stats_tm_kernel<256><<<256, 256, 0, stream>>>(p_tm, psum, pssq);
  bnfin_kernel<256><<<1, 256, 0, stream>>>(psum, pssq, bn2_g, bn2_b, a2, b2);
  // 9. m1 (BN2 affine folded into staging) -> m1o fp32 [n][512]
  mfma_gemm_kernel<512, 256, 0, true, false><<<dim3(25, 4, kB), 256, 0, stream>>>(
      wm116, p_tm, m1o, nullptr, nullptr, a2, b2);
  // 10. BN3 stats
  stats_tm_kernel<512><<<256, 256, 0, stream>>>(m1o, psum, pssq);
  bnfin_kernel<512><<<2, 256, 0, stream>>>(psum, pssq, bn3_g, bn3_b, a3, b3);
  // 11. m2 (BN3 affine + exact GELU folded into staging) -> m2o fp32 [n][256]
  mfma_gemm_kernel<256, 512, 0, true, true><<<dim3(25, 2, kB), 256, 0, stream>>>(
      wm216, m1o, m2o, nullptr, nullptr, a3, b3);
  // 12. BN4 stats + apply (with transpose to ch-major output)
  stats_tm_kernel<256><<<256, 256, 0, stream>>>(m2o, psum, pssq);
  bnfin_kernel<256><<<1, 256, 0, stream>>>(psum, pssq, bn4_g, bn4_b, a4, b4);
  bnout_t_kernel<<<dim3(98, 8, kB), 256, 0, stream>>>(m2o, a4, b4, out);
}

// Round 5
// 363.062 us; speedup vs baseline: 3.3547x; 1.0201x over previous
//
#include <hip/hip_runtime.h>
#include <math.h>

namespace {

constexpr int kB = 8;
constexpr int kC = 128;
constexpr int kHin = 112, kWin = 112;
constexpr int kHout = 56, kWout = 56;
constexpr int kN = kHout * kWout;     // 3136
constexpr int kO = 256;
constexpr int kHd = 512;
constexpr int kQd = 16;
constexpr int kR = 32;
constexpr float kEps = 1e-5f;

typedef __attribute__((ext_vector_type(8))) short short8v;
typedef __attribute__((ext_vector_type(4))) float f32x4;
typedef __attribute__((ext_vector_type(16))) float f32x16;
typedef __attribute__((ext_vector_type(4))) uint uint4v;

__device__ __forceinline__ float gelu_exact(float x) {
  return 0.5f * x * (1.0f + erff(x * 0.70710678118654752f));
}

__device__ __forceinline__ ushort f2bf(float f) {
  uint u = __float_as_uint(f);
  uint r = (u + 0x7FFFu + ((u >> 16) & 1u)) >> 16;
  return (ushort)r;
}
__device__ __forceinline__ uint pack2bf(float a, float b) {
  return (uint)f2bf(a) | ((uint)f2bf(b) << 16);
}

// ---------------- depthwise conv 3x3 stride2 pad1 + per-(b,c) sum/sumsq ----------------
__global__ __launch_bounds__(256) void dwconv_kernel(
    const float* __restrict__ x, const float* __restrict__ w,
    float* __restrict__ h0, float* __restrict__ sums, float* __restrict__ ssqs) {
  int bc = blockIdx.x;
  int c = bc % kC;
  const float* xp = x + (size_t)bc * (kHin * kWin);
  float wr[9];
#pragma unroll
  for (int i = 0; i < 9; ++i) wr[i] = w[c * 9 + i];
  float lsum = 0.f, lssq = 0.f;
  for (int i = threadIdx.x; i < kN; i += 256) {
    int oy = i / kWout, ox = i - oy * kWout;
    int iy0 = 2 * oy - 1, ix0 = 2 * ox - 1;
    float acc = 0.f;
#pragma unroll
    for (int ky = 0; ky < 3; ++ky) {
      int iy = iy0 + ky;
      if (iy < 0 || iy >= kHin) continue;
#pragma unroll
      for (int kx = 0; kx < 3; ++kx) {
        int ix = ix0 + kx;
        if (ix < 0 || ix >= kWin) continue;
        acc += xp[iy * kWin + ix] * wr[ky * 3 + kx];
      }
    }
    h0[(size_t)bc * kN + i] = acc;
    lsum += acc;
    lssq += acc * acc;
  }
  __shared__ float rs[256], rq[256];
  rs[threadIdx.x] = lsum; rq[threadIdx.x] = lssq;
  __syncthreads();
  for (int s = 128; s > 0; s >>= 1) {
    if (threadIdx.x < s) { rs[threadIdx.x] += rs[threadIdx.x + s]; rq[threadIdx.x] += rq[threadIdx.x + s]; }
    __syncthreads();
  }
  if (threadIdx.x == 0) { sums[bc] = rs[0]; ssqs[bc] = rq[0]; }
}

// ---------------- BN1 stats + SE MLP -> per-(b,c) scale/bias ----------------
__global__ __launch_bounds__(128) void se_kernel(
    const float* __restrict__ sums, const float* __restrict__ ssqs,
    const float* __restrict__ bn1_g, const float* __restrict__ bn1_b,
    const float* __restrict__ se_w1, const float* __restrict__ se_b1,
    const float* __restrict__ se_w2, const float* __restrict__ se_b2,
    float* __restrict__ scale_bc, float* __restrict__ bias_bc) {
  int b = blockIdx.x, c = threadIdx.x;
  __shared__ float sin_[kC], s1[kR], alf[kC], bet[kC];
  float ts = 0.f, tq = 0.f;
  for (int bb = 0; bb < kB; ++bb) { ts += sums[bb * kC + c]; tq += ssqs[bb * kC + c]; }
  float inv = 1.0f / ((float)kB * (float)kN);
  float mean = ts * inv;
  float var = tq * inv - mean * mean;
  float a = bn1_g[c] * rsqrtf(var + kEps);
  float be = bn1_b[c] - mean * a;
  alf[c] = a; bet[c] = be;
  sin_[c] = a * (sums[b * kC + c] * (1.0f / kN)) + be;
  __syncthreads();
  if (c < kR) {
    float acc = se_b1[c];
    for (int j = 0; j < kC; ++j) acc += se_w1[c * kC + j] * sin_[j];
    s1[c] = fmaxf(acc, 0.f);
  }
  __syncthreads();
  float acc = se_b2[c];
  for (int j = 0; j < kR; ++j) acc += se_w2[c * kR + j] * s1[j];
  float sg = 1.0f / (1.0f + expf(-acc));
  scale_bc[b * kC + c] = alf[c] * sg;
  bias_bc[b * kC + c] = bet[c] * sg;
}

// ---------------- hfT (token-major fp32) = transpose(scale*h0+bias) ----------------
__global__ __launch_bounds__(256) void scale_tm_kernel(
    const float* __restrict__ h0, const float* __restrict__ sc,
    const float* __restrict__ bi, float* __restrict__ hfT) {
  __shared__ float T[32][33];
  int b = blockIdx.z;
  int c0 = blockIdx.y * 32;
  int n0 = blockIdx.x * 32;
  int tid = threadIdx.x;
  int r = tid >> 3, seg = tid & 7;
  int c = c0 + r;
  int bc = b * kC + c;
  float s = sc[bc], t = bi[bc];
  size_t idx = (size_t)bc * kN + n0 + seg * 4;
  float4 v = *(const float4*)&h0[idx];
  v.x = s * v.x + t; v.y = s * v.y + t; v.z = s * v.z + t; v.w = s * v.w + t;
  T[seg * 4 + 0][r] = v.x; T[seg * 4 + 1][r] = v.y;
  T[seg * 4 + 2][r] = v.z; T[seg * 4 + 3][r] = v.w;
  __syncthreads();
  float4 o = make_float4(T[r][seg * 4], T[r][seg * 4 + 1], T[r][seg * 4 + 2], T[r][seg * 4 + 3]);
  *(float4*)&hfT[((size_t)b * kN + n0 + r) * kC + c0 + seg * 4] = o;
}

// ---------------- weights fp32 -> bf16 ----------------
__global__ void wconv_kernel(const float* __restrict__ vw, const float* __restrict__ pww,
                             const float* __restrict__ m1w, const float* __restrict__ m2w,
                             ushort* __restrict__ ov, ushort* __restrict__ opw,
                             ushort* __restrict__ om1, ushort* __restrict__ om2) {
  int stride = gridDim.x * 256;
  int i0 = blockIdx.x * 256 + threadIdx.x;
  for (int i = i0; i < 128 * 128; i += stride) ov[i] = f2bf(vw[i]);
  for (int i = i0; i < 256 * 128; i += stride) opw[i] = f2bf(pww[i]);
  for (int i = i0; i < 512 * 256; i += stride) om1[i] = f2bf(m1w[i]);
  for (int i = i0; i < 256 * 512; i += stride) om2[i] = f2bf(m2w[i]);
}

// ---------------- q,k projection -> bf16 token-major [n][32] ----------------
__global__ __launch_bounds__(256) void qk_kernel(
    const float* __restrict__ hfT, const float* __restrict__ q_w,
    const float* __restrict__ q_b, const float* __restrict__ k_w,
    const float* __restrict__ k_b, ushort* __restrict__ qkT) {
  __shared__ float Wl[32][128];
  __shared__ float Xl[64][129];
  int b = blockIdx.y;
  int n0 = blockIdx.x * 64;
  int tid = threadIdx.x;
  for (int u = tid; u < 1024; u += 256) {
    int r = u >> 5, seg = u & 31;
    const float* src = (r < 16) ? &q_w[r * 128 + seg * 4] : &k_w[(r - 16) * 128 + seg * 4];
    float4 v = *(const float4*)src;
    *(float4*)&Wl[r][seg * 4] = v;
  }
  const float* Xb = hfT + ((size_t)b * kN + n0) * kC;
  for (int u = tid; u < 2048; u += 256) {
    int r = u >> 5, seg = u & 31;
    float4 v = *(const float4*)&Xb[(size_t)r * kC + seg * 4];
    Xl[r][seg * 4 + 0] = v.x; Xl[r][seg * 4 + 1] = v.y;
    Xl[r][seg * 4 + 2] = v.z; Xl[r][seg * 4 + 3] = v.w;
  }
  __syncthreads();
  int tt = tid & 63, og = tid >> 6;
  float acc[8] = {};
  for (int k = 0; k < 128; ++k) {
    float xx = Xl[tt][k];
#pragma unroll
    for (int j = 0; j < 8; ++j) acc[j] += xx * Wl[og * 8 + j][k];
  }
  uint pk[4];
#pragma unroll
  for (int j2 = 0; j2 < 4; ++j2) {
    int m = og * 8 + j2 * 2;
    float b0 = (m < 16) ? q_b[m] : k_b[m - 16];
    float b1 = (m + 1 < 16) ? q_b[m + 1] : k_b[m + 1 - 16];
    pk[j2] = pack2bf(acc[j2 * 2] + b0, acc[j2 * 2 + 1] + b1);
  }
  *(uint4*)&qkT[((size_t)b * kN + n0 + tt) * 32 + og * 8] = make_uint4(pk[0], pk[1], pk[2], pk[3]);
}

// ---------------- MFMA GEMM: Y = W(bf16) . X(token-major), optional affine/GELU on X ----------------
// OUTMODE 0: fp32 token-major [n][M].  OUTMODE 1: bf16 ch-major [m][n] + bias.
template <int M, int K, int OUTMODE, bool AFFINE, bool GELU>
__global__ __launch_bounds__(256) void mfma_gemm_kernel(
    const ushort* __restrict__ Wb, const float* __restrict__ X,
    float* __restrict__ Yf, ushort* __restrict__ Yh, const float* __restrict__ bias,
    const float* __restrict__ insc, const float* __restrict__ inbi) {
  constexpr int BM = 128, BN = 128, BK = 64, LDW = 72;
  __shared__ ushort Wl[BM * LDW];
  __shared__ ushort Xl[BN * LDW];
  int b = blockIdx.z;
  int n0 = blockIdx.x * BN;
  int m0 = blockIdx.y * BM;
  int tid = threadIdx.x;
  int w = tid >> 6, lane = tid & 63;
  int wm = w >> 1, wn = w & 1;
  int lg = lane >> 4, lq = lane & 15;
  const float* Xb = X + (size_t)b * kN * K;
  f32x4 acc[4][4];
#pragma unroll
  for (int i = 0; i < 4; ++i)
#pragma unroll
    for (int j = 0; j < 4; ++j) acc[i][j] = (f32x4){0.f, 0.f, 0.f, 0.f};

  int wseg = tid & 7;
  int xseg = tid & 15;

  for (int kk = 0; kk < K; kk += BK) {
    __syncthreads();
#pragma unroll
    for (int u = 0; u < 4; ++u) {
      int row = (tid + u * 256) >> 3;
      short8v wv = *(const short8v*)&Wb[(size_t)(m0 + row) * K + kk + wseg * 8];
      *(short8v*)&Wl[row * LDW + wseg * 8] = wv;
    }
    float4 s4, t4;
    if (AFFINE) {
      s4 = *(const float4*)&insc[kk + xseg * 4];
      t4 = *(const float4*)&inbi[kk + xseg * 4];
    }
#pragma unroll
    for (int u = 0; u < 8; ++u) {
      int row = (tid + u * 256) >> 4;
      int n = n0 + row;
      float4 xv = make_float4(0.f, 0.f, 0.f, 0.f);
      if (n < kN) xv = *(const float4*)&Xb[(size_t)n * K + kk + xseg * 4];
      if (AFFINE) {
        xv.x = s4.x * xv.x + t4.x; xv.y = s4.y * xv.y + t4.y;
        xv.z = s4.z * xv.z + t4.z; xv.w = s4.w * xv.w + t4.w;
        if (GELU) {
          xv.x = gelu_exact(xv.x); xv.y = gelu_exact(xv.y);
          xv.z = gelu_exact(xv.z); xv.w = gelu_exact(xv.w);
        }
      }
      *(uint2*)&Xl[row * LDW + xseg * 4] =
          make_uint2(pack2bf(xv.x, xv.y), pack2bf(xv.z, xv.w));
    }
    __syncthreads();
#pragma unroll
    for (int kh = 0; kh < BK; kh += 32) {
      short8v af[4], bfr[4];
#pragma unroll
      for (int f = 0; f < 4; ++f) {
        af[f] = *(const short8v*)&Wl[(wm * 64 + f * 16 + lq) * LDW + kh + 8 * lg];
        bfr[f] = *(const short8v*)&Xl[(wn * 64 + f * 16 + lq) * LDW + kh + 8 * lg];
      }
#pragma unroll
      for (int fi = 0; fi < 4; ++fi)
#pragma unroll
        for (int fj = 0; fj < 4; ++fj)
          acc[fi][fj] = __builtin_amdgcn_mfma_f32_16x16x32_bf16(af[fi], bfr[fj], acc[fi][fj], 0, 0, 0);
    }
  }
  if (OUTMODE == 0) {
    float* Yb = Yf + (size_t)b * kN * M;
#pragma unroll
    for (int fj = 0; fj < 4; ++fj) {
      int n = n0 + wn * 64 + fj * 16 + lq;
      if (n < kN) {
#pragma unroll
        for (int fi = 0; fi < 4; ++fi)
          *(f32x4*)&Yb[(size_t)n * M + m0 + wm * 64 + fi * 16 + 4 * lg] = acc[fi][fj];
      }
    }
  } else {
    ushort* Yb = Yh + (size_t)b * M * kN;
#pragma unroll
    for (int fi = 0; fi < 4; ++fi) {
#pragma unroll
      for (int r = 0; r < 4; ++r) {
        int m = m0 + wm * 64 + fi * 16 + 4 * lg + r;
        float bv = bias ? bias[m] : 0.f;
#pragma unroll
        for (int fj = 0; fj < 4; ++fj) {
          int n = n0 + wn * 64 + fj * 16 + lq;
          if (n < kN) Yb[(size_t)m * kN + n] = f2bf(acc[fi][fj][r] + bv);
        }
      }
    }
  }
}

// ---------------- 32x32x16 MFMA flash attention, barrier-free k-loop ----------------
// Block: 32 queries, 4 waves k-split (wave w: tiles t = w, w+4, ...).
// V-frags read directly from global (per-batch V = 803KB, XCD-L2 resident via bid%8=b).
__global__ __launch_bounds__(256) void attn_mfma32_kernel(
    const ushort* __restrict__ qkT, const ushort* __restrict__ vb,
    const float* __restrict__ hfT, float* __restrict__ attT) {
  int b = blockIdx.x;                   // bid%8 = b -> one batch per XCD
  int n0 = blockIdx.y * 32;
  int tid = threadIdx.x;
  int w = tid >> 6;
  int lane = tid & 63;
  int l31 = lane & 31;
  int hi = lane >> 5;

  __shared__ float mbuf[4][32], lbuf[4][32], lfin[32];
  __shared__ float obuf[32][132];       // [q][c], padded

  const ushort* qkb = qkT + (size_t)b * kN * 32;
  const ushort* vbb = vb + (size_t)b * kC * kN;

  // Q B-frag: col=lane&31 -> query n0+l31, d = 8*hi + j  (k=16 exact, no padding)
  short8v qf = *(const short8v*)&qkb[(size_t)(n0 + l31) * 32 + 8 * hi];

  f32x16 z16 = {0.f,0.f,0.f,0.f,0.f,0.f,0.f,0.f,0.f,0.f,0.f,0.f,0.f,0.f,0.f,0.f};
  f32x16 acc[4];
#pragma unroll
  for (int cg = 0; cg < 4; ++cg) acc[cg] = z16;

  float m = -1e30f, l = 0.f;
  const ushort* vbase = vbb + (size_t)l31 * kN + 8 * hi;

  for (int t = w; t < 98; t += 4) {
    int k0 = t * 32;
    // V A-frags: lane row c = cg*32 + l31, k-elems = 8*hi + j (issued early; QK covers latency)
    short8v va[4], vb2[4];
#pragma unroll
    for (int cg = 0; cg < 4; ++cg) {
      const ushort* p = vbase + (size_t)cg * 32 * kN + k0;
      va[cg] = *(const short8v*)p;         // keys k0..k0+15 slice
      vb2[cg] = *(const short8v*)(p + 16); // keys k0+16..k0+31 slice
    }
    // K A-frag: row = key k0+l31, k-elems d = 8*hi + j
    short8v kf = *(const short8v*)&qkb[(size_t)(k0 + l31) * 32 + 16 + 8 * hi];
    f32x16 s = __builtin_amdgcn_mfma_f32_32x32x16_bf16(kf, qf, z16, 0, 0, 0);
    // lane: q = l31; reg r -> key = k0 + (r&3) + 8*(r>>2) + 4*hi

    float tmax = s[0];
#pragma unroll
    for (int i = 1; i < 16; ++i) tmax = fmaxf(tmax, s[i]);
    tmax = fmaxf(tmax, __shfl_xor(tmax, 32, 64));

    if (!__all(tmax <= m + 8.0f)) {       // T13 defer-max
      float mnew = fmaxf(m, tmax);
      float scl = __expf(m - mnew);
      l *= scl;
#pragma unroll
      for (int cg = 0; cg < 4; ++cg)
#pragma unroll
        for (int i = 0; i < 16; ++i) acc[cg][i] *= scl;
      m = mnew;
    }
    float p[16];
    float ps = 0.f;
#pragma unroll
    for (int i = 0; i < 16; ++i) { p[i] = __expf(s[i] - m); ps += p[i]; }
    ps += __shfl_xor(ps, 32, 64);
    l += ps;

    // pack P to bf16 pairs (adjacent keys): w0..w3 = keys {0,1},{2,3},{8,9},{12,13 part} per layout
    uint wd[8];
#pragma unroll
    for (int i = 0; i < 8; ++i) {
      uint r;
      asm("v_cvt_pk_bf16_f32 %0, %1, %2" : "=v"(r) : "v"(p[2 * i]), "v"(p[2 * i + 1]));
      wd[i] = r;
    }
    // cross-half exchange -> B-frag word order (lo lanes keys 0-7 / hi lanes 8-15 per k-half)
#pragma unroll
    for (int base = 0; base < 8; base += 4) {
#pragma unroll
      for (int j = 0; j < 2; ++j) {
        uint a = wd[base + j], c = wd[base + j + 2];
        uint sa = __shfl_xor(a, 32, 64);
        uint sc = __shfl_xor(c, 32, 64);
        wd[base + j] = (hi == 0) ? a : sc;
        wd[base + j + 2] = (hi == 0) ? sa : c;
      }
    }
    uint4v u1 = {wd[0], wd[1], wd[2], wd[3]};
    uint4v u2 = {wd[4], wd[5], wd[6], wd[7]};
    short8v P1 = __builtin_bit_cast(short8v, u1);
    short8v P2 = __builtin_bit_cast(short8v, u2);
#pragma unroll
    for (int cg = 0; cg < 4; ++cg) {
      acc[cg] = __builtin_amdgcn_mfma_f32_32x32x16_bf16(va[cg], P1, acc[cg], 0, 0, 0);
      acc[cg] = __builtin_amdgcn_mfma_f32_32x32x16_bf16(vb2[cg], P2, acc[cg], 0, 0, 0);
    }
  }

  // ---- 4-way flash merge (once per block) ----
  if (lane < 32) { mbuf[w][lane] = m; lbuf[w][lane] = l; }
  __syncthreads();
  float M = -1e30f;
#pragma unroll
  for (int j = 0; j < 4; ++j) M = fmaxf(M, mbuf[j][l31]);
  float L = 0.f;
#pragma unroll
  for (int j = 0; j < 4; ++j) L += lbuf[j][l31] * __expf(mbuf[j][l31] - M);
  if (w == 0 && lane < 32) lfin[lane] = L;
  float f = __expf(m - M);

  for (int turn = 0; turn < 4; ++turn) {
    if (w == turn) {
#pragma unroll
      for (int cg = 0; cg < 4; ++cg)
#pragma unroll
        for (int rr = 0; rr < 4; ++rr) {
          int c = cg * 32 + 8 * rr + 4 * hi;
          float4 vv;
          vv.x = f * acc[cg][4 * rr + 0];
          vv.y = f * acc[cg][4 * rr + 1];
          vv.z = f * acc[cg][4 * rr + 2];
          vv.w = f * acc[cg][4 * rr + 3];
          if (turn == 0) {
            *(float4*)&obuf[l31][c] = vv;
          } else {
            float4 o = *(const float4*)&obuf[l31][c];
            o.x += vv.x; o.y += vv.y; o.z += vv.z; o.w += vv.w;
            *(float4*)&obuf[l31][c] = o;
          }
        }
    }
    __syncthreads();
  }

  // epilogue: O/L + residual (hfT token-major, coalesced), write attT [n][128]
  int q = tid >> 3;
  int cs = (tid & 7) * 16;
  float linv = 1.0f / lfin[q];
  size_t nidx = (size_t)b * kN + n0 + q;
  const float* hrow = &hfT[nidx * kC + cs];
  float* arow = &attT[nidx * kC + cs];
#pragma unroll
  for (int cc = 0; cc < 16; cc += 4) {
    float4 r = *(const float4*)&hrow[cc];
    float4 o;
    o.x = obuf[q][cs + cc + 0] * linv + r.x;
    o.y = obuf[q][cs + cc + 1] * linv + r.y;
    o.z = obuf[q][cs + cc + 2] * linv + r.z;
    o.w = obuf[q][cs + cc + 3] * linv + r.w;
    *(float4*)&arow[cc] = o;
  }
}

// ---------------- token-major BN stats: partials then finalize ----------------
template <int CH>
__global__ __launch_bounds__(256) void stats_tm_kernel(
    const float* __restrict__ X, float* __restrict__ psum, float* __restrict__ pssq) {
  constexpr int RPB = (kB * kN) / 256;  // 98
  int r0 = blockIdx.x * RPB;
  float s[CH / 256] = {}, q[CH / 256] = {};
  for (int r = r0; r < r0 + RPB; ++r) {
    const float* row = X + (size_t)r * CH;
#pragma unroll
    for (int cc = 0; cc < CH / 256; ++cc) {
      float v = row[threadIdx.x + cc * 256];
      s[cc] += v; q[cc] += v * v;
    }
  }
#pragma unroll
  for (int cc = 0; cc < CH / 256; ++cc) {
    psum[(size_t)blockIdx.x * CH + threadIdx.x + cc * 256] = s[cc];
    pssq[(size_t)blockIdx.x * CH + threadIdx.x + cc * 256] = q[cc];
  }
}

template <int CH>
__global__ __launch_bounds__(256) void bnfin_kernel(
    const float* __restrict__ psum, const float* __restrict__ pssq,
    const float* __restrict__ g, const float* __restrict__ bt,
    float* __restrict__ alpha, float* __restrict__ beta) {
  int ch = blockIdx.x * 256 + threadIdx.x;
  if (ch >= CH) return;
  float s = 0.f, q = 0.f;
  for (int p = 0; p < 256; ++p) { s += psum[(size_t)p * CH + ch]; q += pssq[(size_t)p * CH + ch]; }
  float inv = 1.0f / ((float)kB * (float)kN);
  float mean = s * inv;
  float var = q * inv - mean * mean;
  float a = g[ch] * rsqrtf(var + kEps);
  alpha[ch] = a;
  beta[ch] = bt[ch] - mean * a;
}

// ---------------- final BN apply + transpose [n][256] -> out [b][256][n] ----------------
__global__ __launch_bounds__(256) void bnout_t_kernel(
    const float* __restrict__ X, const float* __restrict__ alpha,
    const float* __restrict__ beta, float* __restrict__ out) {
  __shared__ float T[32][33];
  int b = blockIdx.z;
  int c0 = blockIdx.y * 32;
  int n0 = blockIdx.x * 32;
  int tid = threadIdx.x;
  int r = tid >> 3, seg = tid & 7;
  float4 v = *(const float4*)&X[((size_t)b * kN + n0 + r) * kO + c0 + seg * 4];
  float4 a = *(const float4*)&alpha[c0 + seg * 4];
  float4 bb = *(const float4*)&beta[c0 + seg * 4];
  v.x = a.x * v.x + bb.x; v.y = a.y * v.y + bb.y;
  v.z = a.z * v.z + bb.z; v.w = a.w * v.w + bb.w;
  T[seg * 4 + 0][r] = v.x; T[seg * 4 + 1][r] = v.y;
  T[seg * 4 + 2][r] = v.z; T[seg * 4 + 3][r] = v.w;
  __syncthreads();
  float4 o = make_float4(T[r][seg * 4], T[r][seg * 4 + 1], T[r][seg * 4 + 2], T[r][seg * 4 + 3]);
  *(float4*)&out[((size_t)b * kO + c0 + r) * kN + n0 + seg * 4] = o;
}

}  // namespace

extern "C" void kernel_launch(void* const* d_in, const int* in_sizes, int n_in,
                              void* d_out, int out_size, void* d_ws, size_t ws_size,
                              hipStream_t stream) {
  const float* x     = (const float*)d_in[0];
  const float* dw_w  = (const float*)d_in[1];
  const float* bn1_g = (const float*)d_in[2];
  const float* bn1_b = (const float*)d_in[3];
  const float* se_w1 = (const float*)d_in[4];
  const float* se_b1 = (const float*)d_in[5];
  const float* se_w2 = (const float*)d_in[6];
  const float* se_b2 = (const float*)d_in[7];
  const float* q_w   = (const float*)d_in[8];
  const float* q_b   = (const float*)d_in[9];
  const float* k_w   = (const float*)d_in[10];
  const float* k_b   = (const float*)d_in[11];
  const float* v_w   = (const float*)d_in[12];
  const float* v_b   = (const float*)d_in[13];
  const float* pw_w  = (const float*)d_in[14];
  const float* bn2_g = (const float*)d_in[15];
  const float* bn2_b = (const float*)d_in[16];
  const float* m1_w  = (const float*)d_in[17];
  const float* bn3_g = (const float*)d_in[18];
  const float* bn3_b = (const float*)d_in[19];
  const float* m2_w  = (const float*)d_in[20];
  const float* bn4_g = (const float*)d_in[21];
  const float* bn4_b = (const float*)d_in[22];
  float* out = (float*)d_out;
  float* ws = (float*)d_ws;

  const size_t BCN = (size_t)kB * kC * kN;   // 3,211,264 floats

  // fp32 buffers
  float* h0    = ws;                 // [0, BCN)      dead after scale_tm
  float* hfT32 = ws + 2 * BCN;       // [2BCN, 3BCN)  dead after attn (residual source)
  float* attT  = ws + 3 * BCN;       // [3BCN, 4BCN)  dead after pw
  float* p_tm  = ws + 4 * BCN;       // [4BCN, 6BCN)  dead after m1
  float* m1o   = ws;                 // [0, 4BCN)     (all prior dead)
  float* m2o   = ws + 4 * BCN;       // [4BCN, 6BCN)  (p_tm dead)
  // bf16 buffers inside dead-h0 region
  ushort* vb16  = (ushort*)ws;                         // BCN elems
  ushort* qkT16 = (ushort*)(ws + BCN / 2);             // kB*kN*32 elems
  // weights bf16 + partials + small arrays at [6BCN, ...)
  ushort* wv16  = (ushort*)(ws + 6 * BCN);
  ushort* wpw16 = wv16 + 128 * 128;
  ushort* wm116 = wpw16 + 256 * 128;
  ushort* wm216 = wm116 + 512 * 256;
  float* psum = ws + 6 * BCN + 155648;                 // 256*512
  float* pssq = psum + 131072;
  float* smal = pssq + 131072;
  float* sums  = smal;
  float* ssqs  = smal + 1024;
  float* sc_bc = smal + 2048;
  float* bi_bc = smal + 3072;
  float* a2 = smal + 4096; float* b2 = a2 + kO;
  float* a3 = b2 + kO;     float* b3 = a3 + kHd;
  float* a4 = b3 + kHd;    float* b4 = a4 + kO;

  // 0. weight conversion (independent)
  wconv_kernel<<<512, 256, 0, stream>>>(v_w, pw_w, m1_w, m2_w, wv16, wpw16, wm116, wm216);
  // 1. depthwise conv + BN1 partial stats
  dwconv_kernel<<<kB * kC, 256, 0, stream>>>(x, dw_w, h0, sums, ssqs);
  // 2. BN1 finalize + SE
  se_kernel<<<kB, 128, 0, stream>>>(sums, ssqs, bn1_g, bn1_b, se_w1, se_b1, se_w2, se_b2,
                                    sc_bc, bi_bc);
  // 3. hfT32 (token-major)
  scale_tm_kernel<<<dim3(98, 4, kB), 256, 0, stream>>>(h0, sc_bc, bi_bc, hfT32);
  // 4. q,k -> bf16 token-major [n][32]
  qk_kernel<<<dim3(49, kB), 256, 0, stream>>>(hfT32, q_w, q_b, k_w, k_b, qkT16);
  // 5. v -> bf16 ch-major (MFMA)
  mfma_gemm_kernel<128, 128, 1, false, false><<<dim3(25, 1, kB), 256, 0, stream>>>(
      wv16, hfT32, nullptr, vb16, v_b, nullptr, nullptr);
  // 6. attention + residual -> attT (token-major fp32)
  attn_mfma32_kernel<<<dim3(kB, kN / 32), 256, 0, stream>>>(qkT16, vb16, hfT32, attT);
  // 7. pw -> p_tm fp32 [n][256]
  mfma_gemm_kernel<256, 128, 0, false, false><<<dim3(25, 2, kB), 256, 0, stream>>>(
      wpw16, attT, p_tm, nullptr, nullptr, nullptr, nullptr);
  // 8. BN2 stats
  stats_tm_kernel<256><<<256, 256, 0, stream>>>(p_tm, psum, pssq);
  bnfin_kernel<256><<<1, 256, 0, stream>>>(psum, pssq, bn2_g, bn2_b, a2, b2);
  // 9. m1 (BN2 affine folded into staging) -> m1o fp32 [n][512]
  mfma_gemm_kernel<512, 256, 0, true, false><<<dim3(25, 4, kB), 256, 0, stream>>>(
      wm116, p_tm, m1o, nullptr, nullptr, a2, b2);
  // 10. BN3 stats
  stats_tm_kernel<512><<<256, 256, 0, stream>>>(m1o, psum, pssq);
  bnfin_kernel<512><<<2, 256, 0, stream>>>(psum, pssq, bn3_g, bn3_b, a3, b3);
  // 11. m2 (BN3 affine + exact GELU folded into staging) -> m2o fp32 [n][256]
  mfma_gemm_kernel<256, 512, 0, true, true><<<dim3(25, 2, kB), 256, 0, stream>>>(
      wm216, m1o, m2o, nullptr, nullptr, a3, b3);
  // 12. BN4 stats + apply (with transpose to ch-major output)
  stats_tm_kernel<256><<<256, 256, 0, stream>>>(m2o, psum, pssq);
  bnfin_kernel<256><<<1, 256, 0, stream>>>(psum, pssq, bn4_g, bn4_b, a4, b4);
  bnout_t_kernel<<<dim3(98, 8, kB), 256, 0, stream>>>(m2o, a4, b4, out);
}

// Round 7
// 361.653 us; speedup vs baseline: 3.3678x; 1.0039x over previous
//
#include <hip/hip_runtime.h>
#include <math.h>

namespace {

constexpr int kB = 8;
constexpr int kC = 128;
constexpr int kHin = 112, kWin = 112;
constexpr int kHout = 56, kWout = 56;
constexpr int kN = kHout * kWout;     // 3136
constexpr int kO = 256;
constexpr int kHd = 512;
constexpr int kQd = 16;
constexpr int kR = 32;
constexpr float kEps = 1e-5f;

typedef __attribute__((ext_vector_type(8))) short short8v;
typedef __attribute__((ext_vector_type(4))) float f32x4;
typedef __attribute__((ext_vector_type(16))) float f32x16;
typedef __attribute__((ext_vector_type(4))) uint uint4v;

__device__ __forceinline__ float gelu_exact(float x) {
  return 0.5f * x * (1.0f + erff(x * 0.70710678118654752f));
}

__device__ __forceinline__ ushort f2bf(float f) {
  uint u = __float_as_uint(f);
  uint r = (u + 0x7FFFu + ((u >> 16) & 1u)) >> 16;
  return (ushort)r;
}
__device__ __forceinline__ uint pack2bf(float a, float b) {
  return (uint)f2bf(a) | ((uint)f2bf(b) << 16);
}

// ---------------- depthwise conv 3x3 stride2 pad1 + per-(b,c) sum/sumsq ----------------
__global__ __launch_bounds__(256) void dwconv_kernel(
    const float* __restrict__ x, const float* __restrict__ w,
    float* __restrict__ h0, float* __restrict__ sums, float* __restrict__ ssqs) {
  int bc = blockIdx.x;
  int c = bc % kC;
  const float* xp = x + (size_t)bc * (kHin * kWin);
  float wr[9];
#pragma unroll
  for (int i = 0; i < 9; ++i) wr[i] = w[c * 9 + i];
  float lsum = 0.f, lssq = 0.f;
  for (int i = threadIdx.x; i < kN; i += 256) {
    int oy = i / kWout, ox = i - oy * kWout;
    int iy0 = 2 * oy - 1, ix0 = 2 * ox - 1;
    float acc = 0.f;
#pragma unroll
    for (int ky = 0; ky < 3; ++ky) {
      int iy = iy0 + ky;
      if (iy < 0 || iy >= kHin) continue;
#pragma unroll
      for (int kx = 0; kx < 3; ++kx) {
        int ix = ix0 + kx;
        if (ix < 0 || ix >= kWin) continue;
        acc += xp[iy * kWin + ix] * wr[ky * 3 + kx];
      }
    }
    h0[(size_t)bc * kN + i] = acc;
    lsum += acc;
    lssq += acc * acc;
  }
  __shared__ float rs[256], rq[256];
  rs[threadIdx.x] = lsum; rq[threadIdx.x] = lssq;
  __syncthreads();
  for (int s = 128; s > 0; s >>= 1) {
    if (threadIdx.x < s) { rs[threadIdx.x] += rs[threadIdx.x + s]; rq[threadIdx.x] += rq[threadIdx.x + s]; }
    __syncthreads();
  }
  if (threadIdx.x == 0) { sums[bc] = rs[0]; ssqs[bc] = rq[0]; }
}

// ---------------- BN1 stats + SE MLP -> per-(b,c) scale/bias ----------------
__global__ __launch_bounds__(128) void se_kernel(
    const float* __restrict__ sums, const float* __restrict__ ssqs,
    const float* __restrict__ bn1_g, const float* __restrict__ bn1_b,
    const float* __restrict__ se_w1, const float* __restrict__ se_b1,
    const float* __restrict__ se_w2, const float* __restrict__ se_b2,
    float* __restrict__ scale_bc, float* __restrict__ bias_bc) {
  int b = blockIdx.x, c = threadIdx.x;
  __shared__ float sin_[kC], s1[kR], alf[kC], bet[kC];
  float ts = 0.f, tq = 0.f;
  for (int bb = 0; bb < kB; ++bb) { ts += sums[bb * kC + c]; tq += ssqs[bb * kC + c]; }
  float inv = 1.0f / ((float)kB * (float)kN);
  float mean = ts * inv;
  float var = tq * inv - mean * mean;
  float a = bn1_g[c] * rsqrtf(var + kEps);
  float be = bn1_b[c] - mean * a;
  alf[c] = a; bet[c] = be;
  sin_[c] = a * (sums[b * kC + c] * (1.0f / kN)) + be;
  __syncthreads();
  if (c < kR) {
    float acc = se_b1[c];
    for (int j = 0; j < kC; ++j) acc += se_w1[c * kC + j] * sin_[j];
    s1[c] = fmaxf(acc, 0.f);
  }
  __syncthreads();
  float acc = se_b2[c];
  for (int j = 0; j < kR; ++j) acc += se_w2[c * kR + j] * s1[j];
  float sg = 1.0f / (1.0f + expf(-acc));
  scale_bc[b * kC + c] = alf[c] * sg;
  bias_bc[b * kC + c] = bet[c] * sg;
}

// ---------------- hfT (token-major fp32) = transpose(scale*h0+bias) ----------------
__global__ __launch_bounds__(256) void scale_tm_kernel(
    const float* __restrict__ h0, const float* __restrict__ sc,
    const float* __restrict__ bi, float* __restrict__ hfT) {
  __shared__ float T[32][33];
  int b = blockIdx.z;
  int c0 = blockIdx.y * 32;
  int n0 = blockIdx.x * 32;
  int tid = threadIdx.x;
  int r = tid >> 3, seg = tid & 7;
  int c = c0 + r;
  int bc = b * kC + c;
  float s = sc[bc], t = bi[bc];
  size_t idx = (size_t)bc * kN + n0 + seg * 4;
  float4 v = *(const float4*)&h0[idx];
  v.x = s * v.x + t; v.y = s * v.y + t; v.z = s * v.z + t; v.w = s * v.w + t;
  T[seg * 4 + 0][r] = v.x; T[seg * 4 + 1][r] = v.y;
  T[seg * 4 + 2][r] = v.z; T[seg * 4 + 3][r] = v.w;
  __syncthreads();
  float4 o = make_float4(T[r][seg * 4], T[r][seg * 4 + 1], T[r][seg * 4 + 2], T[r][seg * 4 + 3]);
  *(float4*)&hfT[((size_t)b * kN + n0 + r) * kC + c0 + seg * 4] = o;
}

// ---------------- weights fp32 -> bf16 ----------------
__global__ void wconv_kernel(const float* __restrict__ vw, const float* __restrict__ pww,
                             const float* __restrict__ m1w, const float* __restrict__ m2w,
                             ushort* __restrict__ ov, ushort* __restrict__ opw,
                             ushort* __restrict__ om1, ushort* __restrict__ om2) {
  int stride = gridDim.x * 256;
  int i0 = blockIdx.x * 256 + threadIdx.x;
  for (int i = i0; i < 128 * 128; i += stride) ov[i] = f2bf(vw[i]);
  for (int i = i0; i < 256 * 128; i += stride) opw[i] = f2bf(pww[i]);
  for (int i = i0; i < 512 * 256; i += stride) om1[i] = f2bf(m1w[i]);
  for (int i = i0; i < 256 * 512; i += stride) om2[i] = f2bf(m2w[i]);
}

// ---------------- q,k projection -> bf16 token-major [n][32] ----------------
__global__ __launch_bounds__(256) void qk_kernel(
    const float* __restrict__ hfT, const float* __restrict__ q_w,
    const float* __restrict__ q_b, const float* __restrict__ k_w,
    const float* __restrict__ k_b, ushort* __restrict__ qkT) {
  __shared__ float Wl[32][128];
  __shared__ float Xl[64][129];
  int b = blockIdx.y;
  int n0 = blockIdx.x * 64;
  int tid = threadIdx.x;
  for (int u = tid; u < 1024; u += 256) {
    int r = u >> 5, seg = u & 31;
    const float* src = (r < 16) ? &q_w[r * 128 + seg * 4] : &k_w[(r - 16) * 128 + seg * 4];
    float4 v = *(const float4*)src;
    *(float4*)&Wl[r][seg * 4] = v;
  }
  const float* Xb = hfT + ((size_t)b * kN + n0) * kC;
  for (int u = tid; u < 2048; u += 256) {
    int r = u >> 5, seg = u & 31;
    float4 v = *(const float4*)&Xb[(size_t)r * kC + seg * 4];
    Xl[r][seg * 4 + 0] = v.x; Xl[r][seg * 4 + 1] = v.y;
    Xl[r][seg * 4 + 2] = v.z; Xl[r][seg * 4 + 3] = v.w;
  }
  __syncthreads();
  int tt = tid & 63, og = tid >> 6;
  float acc[8] = {};
  for (int k = 0; k < 128; ++k) {
    float xx = Xl[tt][k];
#pragma unroll
    for (int j = 0; j < 8; ++j) acc[j] += xx * Wl[og * 8 + j][k];
  }
  uint pk[4];
#pragma unroll
  for (int j2 = 0; j2 < 4; ++j2) {
    int m = og * 8 + j2 * 2;
    float b0 = (m < 16) ? q_b[m] : k_b[m - 16];
    float b1 = (m + 1 < 16) ? q_b[m + 1] : k_b[m + 1 - 16];
    pk[j2] = pack2bf(acc[j2 * 2] + b0, acc[j2 * 2 + 1] + b1);
  }
  *(uint4*)&qkT[((size_t)b * kN + n0 + tt) * 32 + og * 8] = make_uint4(pk[0], pk[1], pk[2], pk[3]);
}

// ---------------- MFMA GEMM: Y = W(bf16) . X(token-major), optional affine/GELU on X ----------------
// OUTMODE 0: fp32 token-major [n][M].
// OUTMODE 1: bf16 ch-major [m][n] + bias, with n KEY-PERMUTED (swap bits 2,3 of n)
//            so attention PV needs no cross-lane P exchange. Used ONLY for V.
template <int M, int K, int OUTMODE, bool AFFINE, bool GELU>
__global__ __launch_bounds__(256) void mfma_gemm_kernel(
    const ushort* __restrict__ Wb, const float* __restrict__ X,
    float* __restrict__ Yf, ushort* __restrict__ Yh, const float* __restrict__ bias,
    const float* __restrict__ insc, const float* __restrict__ inbi) {
  constexpr int BM = 128, BN = 128, BK = 64, LDW = 72;
  __shared__ ushort Wl[BM * LDW];
  __shared__ ushort Xl[BN * LDW];
  int b = blockIdx.z;
  int n0 = blockIdx.x * BN;
  int m0 = blockIdx.y * BM;
  int tid = threadIdx.x;
  int w = tid >> 6, lane = tid & 63;
  int wm = w >> 1, wn = w & 1;
  int lg = lane >> 4, lq = lane & 15;
  const float* Xb = X + (size_t)b * kN * K;
  f32x4 acc[4][4];
#pragma unroll
  for (int i = 0; i < 4; ++i)
#pragma unroll
    for (int j = 0; j < 4; ++j) acc[i][j] = (f32x4){0.f, 0.f, 0.f, 0.f};

  int wseg = tid & 7;
  int xseg = tid & 15;

  for (int kk = 0; kk < K; kk += BK) {
    __syncthreads();
#pragma unroll
    for (int u = 0; u < 4; ++u) {
      int row = (tid + u * 256) >> 3;
      short8v wv = *(const short8v*)&Wb[(size_t)(m0 + row) * K + kk + wseg * 8];
      *(short8v*)&Wl[row * LDW + wseg * 8] = wv;
    }
    float4 s4, t4;
    if (AFFINE) {
      s4 = *(const float4*)&insc[kk + xseg * 4];
      t4 = *(const float4*)&inbi[kk + xseg * 4];
    }
#pragma unroll
    for (int u = 0; u < 8; ++u) {
      int row = (tid + u * 256) >> 4;
      int n = n0 + row;
      float4 xv = make_float4(0.f, 0.f, 0.f, 0.f);
      if (n < kN) xv = *(const float4*)&Xb[(size_t)n * K + kk + xseg * 4];
      if (AFFINE) {
        xv.x = s4.x * xv.x + t4.x; xv.y = s4.y * xv.y + t4.y;
        xv.z = s4.z * xv.z + t4.z; xv.w = s4.w * xv.w + t4.w;
        if (GELU) {
          xv.x = gelu_exact(xv.x); xv.y = gelu_exact(xv.y);
          xv.z = gelu_exact(xv.z); xv.w = gelu_exact(xv.w);
        }
      }
      *(uint2*)&Xl[row * LDW + xseg * 4] =
          make_uint2(pack2bf(xv.x, xv.y), pack2bf(xv.z, xv.w));
    }
    __syncthreads();
#pragma unroll
    for (int kh = 0; kh < BK; kh += 32) {
      short8v af[4], bfr[4];
#pragma unroll
      for (int f = 0; f < 4; ++f) {
        af[f] = *(const short8v*)&Wl[(wm * 64 + f * 16 + lq) * LDW + kh + 8 * lg];
        bfr[f] = *(const short8v*)&Xl[(wn * 64 + f * 16 + lq) * LDW + kh + 8 * lg];
      }
#pragma unroll
      for (int fi = 0; fi < 4; ++fi)
#pragma unroll
        for (int fj = 0; fj < 4; ++fj)
          acc[fi][fj] = __builtin_amdgcn_mfma_f32_16x16x32_bf16(af[fi], bfr[fj], acc[fi][fj], 0, 0, 0);
    }
  }
  if (OUTMODE == 0) {
    float* Yb = Yf + (size_t)b * kN * M;
#pragma unroll
    for (int fj = 0; fj < 4; ++fj) {
      int n = n0 + wn * 64 + fj * 16 + lq;
      if (n < kN) {
#pragma unroll
        for (int fi = 0; fi < 4; ++fi)
          *(f32x4*)&Yb[(size_t)n * M + m0 + wm * 64 + fi * 16 + 4 * lg] = acc[fi][fj];
      }
    }
  } else {
    ushort* Yb = Yh + (size_t)b * M * kN;
#pragma unroll
    for (int fi = 0; fi < 4; ++fi) {
#pragma unroll
      for (int r = 0; r < 4; ++r) {
        int m = m0 + wm * 64 + fi * 16 + 4 * lg + r;
        float bv = bias ? bias[m] : 0.f;
#pragma unroll
        for (int fj = 0; fj < 4; ++fj) {
          int n = n0 + wn * 64 + fj * 16 + lq;
          if (n < kN) {
            // key-permutation: pos = n with bits 2,3 swapped
            int np = (n & ~12) | ((n & 4) << 1) | ((n & 8) >> 1);
            Yb[(size_t)m * kN + np] = f2bf(acc[fi][fj][r] + bv);
          }
        }
      }
    }
  }
}

// ---------------- 32x32x16 MFMA flash attention, barrier-free k-loop ----------------
// Block: 32 queries, 4 waves k-split. kf register-prefetched one iteration ahead.
// V stored key-permuted (bits 2,3 of key swapped) so the P B-frag is the natural
// per-lane cvt_pk order — NO cross-lane exchange in the PV path.
__global__ __launch_bounds__(256) void attn_mfma32_kernel(
    const ushort* __restrict__ qkT, const ushort* __restrict__ vb,
    const float* __restrict__ hfT, float* __restrict__ attT) {
  int b = blockIdx.x;                   // bid%8 = b -> one batch per XCD
  int n0 = blockIdx.y * 32;
  int tid = threadIdx.x;
  int w = tid >> 6;
  int lane = tid & 63;
  int l31 = lane & 31;
  int hi = lane >> 5;

  __shared__ float mbuf[4][32], lbuf[4][32], lfin[32];
  __shared__ float obuf[32][132];       // [q][c], padded

  const ushort* qkb = qkT + (size_t)b * kN * 32;
  const ushort* vbb = vb + (size_t)b * kC * kN;

  // Q B-frag: col=lane&31 -> query n0+l31, d = 8*hi + j  (k=16 exact, no padding)
  short8v qf = *(const short8v*)&qkb[(size_t)(n0 + l31) * 32 + 8 * hi];

  f32x16 z16 = {0.f,0.f,0.f,0.f,0.f,0.f,0.f,0.f,0.f,0.f,0.f,0.f,0.f,0.f,0.f,0.f};
  f32x16 acc[4];
#pragma unroll
  for (int cg = 0; cg < 4; ++cg) acc[cg] = z16;

  float m = -1e30f, l = 0.f;
  const ushort* vbase = vbb + (size_t)l31 * kN + 8 * hi;

  // prologue: K-frag for tile t=w
  short8v kf_cur = *(const short8v*)&qkb[(size_t)(w * 32 + l31) * 32 + 16 + 8 * hi];

  for (int t = w; t < 98; t += 4) {
    int k0 = t * 32;
    // V A-frags for current tile (both k-halves), issued at top: softmax covers latency
    short8v va[4], vb2[4];
#pragma unroll
    for (int cg = 0; cg < 4; ++cg) {
      const ushort* p = vbase + (size_t)cg * 32 * kN + k0;
      va[cg] = *(const short8v*)p;
      vb2[cg] = *(const short8v*)(p + 16);
    }
    // prefetch K-frag for tile t+4 (removes load->mfma adjacency next iter)
    int tn = t + 4;
    short8v kf_nxt = kf_cur;
    if (tn < 98)
      kf_nxt = *(const short8v*)&qkb[(size_t)(tn * 32 + l31) * 32 + 16 + 8 * hi];

    f32x16 s = __builtin_amdgcn_mfma_f32_32x32x16_bf16(kf_cur, qf, z16, 0, 0, 0);
    // lane: q = l31; reg r -> key = k0 + (r&3) + 8*(r>>2) + 4*hi

    float tmax = s[0];
#pragma unroll
    for (int i = 1; i < 16; ++i) tmax = fmaxf(tmax, s[i]);
    tmax = fmaxf(tmax, __shfl_xor(tmax, 32, 64));

    if (!__all(tmax <= m + 8.0f)) {       // T13 defer-max
      float mnew = fmaxf(m, tmax);
      float scl = __expf(m - mnew);
      l *= scl;
#pragma unroll
      for (int cg = 0; cg < 4; ++cg)
#pragma unroll
        for (int i = 0; i < 16; ++i) acc[cg][i] *= scl;
      m = mnew;
    }
    // exp fused with bf16 pair-pack; natural order IS the B-frag order (V permuted)
    uint wd[8];
    float ps = 0.f;
#pragma unroll
    for (int i = 0; i < 8; ++i) {
      float pl = __expf(s[2 * i] - m);
      float ph = __expf(s[2 * i + 1] - m);
      ps += pl + ph;
      asm("v_cvt_pk_bf16_f32 %0, %1, %2" : "=v"(wd[i]) : "v"(pl), "v"(ph));
    }
    ps += __shfl_xor(ps, 32, 64);
    l += ps;

    uint4v u1 = {wd[0], wd[1], wd[2], wd[3]};
    uint4v u2 = {wd[4], wd[5], wd[6], wd[7]};
    short8v P1 = __builtin_bit_cast(short8v, u1);
    short8v P2 = __builtin_bit_cast(short8v, u2);
#pragma unroll
    for (int cg = 0; cg < 4; ++cg) {
      acc[cg] = __builtin_amdgcn_mfma_f32_32x32x16_bf16(va[cg], P1, acc[cg], 0, 0, 0);
      acc[cg] = __builtin_amdgcn_mfma_f32_32x32x16_bf16(vb2[cg], P2, acc[cg], 0, 0, 0);
    }
    kf_cur = kf_nxt;
  }

  // ---- 4-way flash merge (once per block) ----
  if (lane < 32) { mbuf[w][lane] = m; lbuf[w][lane] = l; }
  __syncthreads();
  float M = -1e30f;
#pragma unroll
  for (int j = 0; j < 4; ++j) M = fmaxf(M, mbuf[j][l31]);
  float L = 0.f;
#pragma unroll
  for (int j = 0; j < 4; ++j) L += lbuf[j][l31] * __expf(mbuf[j][l31] - M);
  if (w == 0 && lane < 32) lfin[lane] = L;
  float f = __expf(m - M);

  for (int turn = 0; turn < 4; ++turn) {
    if (w == turn) {
#pragma unroll
      for (int cg = 0; cg < 4; ++cg)
#pragma unroll
        for (int rr = 0; rr < 4; ++rr) {
          int c = cg * 32 + 8 * rr + 4 * hi;
          float4 vv;
          vv.x = f * acc[cg][4 * rr + 0];
          vv.y = f * acc[cg][4 * rr + 1];
          vv.z = f * acc[cg][4 * rr + 2];
          vv.w = f * acc[cg][4 * rr + 3];
          if (turn == 0) {
            *(float4*)&obuf[l31][c] = vv;
          } else {
            float4 o = *(const float4*)&obuf[l31][c];
            o.x += vv.x; o.y += vv.y; o.z += vv.z; o.w += vv.w;
            *(float4*)&obuf[l31][c] = o;
          }
        }
    }
    __syncthreads();
  }

  // epilogue: O/L + residual (hfT token-major, coalesced), write attT [n][128]
  int q = tid >> 3;
  int cs = (tid & 7) * 16;
  float linv = 1.0f / lfin[q];
  size_t nidx = (size_t)b * kN + n0 + q;
  const float* hrow = &hfT[nidx * kC + cs];
  float* arow = &attT[nidx * kC + cs];
#pragma unroll
  for (int cc = 0; cc < 16; cc += 4) {
    float4 r = *(const float4*)&hrow[cc];
    float4 o;
    o.x = obuf[q][cs + cc + 0] * linv + r.x;
    o.y = obuf[q][cs + cc + 1] * linv + r.y;
    o.z = obuf[q][cs + cc + 2] * linv + r.z;
    o.w = obuf[q][cs + cc + 3] * linv + r.w;
    *(float4*)&arow[cc] = o;
  }
}

// ---------------- token-major BN stats: partials then finalize ----------------
template <int CH>
__global__ __launch_bounds__(256) void stats_tm_kernel(
    const float* __restrict__ X, float* __restrict__ psum, float* __restrict__ pssq) {
  constexpr int RPB = (kB * kN) / 256;  // 98
  int r0 = blockIdx.x * RPB;
  float s[CH / 256] = {}, q[CH / 256] = {};
  for (int r = r0; r < r0 + RPB; ++r) {
    const float* row = X + (size_t)r * CH;
#pragma unroll
    for (int cc = 0; cc < CH / 256; ++cc) {
      float v = row[threadIdx.x + cc * 256];
      s[cc] += v; q[cc] += v * v;
    }
  }
#pragma unroll
  for (int cc = 0; cc < CH / 256; ++cc) {
    psum[(size_t)blockIdx.x * CH + threadIdx.x + cc * 256] = s[cc];
    pssq[(size_t)blockIdx.x * CH + threadIdx.x + cc * 256] = q[cc];
  }
}

template <int CH>
__global__ __launch_bounds__(256) void bnfin_kernel(
    const float* __restrict__ psum, const float* __restrict__ pssq,
    const float* __restrict__ g, const float* __restrict__ bt,
    float* __restrict__ alpha, float* __restrict__ beta) {
  int ch = blockIdx.x * 256 + threadIdx.x;
  if (ch >= CH) return;
  float s = 0.f, q = 0.f;
  for (int p = 0; p < 256; ++p) { s += psum[(size_t)p * CH + ch]; q += pssq[(size_t)p * CH + ch]; }
  float inv = 1.0f / ((float)kB * (float)kN);
  float mean = s * inv;
  float var = q * inv - mean * mean;
  float a = g[ch] * rsqrtf(var + kEps);
  alpha[ch] = a;
  beta[ch] = bt[ch] - mean * a;
}

// ---------------- final BN apply + transpose [n][256] -> out [b][256][n] ----------------
__global__ __launch_bounds__(256) void bnout_t_kernel(
    const float* __restrict__ X, const float* __restrict__ alpha,
    const float* __restrict__ beta, float* __restrict__ out) {
  __shared__ float T[32][33];
  int b = blockIdx.z;
  int c0 = blockIdx.y * 32;
  int n0 = blockIdx.x * 32;
  int tid = threadIdx.x;
  int r = tid >> 3, seg = tid & 7;
  float4 v = *(const float4*)&X[((size_t)b * kN + n0 + r) * kO + c0 + seg * 4];
  float4 a = *(const float4*)&alpha[c0 + seg * 4];
  float4 bb = *(const float4*)&beta[c0 + seg * 4];
  v.x = a.x * v.x + bb.x; v.y = a.y * v.y + bb.y;
  v.z = a.z * v.z + bb.z; v.w = a.w * v.w + bb.w;
  T[seg * 4 + 0][r] = v.x; T[seg * 4 + 1][r] = v.y;
  T[seg * 4 + 2][r] = v.z; T[seg * 4 + 3][r] = v.w;
  __syncthreads();
  float4 o = make_float4(T[r][seg * 4], T[r][seg * 4 + 1], T[r][seg * 4 + 2], T[r][seg * 4 + 3]);
  *(float4*)&out[((size_t)b * kO + c0 + r) * kN + n0 + seg * 4] = o;
}

}  // namespace

extern "C" void kernel_launch(void* const* d_in, const int* in_sizes, int n_in,
                              void* d_out, int out_size, void* d_ws, size_t ws_size,
                              hipStream_t stream) {
  const float* x     = (const float*)d_in[0];
  const float* dw_w  = (const float*)d_in[1];
  const float* bn1_g = (const float*)d_in[2];
  const float* bn1_b = (const float*)d_in[3];
  const float* se_w1 = (const float*)d_in[4];
  const float* se_b1 = (const float*)d_in[5];
  const float* se_w2 = (const float*)d_in[6];
  const float* se_b2 = (const float*)d_in[7];
  const float* q_w   = (const float*)d_in[8];
  const float* q_b   = (const float*)d_in[9];
  const float* k_w   = (const float*)d_in[10];
  const float* k_b   = (const float*)d_in[11];
  const float* v_w   = (const float*)d_in[12];
  const float* v_b   = (const float*)d_in[13];
  const float* pw_w  = (const float*)d_in[14];
  const float* bn2_g = (const float*)d_in[15];
  const float* bn2_b = (const float*)d_in[16];
  const float* m1_w  = (const float*)d_in[17];
  const float* bn3_g = (const float*)d_in[18];
  const float* bn3_b = (const float*)d_in[19];
  const float* m2_w  = (const float*)d_in[20];
  const float* bn4_g = (const float*)d_in[21];
  const float* bn4_b = (const float*)d_in[22];
  float* out = (float*)d_out;
  float* ws = (float*)d_ws;

  const size_t BCN = (size_t)kB * kC * kN;   // 3,211,264 floats

  // fp32 buffers
  float* h0    = ws;                 // [0, BCN)      dead after scale_tm
  float* hfT32 = ws + 2 * BCN;       // [2BCN, 3BCN)  dead after attn (residual source)
  float* attT  = ws + 3 * BCN;       // [3BCN, 4BCN)  dead after pw
  float* p_tm  = ws + 4 * BCN;       // [4BCN, 6BCN)  dead after m1
  float* m1o   = ws;                 // [0, 4BCN)     (all prior dead)
  float* m2o   = ws + 4 * BCN;       // [4BCN, 6BCN)  (p_tm dead)
  // bf16 buffers inside dead-h0 region
  ushort* vb16  = (ushort*)ws;                         // BCN elems
  ushort* qkT16 = (ushort*)(ws + BCN / 2);             // kB*kN*32 elems
  // weights bf16 + partials + small arrays at [6BCN, ...)
  ushort* wv16  = (ushort*)(ws + 6 * BCN);
  ushort* wpw16 = wv16 + 128 * 128;
  ushort* wm116 = wpw16 + 256 * 128;
  ushort* wm216 = wm116 + 512 * 256;
  float* psum = ws + 6 * BCN + 155648;                 // 256*512
  float* pssq = psum + 131072;
  float* smal = pssq + 131072;
  float* sums  = smal;
  float* ssqs  = smal + 1024;
  float* sc_bc = smal + 2048;
  float* bi_bc = smal + 3072;
  float* a2 = smal + 4096; float* b2 = a2 + kO;
  float* a3 = b2 + kO;     float* b3 = a3 + kHd;
  float* a4 = b3 + kHd;    float* b4 = a4 + kO;

  // 0. weight conversion (independent)
  wconv_kernel<<<512, 256, 0, stream>>>(v_w, pw_w, m1_w, m2_w, wv16, wpw16, wm116, wm216);
  // 1. depthwise conv + BN1 partial stats
  dwconv_kernel<<<kB * kC, 256, 0, stream>>>(x, dw_w, h0, sums, ssqs);
  // 2. BN1 finalize + SE
  se_kernel<<<kB, 128, 0, stream>>>(sums, ssqs, bn1_g, bn1_b, se_w1, se_b1, se_w2, se_b2,
                                    sc_bc, bi_bc);
  // 3. hfT32 (token-major)
  scale_tm_kernel<<<dim3(98, 4, kB), 256, 0, stream>>>(h0, sc_bc, bi_bc, hfT32);
  // 4. q,k -> bf16 token-major [n][32]
  qk_kernel<<<dim3(49, kB), 256, 0, stream>>>(hfT32, q_w, q_b, k_w, k_b, qkT16);
  // 5. v -> bf16 ch-major, key-permuted (MFMA)
  mfma_gemm_kernel<128, 128, 1, false, false><<<dim3(25, 1, kB), 256, 0, stream>>>(
      wv16, hfT32, nullptr, vb16, v_b, nullptr, nullptr);
  // 6. attention + residual -> attT (token-major fp32)
  attn_mfma32_kernel<<<dim3(kB, kN / 32), 256, 0, stream>>>(qkT16, vb16, hfT32, attT);
  // 7. pw -> p_tm fp32 [n][256]
  mfma_gemm_kernel<256, 128, 0, false, false><<<dim3(25, 2, kB), 256, 0, stream>>>(
      wpw16, attT, p_tm, nullptr, nullptr, nullptr, nullptr);
  // 8. BN2 stats
  stats_tm_kernel<256><<<256, 256, 0, stream>>>(p_tm, psum, pssq);
  bnfin_kernel<256><<<1, 256, 0, stream>>>(psum, pssq, bn2_g, bn2_b, a2, b2);
  // 9. m1 (BN2 affine folded into staging) -> m1o fp32 [n][512]
  mfma_gemm_kernel<512, 256, 0, true, false><<<dim3(25, 4, kB), 256, 0, stream>>>(
      wm116, p_tm, m1o, nullptr, nullptr, a2, b2);
  // 10. BN3 stats
  stats_tm_kernel<512><<<256, 256, 0, stream>>>(m1o, psum, pssq);
  bnfin_kernel<512><<<2, 256, 0, stream>>>(psum, pssq, bn3_g, bn3_b, a3, b3);
  // 11. m2 (BN3 affine + exact GELU folded into staging) -> m2o fp32 [n][256]
  mfma_gemm_kernel<256, 512, 0, true, true><<<dim3(25, 2, kB), 256, 0, stream>>>(
      wm216, m1o, m2o, nullptr, nullptr, a3, b3);
  // 12. BN4 stats + apply (with transpose to ch-major output)
  stats_tm_kernel<256><<<256, 256, 0, stream>>>(m2o, psum, pssq);
  bnfin_kernel<256><<<1, 256, 0, stream>>>(psum, pssq, bn4_g, bn4_b, a4, b4);
  bnout_t_kernel<<<dim3(98, 8, kB), 256, 0, stream>>>(m2o, a4, b4, out);
}

// Round 8
// 315.876 us; speedup vs baseline: 3.8558x; 1.1449x over previous
//
#include <hip/hip_runtime.h>
#include <math.h>

namespace {

constexpr int kB = 8;
constexpr int kC = 128;
constexpr int kHin = 112, kWin = 112;
constexpr int kHout = 56, kWout = 56;
constexpr int kN = kHout * kWout;     // 3136
constexpr int kO = 256;
constexpr int kHd = 512;
constexpr int kQd = 16;
constexpr int kR = 32;
constexpr float kEps = 1e-5f;

typedef __attribute__((ext_vector_type(8))) short short8v;
typedef __attribute__((ext_vector_type(4))) float f32x4;
typedef __attribute__((ext_vector_type(16))) float f32x16;
typedef __attribute__((ext_vector_type(4))) uint uint4v;

__device__ __forceinline__ float gelu_exact(float x) {
  return 0.5f * x * (1.0f + erff(x * 0.70710678118654752f));
}

__device__ __forceinline__ ushort f2bf(float f) {
  uint u = __float_as_uint(f);
  uint r = (u + 0x7FFFu + ((u >> 16) & 1u)) >> 16;
  return (ushort)r;
}
__device__ __forceinline__ uint pack2bf(float a, float b) {
  return (uint)f2bf(a) | ((uint)f2bf(b) << 16);
}

// ---------------- depthwise conv 3x3 stride2 pad1 + per-(b,c) sum/sumsq ----------------
__global__ __launch_bounds__(256) void dwconv_kernel(
    const float* __restrict__ x, const float* __restrict__ w,
    float* __restrict__ h0, float* __restrict__ sums, float* __restrict__ ssqs) {
  int bc = blockIdx.x;
  int c = bc % kC;
  const float* xp = x + (size_t)bc * (kHin * kWin);
  float wr[9];
#pragma unroll
  for (int i = 0; i < 9; ++i) wr[i] = w[c * 9 + i];
  float lsum = 0.f, lssq = 0.f;
  for (int i = threadIdx.x; i < kN; i += 256) {
    int oy = i / kWout, ox = i - oy * kWout;
    int iy0 = 2 * oy - 1, ix0 = 2 * ox - 1;
    float acc = 0.f;
#pragma unroll
    for (int ky = 0; ky < 3; ++ky) {
      int iy = iy0 + ky;
      if (iy < 0 || iy >= kHin) continue;
#pragma unroll
      for (int kx = 0; kx < 3; ++kx) {
        int ix = ix0 + kx;
        if (ix < 0 || ix >= kWin) continue;
        acc += xp[iy * kWin + ix] * wr[ky * 3 + kx];
      }
    }
    h0[(size_t)bc * kN + i] = acc;
    lsum += acc;
    lssq += acc * acc;
  }
  __shared__ float rs[256], rq[256];
  rs[threadIdx.x] = lsum; rq[threadIdx.x] = lssq;
  __syncthreads();
  for (int s = 128; s > 0; s >>= 1) {
    if (threadIdx.x < s) { rs[threadIdx.x] += rs[threadIdx.x + s]; rq[threadIdx.x] += rq[threadIdx.x + s]; }
    __syncthreads();
  }
  if (threadIdx.x == 0) { sums[bc] = rs[0]; ssqs[bc] = rq[0]; }
}

// ---------------- BN1 stats + SE MLP -> per-(b,c) scale/bias ----------------
__global__ __launch_bounds__(128) void se_kernel(
    const float* __restrict__ sums, const float* __restrict__ ssqs,
    const float* __restrict__ bn1_g, const float* __restrict__ bn1_b,
    const float* __restrict__ se_w1, const float* __restrict__ se_b1,
    const float* __restrict__ se_w2, const float* __restrict__ se_b2,
    float* __restrict__ scale_bc, float* __restrict__ bias_bc) {
  int b = blockIdx.x, c = threadIdx.x;
  __shared__ float sin_[kC], s1[kR], alf[kC], bet[kC];
  float ts = 0.f, tq = 0.f;
  for (int bb = 0; bb < kB; ++bb) { ts += sums[bb * kC + c]; tq += ssqs[bb * kC + c]; }
  float inv = 1.0f / ((float)kB * (float)kN);
  float mean = ts * inv;
  float var = tq * inv - mean * mean;
  float a = bn1_g[c] * rsqrtf(var + kEps);
  float be = bn1_b[c] - mean * a;
  alf[c] = a; bet[c] = be;
  sin_[c] = a * (sums[b * kC + c] * (1.0f / kN)) + be;
  __syncthreads();
  if (c < kR) {
    float acc = se_b1[c];
    for (int j = 0; j < kC; ++j) acc += se_w1[c * kC + j] * sin_[j];
    s1[c] = fmaxf(acc, 0.f);
  }
  __syncthreads();
  float acc = se_b2[c];
  for (int j = 0; j < kR; ++j) acc += se_w2[c * kR + j] * s1[j];
  float sg = 1.0f / (1.0f + expf(-acc));
  scale_bc[b * kC + c] = alf[c] * sg;
  bias_bc[b * kC + c] = bet[c] * sg;
}

// ---------------- hfT (token-major fp32) = transpose(scale*h0+bias) ----------------
__global__ __launch_bounds__(256) void scale_tm_kernel(
    const float* __restrict__ h0, const float* __restrict__ sc,
    const float* __restrict__ bi, float* __restrict__ hfT) {
  __shared__ float T[32][33];
  int b = blockIdx.z;
  int c0 = blockIdx.y * 32;
  int n0 = blockIdx.x * 32;
  int tid = threadIdx.x;
  int r = tid >> 3, seg = tid & 7;
  int c = c0 + r;
  int bc = b * kC + c;
  float s = sc[bc], t = bi[bc];
  size_t idx = (size_t)bc * kN + n0 + seg * 4;
  float4 v = *(const float4*)&h0[idx];
  v.x = s * v.x + t; v.y = s * v.y + t; v.z = s * v.z + t; v.w = s * v.w + t;
  T[seg * 4 + 0][r] = v.x; T[seg * 4 + 1][r] = v.y;
  T[seg * 4 + 2][r] = v.z; T[seg * 4 + 3][r] = v.w;
  __syncthreads();
  float4 o = make_float4(T[r][seg * 4], T[r][seg * 4 + 1], T[r][seg * 4 + 2], T[r][seg * 4 + 3]);
  *(float4*)&hfT[((size_t)b * kN + n0 + r) * kC + c0 + seg * 4] = o;
}

// ---------------- weights fp32 -> bf16 ----------------
__global__ void wconv_kernel(const float* __restrict__ vw, const float* __restrict__ pww,
                             const float* __restrict__ m1w, const float* __restrict__ m2w,
                             ushort* __restrict__ ov, ushort* __restrict__ opw,
                             ushort* __restrict__ om1, ushort* __restrict__ om2) {
  int stride = gridDim.x * 256;
  int i0 = blockIdx.x * 256 + threadIdx.x;
  for (int i = i0; i < 128 * 128; i += stride) ov[i] = f2bf(vw[i]);
  for (int i = i0; i < 256 * 128; i += stride) opw[i] = f2bf(pww[i]);
  for (int i = i0; i < 512 * 256; i += stride) om1[i] = f2bf(m1w[i]);
  for (int i = i0; i < 256 * 512; i += stride) om2[i] = f2bf(m2w[i]);
}

// ---------------- q,k projection -> MFMA-fragment-tiled bf16 qA/kA [t][hi][32][8] ----------------
__global__ __launch_bounds__(256) void qk_kernel(
    const float* __restrict__ hfT, const float* __restrict__ q_w,
    const float* __restrict__ q_b, const float* __restrict__ k_w,
    const float* __restrict__ k_b, ushort* __restrict__ qA, ushort* __restrict__ kA) {
  __shared__ float Wl[32][128];
  __shared__ float Xl[64][129];
  int b = blockIdx.y;
  int n0 = blockIdx.x * 64;
  int tid = threadIdx.x;
  for (int u = tid; u < 1024; u += 256) {
    int r = u >> 5, seg = u & 31;
    const float* src = (r < 16) ? &q_w[r * 128 + seg * 4] : &k_w[(r - 16) * 128 + seg * 4];
    float4 v = *(const float4*)src;
    *(float4*)&Wl[r][seg * 4] = v;
  }
  const float* Xb = hfT + ((size_t)b * kN + n0) * kC;
  for (int u = tid; u < 2048; u += 256) {
    int r = u >> 5, seg = u & 31;
    float4 v = *(const float4*)&Xb[(size_t)r * kC + seg * 4];
    Xl[r][seg * 4 + 0] = v.x; Xl[r][seg * 4 + 1] = v.y;
    Xl[r][seg * 4 + 2] = v.z; Xl[r][seg * 4 + 3] = v.w;
  }
  __syncthreads();
  int tt = tid & 63, og = tid >> 6;
  float acc[8] = {};
  for (int k = 0; k < 128; ++k) {
    float xx = Xl[tt][k];
#pragma unroll
    for (int j = 0; j < 8; ++j) acc[j] += xx * Wl[og * 8 + j][k];
  }
  uint pk[4];
#pragma unroll
  for (int j2 = 0; j2 < 4; ++j2) {
    int m = og * 8 + j2 * 2;
    float b0 = (m < 16) ? q_b[m] : k_b[m - 16];
    float b1 = (m + 1 < 16) ? q_b[m + 1] : k_b[m + 1 - 16];
    pk[j2] = pack2bf(acc[j2 * 2] + b0, acc[j2 * 2 + 1] + b1);
  }
  // dims og*8..og*8+7 = (q if og<2 else k), chunk h = og&1
  int n = n0 + tt;
  int t = n >> 5, r = n & 31, h = og & 1;
  ushort* dst = (og < 2 ? qA : kA) + (size_t)b * kN * 16 + (((size_t)t * 2 + h) * 32 + r) * 8;
  *(uint4*)dst = make_uint4(pk[0], pk[1], pk[2], pk[3]);
}

// ---------------- MFMA GEMM: Y = W(bf16) . X(token-major), optional affine/GELU on X ----------------
// OUTMODE 0: fp32 token-major [n][M].
// OUTMODE 1 (V only): bf16 fragment-tiled vA[t][chunk][128][8]; within-tile key nl is
//   stored at position swap-bits-2-3(nl) so attention PV needs no cross-lane P exchange.
template <int M, int K, int OUTMODE, bool AFFINE, bool GELU>
__global__ __launch_bounds__(256) void mfma_gemm_kernel(
    const ushort* __restrict__ Wb, const float* __restrict__ X,
    float* __restrict__ Yf, ushort* __restrict__ Yh, const float* __restrict__ bias,
    const float* __restrict__ insc, const float* __restrict__ inbi) {
  constexpr int BM = 128, BN = 128, BK = 64, LDW = 72;
  __shared__ ushort Wl[BM * LDW];
  __shared__ ushort Xl[BN * LDW];
  int b = blockIdx.z;
  int n0 = blockIdx.x * BN;
  int m0 = blockIdx.y * BM;
  int tid = threadIdx.x;
  int w = tid >> 6, lane = tid & 63;
  int wm = w >> 1, wn = w & 1;
  int lg = lane >> 4, lq = lane & 15;
  const float* Xb = X + (size_t)b * kN * K;
  f32x4 acc[4][4];
#pragma unroll
  for (int i = 0; i < 4; ++i)
#pragma unroll
    for (int j = 0; j < 4; ++j) acc[i][j] = (f32x4){0.f, 0.f, 0.f, 0.f};

  int wseg = tid & 7;
  int xseg = tid & 15;

  for (int kk = 0; kk < K; kk += BK) {
    __syncthreads();
#pragma unroll
    for (int u = 0; u < 4; ++u) {
      int row = (tid + u * 256) >> 3;
      short8v wv = *(const short8v*)&Wb[(size_t)(m0 + row) * K + kk + wseg * 8];
      *(short8v*)&Wl[row * LDW + wseg * 8] = wv;
    }
    float4 s4, t4;
    if (AFFINE) {
      s4 = *(const float4*)&insc[kk + xseg * 4];
      t4 = *(const float4*)&inbi[kk + xseg * 4];
    }
#pragma unroll
    for (int u = 0; u < 8; ++u) {
      int row = (tid + u * 256) >> 4;
      int n = n0 + row;
      float4 xv = make_float4(0.f, 0.f, 0.f, 0.f);
      if (n < kN) xv = *(const float4*)&Xb[(size_t)n * K + kk + xseg * 4];
      if (AFFINE) {
        xv.x = s4.x * xv.x + t4.x; xv.y = s4.y * xv.y + t4.y;
        xv.z = s4.z * xv.z + t4.z; xv.w = s4.w * xv.w + t4.w;
        if (GELU) {
          xv.x = gelu_exact(xv.x); xv.y = gelu_exact(xv.y);
          xv.z = gelu_exact(xv.z); xv.w = gelu_exact(xv.w);
        }
      }
      *(uint2*)&Xl[row * LDW + xseg * 4] =
          make_uint2(pack2bf(xv.x, xv.y), pack2bf(xv.z, xv.w));
    }
    __syncthreads();
#pragma unroll
    for (int kh = 0; kh < BK; kh += 32) {
      short8v af[4], bfr[4];
#pragma unroll
      for (int f = 0; f < 4; ++f) {
        af[f] = *(const short8v*)&Wl[(wm * 64 + f * 16 + lq) * LDW + kh + 8 * lg];
        bfr[f] = *(const short8v*)&Xl[(wn * 64 + f * 16 + lq) * LDW + kh + 8 * lg];
      }
#pragma unroll
      for (int fi = 0; fi < 4; ++fi)
#pragma unroll
        for (int fj = 0; fj < 4; ++fj)
          acc[fi][fj] = __builtin_amdgcn_mfma_f32_16x16x32_bf16(af[fi], bfr[fj], acc[fi][fj], 0, 0, 0);
    }
  }
  if (OUTMODE == 0) {
    float* Yb = Yf + (size_t)b * kN * M;
#pragma unroll
    for (int fj = 0; fj < 4; ++fj) {
      int n = n0 + wn * 64 + fj * 16 + lq;
      if (n < kN) {
#pragma unroll
        for (int fi = 0; fi < 4; ++fi)
          *(f32x4*)&Yb[(size_t)n * M + m0 + wm * 64 + fi * 16 + 4 * lg] = acc[fi][fj];
      }
    }
  } else {
    ushort* Yb = Yh + (size_t)b * M * kN;   // vA [98][4][128][8]
#pragma unroll
    for (int fi = 0; fi < 4; ++fi) {
#pragma unroll
      for (int r = 0; r < 4; ++r) {
        int m = m0 + wm * 64 + fi * 16 + 4 * lg + r;
        float bv = bias ? bias[m] : 0.f;
#pragma unroll
        for (int fj = 0; fj < 4; ++fj) {
          int n = n0 + wn * 64 + fj * 16 + lq;
          if (n < kN) {
            int t = n >> 5, nl = n & 31;
            int pp = (nl & ~12) | ((nl & 4) << 1) | ((nl & 8) >> 1);  // swap bits 2,3
            Yb[(((size_t)t * 4 + (pp >> 3)) * 128 + m) * 8 + (pp & 7)] =
                f2bf(acc[fi][fj][r] + bv);
          }
        }
      }
    }
  }
}

// ---------------- 32x32x16 MFMA flash attention, barrier-free k-loop ----------------
// Block: 32 queries, 4 waves k-split. All operands pre-tiled in MFMA fragment order:
// every global load is dense (two 512B segments), no gathers, no cross-lane P exchange.
__global__ __launch_bounds__(256) void attn_mfma32_kernel(
    const ushort* __restrict__ qA, const ushort* __restrict__ kA,
    const ushort* __restrict__ vA, const float* __restrict__ hfT,
    float* __restrict__ attT) {
  int b = blockIdx.x;                   // bid%8 = b -> one batch per XCD
  int n0 = blockIdx.y * 32;
  int tid = threadIdx.x;
  int w = tid >> 6;
  int lane = tid & 63;
  int l31 = lane & 31;
  int hi = lane >> 5;

  __shared__ float mbuf[4][32], lbuf[4][32], lfin[32];
  __shared__ float obuf[32][132];       // [q][c], padded

  const ushort* qAb = qA + (size_t)b * kN * 16;
  const ushort* kAb = kA + (size_t)b * kN * 16;
  const ushort* vAb = vA + (size_t)b * kN * 128;

  // Q B-frag (dense): qA[t=by][hi][l31][8]
  short8v qf = *(const short8v*)&qAb[(((size_t)blockIdx.y * 2 + hi) * 32 + l31) * 8];

  f32x16 z16 = {0.f,0.f,0.f,0.f,0.f,0.f,0.f,0.f,0.f,0.f,0.f,0.f,0.f,0.f,0.f,0.f};
  f32x16 acc[4];
#pragma unroll
  for (int cg = 0; cg < 4; ++cg) acc[cg] = z16;

  float m = -1e30f, l = 0.f;

  // prologue: K-frag for tile t=w (dense)
  short8v kf_cur = *(const short8v*)&kAb[(((size_t)w * 2 + hi) * 32 + l31) * 8];

  for (int t = w; t < 98; t += 4) {
    // V A-frags for current tile (dense 512B segments), issued at top
    const ushort* vt = vAb + (size_t)t * 4 * 128 * 8;
    short8v va[4], vb2[4];
#pragma unroll
    for (int cg = 0; cg < 4; ++cg) {
      va[cg]  = *(const short8v*)&vt[((size_t)hi * 128 + cg * 32 + l31) * 8];
      vb2[cg] = *(const short8v*)&vt[(((size_t)(2 + hi)) * 128 + cg * 32 + l31) * 8];
    }
    // prefetch K-frag for tile t+4
    int tn = t + 4;
    short8v kf_nxt = kf_cur;
    if (tn < 98)
      kf_nxt = *(const short8v*)&kAb[(((size_t)tn * 2 + hi) * 32 + l31) * 8];

    f32x16 s = __builtin_amdgcn_mfma_f32_32x32x16_bf16(kf_cur, qf, z16, 0, 0, 0);

    float tmax = s[0];
#pragma unroll
    for (int i = 1; i < 16; ++i) tmax = fmaxf(tmax, s[i]);
    tmax = fmaxf(tmax, __shfl_xor(tmax, 32, 64));

    if (!__all(tmax <= m + 8.0f)) {       // T13 defer-max
      float mnew = fmaxf(m, tmax);
      float scl = __expf(m - mnew);
      l *= scl;
#pragma unroll
      for (int cg = 0; cg < 4; ++cg)
#pragma unroll
        for (int i = 0; i < 16; ++i) acc[cg][i] *= scl;
      m = mnew;
    }
    // exp fused with bf16 pair-pack; natural order IS the B-frag order (V position-permuted)
    uint wd[8];
    float ps = 0.f;
#pragma unroll
    for (int i = 0; i < 8; ++i) {
      float pl = __expf(s[2 * i] - m);
      float ph = __expf(s[2 * i + 1] - m);
      ps += pl + ph;
      asm("v_cvt_pk_bf16_f32 %0, %1, %2" : "=v"(wd[i]) : "v"(pl), "v"(ph));
    }
    ps += __shfl_xor(ps, 32, 64);
    l += ps;

    uint4v u1 = {wd[0], wd[1], wd[2], wd[3]};
    uint4v u2 = {wd[4], wd[5], wd[6], wd[7]};
    short8v P1 = __builtin_bit_cast(short8v, u1);
    short8v P2 = __builtin_bit_cast(short8v, u2);
#pragma unroll
    for (int cg = 0; cg < 4; ++cg) {
      acc[cg] = __builtin_amdgcn_mfma_f32_32x32x16_bf16(va[cg], P1, acc[cg], 0, 0, 0);
      acc[cg] = __builtin_amdgcn_mfma_f32_32x32x16_bf16(vb2[cg], P2, acc[cg], 0, 0, 0);
    }
    kf_cur = kf_nxt;
  }

  // ---- 4-way flash merge (once per block) ----
  if (lane < 32) { mbuf[w][lane] = m; lbuf[w][lane] = l; }
  __syncthreads();
  float M = -1e30f;
#pragma unroll
  for (int j = 0; j < 4; ++j) M = fmaxf(M, mbuf[j][l31]);
  float L = 0.f;
#pragma unroll
  for (int j = 0; j < 4; ++j) L += lbuf[j][l31] * __expf(mbuf[j][l31] - M);
  if (w == 0 && lane < 32) lfin[lane] = L;
  float f = __expf(m - M);

  for (int turn = 0; turn < 4; ++turn) {
    if (w == turn) {
#pragma unroll
      for (int cg = 0; cg < 4; ++cg)
#pragma unroll
        for (int rr = 0; rr < 4; ++rr) {
          int c = cg * 32 + 8 * rr + 4 * hi;
          float4 vv;
          vv.x = f * acc[cg][4 * rr + 0];
          vv.y = f * acc[cg][4 * rr + 1];
          vv.z = f * acc[cg][4 * rr + 2];
          vv.w = f * acc[cg][4 * rr + 3];
          if (turn == 0) {
            *(float4*)&obuf[l31][c] = vv;
          } else {
            float4 o = *(const float4*)&obuf[l31][c];
            o.x += vv.x; o.y += vv.y; o.z += vv.z; o.w += vv.w;
            *(float4*)&obuf[l31][c] = o;
          }
        }
    }
    __syncthreads();
  }

  // epilogue: O/L + residual (hfT token-major, coalesced), write attT [n][128]
  int q = tid >> 3;
  int cs = (tid & 7) * 16;
  float linv = 1.0f / lfin[q];
  size_t nidx = (size_t)b * kN + n0 + q;
  const float* hrow = &hfT[nidx * kC + cs];
  float* arow = &attT[nidx * kC + cs];
#pragma unroll
  for (int cc = 0; cc < 16; cc += 4) {
    float4 r = *(const float4*)&hrow[cc];
    float4 o;
    o.x = obuf[q][cs + cc + 0] * linv + r.x;
    o.y = obuf[q][cs + cc + 1] * linv + r.y;
    o.z = obuf[q][cs + cc + 2] * linv + r.z;
    o.w = obuf[q][cs + cc + 3] * linv + r.w;
    *(float4*)&arow[cc] = o;
  }
}

// ---------------- token-major BN stats: partials then finalize ----------------
template <int CH>
__global__ __launch_bounds__(256) void stats_tm_kernel(
    const float* __restrict__ X, float* __restrict__ psum, float* __restrict__ pssq) {
  constexpr int RPB = (kB * kN) / 256;  // 98
  int r0 = blockIdx.x * RPB;
  float s[CH / 256] = {}, q[CH / 256] = {};
  for (int r = r0; r < r0 + RPB; ++r) {
    const float* row = X + (size_t)r * CH;
#pragma unroll
    for (int cc = 0; cc < CH / 256; ++cc) {
      float v = row[threadIdx.x + cc * 256];
      s[cc] += v; q[cc] += v * v;
    }
  }
#pragma unroll
  for (int cc = 0; cc < CH / 256; ++cc) {
    psum[(size_t)blockIdx.x * CH + threadIdx.x + cc * 256] = s[cc];
    pssq[(size_t)blockIdx.x * CH + threadIdx.x + cc * 256] = q[cc];
  }
}

template <int CH>
__global__ __launch_bounds__(256) void bnfin_kernel(
    const float* __restrict__ psum, const float* __restrict__ pssq,
    const float* __restrict__ g, const float* __restrict__ bt,
    float* __restrict__ alpha, float* __restrict__ beta) {
  int ch = blockIdx.x * 256 + threadIdx.x;
  if (ch >= CH) return;
  float s = 0.f, q = 0.f;
  for (int p = 0; p < 256; ++p) { s += psum[(size_t)p * CH + ch]; q += pssq[(size_t)p * CH + ch]; }
  float inv = 1.0f / ((float)kB * (float)kN);
  float mean = s * inv;
  float var = q * inv - mean * mean;
  float a = g[ch] * rsqrtf(var + kEps);
  alpha[ch] = a;
  beta[ch] = bt[ch] - mean * a;
}

// ---------------- final BN apply + transpose [n][256] -> out [b][256][n] ----------------
__global__ __launch_bounds__(256) void bnout_t_kernel(
    const float* __restrict__ X, const float* __restrict__ alpha,
    const float* __restrict__ beta, float* __restrict__ out) {
  __shared__ float T[32][33];
  int b = blockIdx.z;
  int c0 = blockIdx.y * 32;
  int n0 = blockIdx.x * 32;
  int tid = threadIdx.x;
  int r = tid >> 3, seg = tid & 7;
  float4 v = *(const float4*)&X[((size_t)b * kN + n0 + r) * kO + c0 + seg * 4];
  float4 a = *(const float4*)&alpha[c0 + seg * 4];
  float4 bb = *(const float4*)&beta[c0 + seg * 4];
  v.x = a.x * v.x + bb.x; v.y = a.y * v.y + bb.y;
  v.z = a.z * v.z + bb.z; v.w = a.w * v.w + bb.w;
  T[seg * 4 + 0][r] = v.x; T[seg * 4 + 1][r] = v.y;
  T[seg * 4 + 2][r] = v.z; T[seg * 4 + 3][r] = v.w;
  __syncthreads();
  float4 o = make_float4(T[r][seg * 4], T[r][seg * 4 + 1], T[r][seg * 4 + 2], T[r][seg * 4 + 3]);
  *(float4*)&out[((size_t)b * kO + c0 + r) * kN + n0 + seg * 4] = o;
}

}  // namespace

extern "C" void kernel_launch(void* const* d_in, const int* in_sizes, int n_in,
                              void* d_out, int out_size, void* d_ws, size_t ws_size,
                              hipStream_t stream) {
  const float* x     = (const float*)d_in[0];
  const float* dw_w  = (const float*)d_in[1];
  const float* bn1_g = (const float*)d_in[2];
  const float* bn1_b = (const float*)d_in[3];
  const float* se_w1 = (const float*)d_in[4];
  const float* se_b1 = (const float*)d_in[5];
  const float* se_w2 = (const float*)d_in[6];
  const float* se_b2 = (const float*)d_in[7];
  const float* q_w   = (const float*)d_in[8];
  const float* q_b   = (const float*)d_in[9];
  const float* k_w   = (const float*)d_in[10];
  const float* k_b   = (const float*)d_in[11];
  const float* v_w   = (const float*)d_in[12];
  const float* v_b   = (const float*)d_in[13];
  const float* pw_w  = (const float*)d_in[14];
  const float* bn2_g = (const float*)d_in[15];
  const float* bn2_b = (const float*)d_in[16];
  const float* m1_w  = (const float*)d_in[17];
  const float* bn3_g = (const float*)d_in[18];
  const float* bn3_b = (const float*)d_in[19];
  const float* m2_w  = (const float*)d_in[20];
  const float* bn4_g = (const float*)d_in[21];
  const float* bn4_b = (const float*)d_in[22];
  float* out = (float*)d_out;
  float* ws = (float*)d_ws;

  const size_t BCN = (size_t)kB * kC * kN;   // 3,211,264 floats

  // fp32 buffers
  float* h0    = ws;                 // [0, BCN)      dead after scale_tm
  float* hfT32 = ws + 2 * BCN;       // [2BCN, 3BCN)  dead after attn (residual source)
  float* attT  = ws + 3 * BCN;       // [3BCN, 4BCN)  dead after pw
  float* p_tm  = ws + 4 * BCN;       // [4BCN, 6BCN)  dead after m1
  float* m1o   = ws;                 // [0, 4BCN)     (all prior dead)
  float* m2o   = ws + 4 * BCN;       // [4BCN, 6BCN)  (p_tm dead)
  // bf16 buffers inside dead-h0 region [0, BCN):
  ushort* vA16 = (ushort*)ws;                          // kB*kN*128 elems (6.4 MB)
  ushort* qA16 = (ushort*)(ws + BCN / 2);              // kB*kN*16 elems
  ushort* kA16 = qA16 + (size_t)kB * kN * 16;          // kB*kN*16 elems
  // weights bf16 + partials + small arrays at [6BCN, ...)
  ushort* wv16  = (ushort*)(ws + 6 * BCN);
  ushort* wpw16 = wv16 + 128 * 128;
  ushort* wm116 = wpw16 + 256 * 128;
  ushort* wm216 = wm116 + 512 * 256;
  float* psum = ws + 6 * BCN + 155648;                 // 256*512
  float* pssq = psum + 131072;
  float* smal = pssq + 131072;
  float* sums  = smal;
  float* ssqs  = smal + 1024;
  float* sc_bc = smal + 2048;
  float* bi_bc = smal + 3072;
  float* a2 = smal + 4096; float* b2 = a2 + kO;
  float* a3 = b2 + kO;     float* b3 = a3 + kHd;
  float* a4 = b3 + kHd;    float* b4 = a4 + kO;

  // 0. weight conversion (independent)
  wconv_kernel<<<512, 256, 0, stream>>>(v_w, pw_w, m1_w, m2_w, wv16, wpw16, wm116, wm216);
  // 1. depthwise conv + BN1 partial stats
  dwconv_kernel<<<kB * kC, 256, 0, stream>>>(x, dw_w, h0, sums, ssqs);
  // 2. BN1 finalize + SE
  se_kernel<<<kB, 128, 0, stream>>>(sums, ssqs, bn1_g, bn1_b, se_w1, se_b1, se_w2, se_b2,
                                    sc_bc, bi_bc);
  // 3. hfT32 (token-major)
  scale_tm_kernel<<<dim3(98, 4, kB), 256, 0, stream>>>(h0, sc_bc, bi_bc, hfT32);
  // 4. q,k -> fragment-tiled bf16 qA/kA
  qk_kernel<<<dim3(49, kB), 256, 0, stream>>>(hfT32, q_w, q_b, k_w, k_b, qA16, kA16);
  // 5. v -> fragment-tiled bf16 vA (MFMA)
  mfma_gemm_kernel<128, 128, 1, false, false><<<dim3(25, 1, kB), 256, 0, stream>>>(
      wv16, hfT32, nullptr, vA16, v_b, nullptr, nullptr);
  // 6. attention + residual -> attT (token-major fp32)
  attn_mfma32_kernel<<<dim3(kB, kN / 32), 256, 0, stream>>>(qA16, kA16, vA16, hfT32, attT);
  // 7. pw -> p_tm fp32 [n][256]
  mfma_gemm_kernel<256, 128, 0, false, false><<<dim3(25, 2, kB), 256, 0, stream>>>(
      wpw16, attT, p_tm, nullptr, nullptr, nullptr, nullptr);
  // 8. BN2 stats
  stats_tm_kernel<256><<<256, 256, 0, stream>>>(p_tm, psum, pssq);
  bnfin_kernel<256><<<1, 256, 0, stream>>>(psum, pssq, bn2_g, bn2_b, a2, b2);
  // 9. m1 (BN2 affine folded into staging) -> m1o fp32 [n][512]
  mfma_gemm_kernel<512, 256, 0, true, false><<<dim3(25, 4, kB), 256, 0, stream>>>(
      wm116, p_tm, m1o, nullptr, nullptr, a2, b2);
  // 10. BN3 stats
  stats_tm_kernel<512><<<256, 256, 0, stream>>>(m1o, psum, pssq);
  bnfin_kernel<512><<<2, 256, 0, stream>>>(psum, pssq, bn3_g, bn3_b, a3, b3);
  // 11. m2 (BN3 affine + exact GELU folded into staging) -> m2o fp32 [n][256]
  mfma_gemm_kernel<256, 512, 0, true, true><<<dim3(25, 2, kB), 256, 0, stream>>>(
      wm216, m1o, m2o, nullptr, nullptr, a3, b3);
  // 12. BN4 stats + apply (with transpose to ch-major output)
  stats_tm_kernel<256><<<256, 256, 0, stream>>>(m2o, psum, pssq);
  bnfin_kernel<256><<<1, 256, 0, stream>>>(psum, pssq, bn4_g, bn4_b, a4, b4);
  bnout_t_kernel<<<dim3(98, 8, kB), 256, 0, stream>>>(m2o, a4, b4, out);
}

// Round 10
// 272.762 us; speedup vs baseline: 4.4653x; 1.1581x over previous
//
#include <hip/hip_runtime.h>
#include <math.h>

namespace {

constexpr int kB = 8;
constexpr int kC = 128;
constexpr int kHin = 112, kWin = 112;
constexpr int kHout = 56, kWout = 56;
constexpr int kN = kHout * kWout;     // 3136
constexpr int kO = 256;
constexpr int kHd = 512;
constexpr int kR = 32;
constexpr float kEps = 1e-5f;

typedef __attribute__((ext_vector_type(8))) short short8v;
typedef __attribute__((ext_vector_type(4))) float f32x4;
typedef __attribute__((ext_vector_type(16))) float f32x16;
typedef __attribute__((ext_vector_type(4))) uint uint4v;

__device__ __forceinline__ ushort f2bf(float f) {
  uint u = __float_as_uint(f);
  uint r = (u + 0x7FFFu + ((u >> 16) & 1u)) >> 16;
  return (ushort)r;
}
__device__ __forceinline__ uint pack2bf(float a, float b) {
  return (uint)f2bf(a) | ((uint)f2bf(b) << 16);
}
__device__ __forceinline__ float bf2f(ushort u) {
  return __uint_as_float((uint)u << 16);
}
// tanh-form GELU (max dev from exact erf-GELU ~3e-3, well under threshold)
__device__ __forceinline__ float gelu_fast(float x) {
  float y = 0.7978845608f * (x + 0.044715f * x * x * x);
  float e = __expf(2.0f * y);
  float t = 1.0f - 2.0f / (e + 1.0f);
  return 0.5f * x * (1.0f + t);
}

// ---------------- depthwise conv 3x3 stride2 pad1 + per-(b,c) sum/sumsq ----------------
__global__ __launch_bounds__(256) void dwconv_kernel(
    const float* __restrict__ x, const float* __restrict__ w,
    float* __restrict__ h0, float* __restrict__ sums, float* __restrict__ ssqs) {
  int bc = blockIdx.x;
  int c = bc % kC;
  const float* xp = x + (size_t)bc * (kHin * kWin);
  float wr[9];
#pragma unroll
  for (int i = 0; i < 9; ++i) wr[i] = w[c * 9 + i];
  float lsum = 0.f, lssq = 0.f;
  for (int i = threadIdx.x; i < kN; i += 256) {
    int oy = i / kWout, ox = i - oy * kWout;
    int iy0 = 2 * oy - 1, ix0 = 2 * ox - 1;
    float acc = 0.f;
#pragma unroll
    for (int ky = 0; ky < 3; ++ky) {
      int iy = iy0 + ky;
      if (iy < 0 || iy >= kHin) continue;
#pragma unroll
      for (int kx = 0; kx < 3; ++kx) {
        int ix = ix0 + kx;
        if (ix < 0 || ix >= kWin) continue;
        acc += xp[iy * kWin + ix] * wr[ky * 3 + kx];
      }
    }
    h0[(size_t)bc * kN + i] = acc;
    lsum += acc;
    lssq += acc * acc;
  }
  __shared__ float rs[256], rq[256];
  rs[threadIdx.x] = lsum; rq[threadIdx.x] = lssq;
  __syncthreads();
  for (int s = 128; s > 0; s >>= 1) {
    if (threadIdx.x < s) { rs[threadIdx.x] += rs[threadIdx.x + s]; rq[threadIdx.x] += rq[threadIdx.x + s]; }
    __syncthreads();
  }
  if (threadIdx.x == 0) { sums[bc] = rs[0]; ssqs[bc] = rq[0]; }
}

// ---------------- BN1 stats + SE MLP -> per-(b,c) scale/bias ----------------
__global__ __launch_bounds__(128) void se_kernel(
    const float* __restrict__ sums, const float* __restrict__ ssqs,
    const float* __restrict__ bn1_g, const float* __restrict__ bn1_b,
    const float* __restrict__ se_w1, const float* __restrict__ se_b1,
    const float* __restrict__ se_w2, const float* __restrict__ se_b2,
    float* __restrict__ scale_bc, float* __restrict__ bias_bc) {
  int b = blockIdx.x, c = threadIdx.x;
  __shared__ float sin_[kC], s1[kR], alf[kC], bet[kC];
  float ts = 0.f, tq = 0.f;
  for (int bb = 0; bb < kB; ++bb) { ts += sums[bb * kC + c]; tq += ssqs[bb * kC + c]; }
  float inv = 1.0f / ((float)kB * (float)kN);
  float mean = ts * inv;
  float var = tq * inv - mean * mean;
  float a = bn1_g[c] * rsqrtf(var + kEps);
  float be = bn1_b[c] - mean * a;
  alf[c] = a; bet[c] = be;
  sin_[c] = a * (sums[b * kC + c] * (1.0f / kN)) + be;
  __syncthreads();
  if (c < kR) {
    float acc = se_b1[c];
    for (int j = 0; j < kC; ++j) acc += se_w1[c * kC + j] * sin_[j];
    s1[c] = fmaxf(acc, 0.f);
  }
  __syncthreads();
  float acc = se_b2[c];
  for (int j = 0; j < kR; ++j) acc += se_w2[c * kR + j] * s1[j];
  float sg = 1.0f / (1.0f + expf(-acc));
  scale_bc[b * kC + c] = alf[c] * sg;
  bias_bc[b * kC + c] = bet[c] * sg;
}

// ---------------- hfT (token-major fp32) = transpose(scale*h0+bias) ----------------
__global__ __launch_bounds__(256) void scale_tm_kernel(
    const float* __restrict__ h0, const float* __restrict__ sc,
    const float* __restrict__ bi, float* __restrict__ hfT) {
  __shared__ float T[32][33];
  int b = blockIdx.z;
  int c0 = blockIdx.y * 32;
  int n0 = blockIdx.x * 32;
  int tid = threadIdx.x;
  int r = tid >> 3, seg = tid & 7;
  int c = c0 + r;
  int bc = b * kC + c;
  float s = sc[bc], t = bi[bc];
  size_t idx = (size_t)bc * kN + n0 + seg * 4;
  float4 v = *(const float4*)&h0[idx];
  v.x = s * v.x + t; v.y = s * v.y + t; v.z = s * v.z + t; v.w = s * v.w + t;
  T[seg * 4 + 0][r] = v.x; T[seg * 4 + 1][r] = v.y;
  T[seg * 4 + 2][r] = v.z; T[seg * 4 + 3][r] = v.w;
  __syncthreads();
  float4 o = make_float4(T[r][seg * 4], T[r][seg * 4 + 1], T[r][seg * 4 + 2], T[r][seg * 4 + 3]);
  *(float4*)&hfT[((size_t)b * kN + n0 + r) * kC + c0 + seg * 4] = o;
}

// ---------------- weights fp32 -> bf16 (v, pw, m2; m1 is runtime-folded) ----------------
__global__ void wconv_kernel(const float* __restrict__ vw, const float* __restrict__ pww,
                             const float* __restrict__ m2w,
                             ushort* __restrict__ ov, ushort* __restrict__ opw,
                             ushort* __restrict__ om2) {
  int stride = gridDim.x * 256;
  int i0 = blockIdx.x * 256 + threadIdx.x;
  for (int i = i0; i < 128 * 128; i += stride) ov[i] = f2bf(vw[i]);
  for (int i = i0; i < 256 * 128; i += stride) opw[i] = f2bf(pww[i]);
  for (int i = i0; i < 256 * 512; i += stride) om2[i] = f2bf(m2w[i]);
}

// ---------------- fold BN2 affine into m1 weight: W' = W*diag(a2), bias1 = W*b2 ----------------
__global__ __launch_bounds__(256) void foldm1_kernel(
    const float* __restrict__ m1w, const float* __restrict__ a2,
    const float* __restrict__ b2, ushort* __restrict__ wf, float* __restrict__ bias1) {
  int r = blockIdx.x;            // 512 rows
  int c = threadIdx.x;           // 256 cols
  float w = m1w[r * 256 + c];
  wf[r * 256 + c] = f2bf(w * a2[c]);
  __shared__ float red[256];
  red[c] = w * b2[c];
  __syncthreads();
  for (int s = 128; s > 0; s >>= 1) {
    if (c < s) red[c] += red[c + s];
    __syncthreads();
  }
  if (c == 0) bias1[r] = red[0];
}

// ---------------- q,k projection -> MFMA-fragment-tiled bf16 qA/kA [t][hi][32][8] ----------------
__global__ __launch_bounds__(256) void qk_kernel(
    const float* __restrict__ hfT, const float* __restrict__ q_w,
    const float* __restrict__ q_b, const float* __restrict__ k_w,
    const float* __restrict__ k_b, ushort* __restrict__ qA, ushort* __restrict__ kA) {
  __shared__ float Wl[32][128];
  __shared__ float Xl[64][129];
  int b = blockIdx.y;
  int n0 = blockIdx.x * 64;
  int tid = threadIdx.x;
  for (int u = tid; u < 1024; u += 256) {
    int r = u >> 5, seg = u & 31;
    const float* src = (r < 16) ? &q_w[r * 128 + seg * 4] : &k_w[(r - 16) * 128 + seg * 4];
    float4 v = *(const float4*)src;
    *(float4*)&Wl[r][seg * 4] = v;
  }
  const float* Xb = hfT + ((size_t)b * kN + n0) * kC;
  for (int u = tid; u < 2048; u += 256) {
    int r = u >> 5, seg = u & 31;
    float4 v = *(const float4*)&Xb[(size_t)r * kC + seg * 4];
    Xl[r][seg * 4 + 0] = v.x; Xl[r][seg * 4 + 1] = v.y;
    Xl[r][seg * 4 + 2] = v.z; Xl[r][seg * 4 + 3] = v.w;
  }
  __syncthreads();
  int tt = tid & 63, og = tid >> 6;
  float acc[8] = {};
  for (int k = 0; k < 128; ++k) {
    float xx = Xl[tt][k];
#pragma unroll
    for (int j = 0; j < 8; ++j) acc[j] += xx * Wl[og * 8 + j][k];
  }
  uint pk[4];
#pragma unroll
  for (int j2 = 0; j2 < 4; ++j2) {
    int m = og * 8 + j2 * 2;
    float b0 = (m < 16) ? q_b[m] : k_b[m - 16];
    float b1 = (m + 1 < 16) ? q_b[m + 1] : k_b[m + 1 - 16];
    pk[j2] = pack2bf(acc[j2 * 2] + b0, acc[j2 * 2 + 1] + b1);
  }
  int n = n0 + tt;
  int t = n >> 5, r = n & 31, h = og & 1;
  ushort* dst = (og < 2 ? qA : kA) + (size_t)b * kN * 16 + (((size_t)t * 2 + h) * 32 + r) * 8;
  *(uint4*)dst = make_uint4(pk[0], pk[1], pk[2], pk[3]);
}

// ---------------- MFMA GEMM: Y = W(bf16) . X(token-major) ----------------
// INMODE 0: X fp32 [n][K].  INMODE 1: X bf16 [n][K] (zero-transform staging).
// OUTMODE 1 (V only): fragment-tiled bf16 vA[t][chunk][128][8], key bits2/3 swapped.
// OUTMODE 2: bf16 token-major [n][M] (+ optional fp32 row-bias).
template <int M, int K, int INMODE, int OUTMODE>
__global__ __launch_bounds__(256) void mfma_gemm_kernel(
    const ushort* __restrict__ Wb, const float* __restrict__ Xf,
    const ushort* __restrict__ Xh, ushort* __restrict__ Yh,
    const float* __restrict__ bias) {
  constexpr int BM = 128, BN = 128, BK = 64, LDW = 72;
  __shared__ ushort Wl[BM * LDW];
  __shared__ ushort Xl[BN * LDW];
  int b = blockIdx.z;
  int n0 = blockIdx.x * BN;
  int m0 = blockIdx.y * BM;
  int tid = threadIdx.x;
  int w = tid >> 6, lane = tid & 63;
  int wm = w >> 1, wn = w & 1;
  int lg = lane >> 4, lq = lane & 15;
  f32x4 acc[4][4];
#pragma unroll
  for (int i = 0; i < 4; ++i)
#pragma unroll
    for (int j = 0; j < 4; ++j) acc[i][j] = (f32x4){0.f, 0.f, 0.f, 0.f};

  int wseg = tid & 7;
  int xseg = tid & 15;

  for (int kk = 0; kk < K; kk += BK) {
    __syncthreads();
#pragma unroll
    for (int u = 0; u < 4; ++u) {
      int row = (tid + u * 256) >> 3;
      short8v wv = *(const short8v*)&Wb[(size_t)(m0 + row) * K + kk + wseg * 8];
      *(short8v*)&Wl[row * LDW + wseg * 8] = wv;
    }
    if (INMODE == 0) {
      const float* Xb = Xf + (size_t)b * kN * K;
#pragma unroll
      for (int u = 0; u < 8; ++u) {
        int row = (tid + u * 256) >> 4;
        int n = n0 + row;
        float4 xv = make_float4(0.f, 0.f, 0.f, 0.f);
        if (n < kN) xv = *(const float4*)&Xb[(size_t)n * K + kk + xseg * 4];
        *(uint2*)&Xl[row * LDW + xseg * 4] =
            make_uint2(pack2bf(xv.x, xv.y), pack2bf(xv.z, xv.w));
      }
    } else {
      const ushort* Xb = Xh + (size_t)b * kN * K;
#pragma unroll
      for (int u = 0; u < 4; ++u) {
        int idx = tid + u * 256;
        int row = idx >> 3, seg = idx & 7;
        int n = n0 + row;
        short8v xv = (short8v){0, 0, 0, 0, 0, 0, 0, 0};
        if (n < kN) xv = *(const short8v*)&Xb[(size_t)n * K + kk + seg * 8];
        *(short8v*)&Xl[row * LDW + seg * 8] = xv;
      }
    }
    __syncthreads();
#pragma unroll
    for (int kh = 0; kh < BK; kh += 32) {
      short8v af[4], bfr[4];
#pragma unroll
      for (int f = 0; f < 4; ++f) {
        af[f] = *(const short8v*)&Wl[(wm * 64 + f * 16 + lq) * LDW + kh + 8 * lg];
        bfr[f] = *(const short8v*)&Xl[(wn * 64 + f * 16 + lq) * LDW + kh + 8 * lg];
      }
#pragma unroll
      for (int fi = 0; fi < 4; ++fi)
#pragma unroll
        for (int fj = 0; fj < 4; ++fj)
          acc[fi][fj] = __builtin_amdgcn_mfma_f32_16x16x32_bf16(af[fi], bfr[fj], acc[fi][fj], 0, 0, 0);
    }
  }
  if (OUTMODE == 1) {
    ushort* Yb = Yh + (size_t)b * M * kN;   // vA [98][4][128][8]
#pragma unroll
    for (int fi = 0; fi < 4; ++fi) {
#pragma unroll
      for (int r = 0; r < 4; ++r) {
        int m = m0 + wm * 64 + fi * 16 + 4 * lg + r;
        float bv = bias ? bias[m] : 0.f;
#pragma unroll
        for (int fj = 0; fj < 4; ++fj) {
          int n = n0 + wn * 64 + fj * 16 + lq;
          if (n < kN) {
            int t = n >> 5, nl = n & 31;
            int pp = (nl & ~12) | ((nl & 4) << 1) | ((nl & 8) >> 1);  // swap bits 2,3
            Yb[(((size_t)t * 4 + (pp >> 3)) * 128 + m) * 8 + (pp & 7)] =
                f2bf(acc[fi][fj][r] + bv);
          }
        }
      }
    }
  } else {
    ushort* Yb = Yh + (size_t)b * kN * M;
#pragma unroll
    for (int fj = 0; fj < 4; ++fj) {
      int n = n0 + wn * 64 + fj * 16 + lq;
      if (n < kN) {
#pragma unroll
        for (int fi = 0; fi < 4; ++fi) {
          int mb = m0 + wm * 64 + fi * 16 + 4 * lg;
          f32x4 v = acc[fi][fj];
          if (bias) {
            v[0] += bias[mb]; v[1] += bias[mb + 1];
            v[2] += bias[mb + 2]; v[3] += bias[mb + 3];
          }
          *(uint2*)&Yb[(size_t)n * M + mb] =
              make_uint2(pack2bf(v[0], v[1]), pack2bf(v[2], v[3]));
        }
      }
    }
  }
}

// ---------------- 32x32x16 MFMA flash attention, barrier-free k-loop ----------------
__global__ __launch_bounds__(256) void attn_mfma32_kernel(
    const ushort* __restrict__ qA, const ushort* __restrict__ kA,
    const ushort* __restrict__ vA, const float* __restrict__ hfT,
    ushort* __restrict__ attT) {
  int b = blockIdx.x;                   // bid%8 = b -> one batch per XCD
  int n0 = blockIdx.y * 32;
  int tid = threadIdx.x;
  int w = tid >> 6;
  int lane = tid & 63;
  int l31 = lane & 31;
  int hi = lane >> 5;

  __shared__ float mbuf[4][32], lbuf[4][32], lfin[32];
  __shared__ float obuf[32][132];       // [q][c], padded

  const ushort* qAb = qA + (size_t)b * kN * 16;
  const ushort* kAb = kA + (size_t)b * kN * 16;
  const ushort* vAb = vA + (size_t)b * kN * 128;

  short8v qf = *(const short8v*)&qAb[(((size_t)blockIdx.y * 2 + hi) * 32 + l31) * 8];

  f32x16 z16 = {0.f,0.f,0.f,0.f,0.f,0.f,0.f,0.f,0.f,0.f,0.f,0.f,0.f,0.f,0.f,0.f};
  f32x16 acc[4];
#pragma unroll
  for (int cg = 0; cg < 4; ++cg) acc[cg] = z16;

  float m = -1e30f, l = 0.f;

  short8v kf_cur = *(const short8v*)&kAb[(((size_t)w * 2 + hi) * 32 + l31) * 8];

  for (int t = w; t < 98; t += 4) {
    const ushort* vt = vAb + (size_t)t * 4 * 128 * 8;
    short8v va[4], vb2[4];
#pragma unroll
    for (int cg = 0; cg < 4; ++cg) {
      va[cg]  = *(const short8v*)&vt[((size_t)hi * 128 + cg * 32 + l31) * 8];
      vb2[cg] = *(const short8v*)&vt[(((size_t)(2 + hi)) * 128 + cg * 32 + l31) * 8];
    }
    int tn = t + 4;
    short8v kf_nxt = kf_cur;
    if (tn < 98)
      kf_nxt = *(const short8v*)&kAb[(((size_t)tn * 2 + hi) * 32 + l31) * 8];

    f32x16 s = __builtin_amdgcn_mfma_f32_32x32x16_bf16(kf_cur, qf, z16, 0, 0, 0);

    float tmax = s[0];
#pragma unroll
    for (int i = 1; i < 16; ++i) tmax = fmaxf(tmax, s[i]);
    tmax = fmaxf(tmax, __shfl_xor(tmax, 32, 64));

    if (!__all(tmax <= m + 8.0f)) {       // T13 defer-max
      float mnew = fmaxf(m, tmax);
      float scl = __expf(m - mnew);
      l *= scl;
#pragma unroll
      for (int cg = 0; cg < 4; ++cg)
#pragma unroll
        for (int i = 0; i < 16; ++i) acc[cg][i] *= scl;
      m = mnew;
    }
    uint wd[8];
    float ps = 0.f;
#pragma unroll
    for (int i = 0; i < 8; ++i) {
      float pl = __expf(s[2 * i] - m);
      float ph = __expf(s[2 * i + 1] - m);
      ps += pl + ph;
      asm("v_cvt_pk_bf16_f32 %0, %1, %2" : "=v"(wd[i]) : "v"(pl), "v"(ph));
    }
    ps += __shfl_xor(ps, 32, 64);
    l += ps;

    uint4v u1 = {wd[0], wd[1], wd[2], wd[3]};
    uint4v u2 = {wd[4], wd[5], wd[6], wd[7]};
    short8v P1 = __builtin_bit_cast(short8v, u1);
    short8v P2 = __builtin_bit_cast(short8v, u2);
#pragma unroll
    for (int cg = 0; cg < 4; ++cg) {
      acc[cg] = __builtin_amdgcn_mfma_f32_32x32x16_bf16(va[cg], P1, acc[cg], 0, 0, 0);
      acc[cg] = __builtin_amdgcn_mfma_f32_32x32x16_bf16(vb2[cg], P2, acc[cg], 0, 0, 0);
    }
    kf_cur = kf_nxt;
  }

  // ---- 4-way flash merge ----
  if (lane < 32) { mbuf[w][lane] = m; lbuf[w][lane] = l; }
  __syncthreads();
  float M = -1e30f;
#pragma unroll
  for (int j = 0; j < 4; ++j) M = fmaxf(M, mbuf[j][l31]);
  float L = 0.f;
#pragma unroll
  for (int j = 0; j < 4; ++j) L += lbuf[j][l31] * __expf(mbuf[j][l31] - M);
  if (w == 0 && lane < 32) lfin[lane] = L;
  float f = __expf(m - M);

  for (int turn = 0; turn < 4; ++turn) {
    if (w == turn) {
#pragma unroll
      for (int cg = 0; cg < 4; ++cg)
#pragma unroll
        for (int rr = 0; rr < 4; ++rr) {
          int c = cg * 32 + 8 * rr + 4 * hi;
          float4 vv;
          vv.x = f * acc[cg][4 * rr + 0];
          vv.y = f * acc[cg][4 * rr + 1];
          vv.z = f * acc[cg][4 * rr + 2];
          vv.w = f * acc[cg][4 * rr + 3];
          if (turn == 0) {
            *(float4*)&obuf[l31][c] = vv;
          } else {
            float4 o = *(const float4*)&obuf[l31][c];
            o.x += vv.x; o.y += vv.y; o.z += vv.z; o.w += vv.w;
            *(float4*)&obuf[l31][c] = o;
          }
        }
    }
    __syncthreads();
  }

  // epilogue: O/L + residual (hfT fp32) -> attT bf16 [n][128]
  int q = tid >> 3;
  int cs = (tid & 7) * 16;
  float linv = 1.0f / lfin[q];
  size_t nidx = (size_t)b * kN + n0 + q;
  const float* hrow = &hfT[nidx * kC + cs];
  ushort* arow = &attT[nidx * kC + cs];
#pragma unroll
  for (int cc = 0; cc < 16; cc += 4) {
    float4 r = *(const float4*)&hrow[cc];
    float o0 = obuf[q][cs + cc + 0] * linv + r.x;
    float o1 = obuf[q][cs + cc + 1] * linv + r.y;
    float o2 = obuf[q][cs + cc + 2] * linv + r.z;
    float o3 = obuf[q][cs + cc + 3] * linv + r.w;
    *(uint2*)&arow[cc] = make_uint2(pack2bf(o0, o1), pack2bf(o2, o3));
  }
}

// ---------------- bf16 token-major BN stats: partials then finalize ----------------
template <int CH>
__global__ __launch_bounds__(256) void stats_bf_kernel(
    const ushort* __restrict__ X, float* __restrict__ psum, float* __restrict__ pssq) {
  constexpr int RPB = (kB * kN) / 256;  // 98
  int r0 = blockIdx.x * RPB;
  float s[CH / 256] = {}, q[CH / 256] = {};
  for (int r = r0; r < r0 + RPB; ++r) {
    const ushort* row = X + (size_t)r * CH;
#pragma unroll
    for (int cc = 0; cc < CH / 256; ++cc) {
      float v = bf2f(row[threadIdx.x + cc * 256]);
      s[cc] += v; q[cc] += v * v;
    }
  }
#pragma unroll
  for (int cc = 0; cc < CH / 256; ++cc) {
    psum[(size_t)blockIdx.x * CH + threadIdx.x + cc * 256] = s[cc];
    pssq[(size_t)blockIdx.x * CH + threadIdx.x + cc * 256] = q[cc];
  }
}

template <int CH>
__global__ __launch_bounds__(256) void bnfin_kernel(
    const float* __restrict__ psum, const float* __restrict__ pssq,
    const float* __restrict__ g, const float* __restrict__ bt,
    float* __restrict__ alpha, float* __restrict__ beta) {
  int ch = blockIdx.x * 256 + threadIdx.x;
  if (ch >= CH) return;
  float s = 0.f, q = 0.f;
  for (int p = 0; p < 256; ++p) { s += psum[(size_t)p * CH + ch]; q += pssq[(size_t)p * CH + ch]; }
  float inv = 1.0f / ((float)kB * (float)kN);
  float mean = s * inv;
  float var = q * inv - mean * mean;
  float a = g[ch] * rsqrtf(var + kEps);
  alpha[ch] = a;
  beta[ch] = bt[ch] - mean * a;
}

// ---------------- BN3 affine + fast GELU: m1o bf16 -> g bf16 ----------------
__global__ __launch_bounds__(256) void gelupass_kernel(
    const ushort* __restrict__ m1o, const float* __restrict__ a3,
    const float* __restrict__ b3, ushort* __restrict__ g) {
  size_t total8 = (size_t)kB * kN * kHd / 8;
  for (size_t i = (size_t)blockIdx.x * 256 + threadIdx.x; i < total8;
       i += (size_t)gridDim.x * 256) {
    int c8 = (int)(i & 63) * 8;
    short8v x = ((const short8v*)m1o)[i];
    float4 a0 = *(const float4*)&a3[c8];
    float4 a1 = *(const float4*)&a3[c8 + 4];
    float4 b0 = *(const float4*)&b3[c8];
    float4 b1 = *(const float4*)&b3[c8 + 4];
    float y0 = gelu_fast(a0.x * bf2f((ushort)x[0]) + b0.x);
    float y1 = gelu_fast(a0.y * bf2f((ushort)x[1]) + b0.y);
    float y2 = gelu_fast(a0.z * bf2f((ushort)x[2]) + b0.z);
    float y3 = gelu_fast(a0.w * bf2f((ushort)x[3]) + b0.w);
    float y4 = gelu_fast(a1.x * bf2f((ushort)x[4]) + b1.x);
    float y5 = gelu_fast(a1.y * bf2f((ushort)x[5]) + b1.y);
    float y6 = gelu_fast(a1.z * bf2f((ushort)x[6]) + b1.z);
    float y7 = gelu_fast(a1.w * bf2f((ushort)x[7]) + b1.w);
    uint4v o = {pack2bf(y0, y1), pack2bf(y2, y3), pack2bf(y4, y5), pack2bf(y6, y7)};
    ((uint4v*)g)[i] = o;
  }
}

// ---------------- final BN apply + transpose bf16 [n][256] -> out fp32 [b][256][n] ----------------
__global__ __launch_bounds__(256) void bnout_t_kernel(
    const ushort* __restrict__ X, const float* __restrict__ alpha,
    const float* __restrict__ beta, float* __restrict__ out) {
  __shared__ float T[32][33];
  int b = blockIdx.z;
  int c0 = blockIdx.y * 32;
  int n0 = blockIdx.x * 32;
  int tid = threadIdx.x;
  int r = tid >> 3, seg = tid & 7;
  uint2 u = *(const uint2*)&X[((size_t)b * kN + n0 + r) * kO + c0 + seg * 4];
  float x0 = __uint_as_float(u.x << 16);
  float x1 = __uint_as_float(u.x & 0xFFFF0000u);
  float x2 = __uint_as_float(u.y << 16);
  float x3 = __uint_as_float(u.y & 0xFFFF0000u);
  float4 a = *(const float4*)&alpha[c0 + seg * 4];
  float4 bb = *(const float4*)&beta[c0 + seg * 4];
  T[seg * 4 + 0][r] = a.x * x0 + bb.x;
  T[seg * 4 + 1][r] = a.y * x1 + bb.y;
  T[seg * 4 + 2][r] = a.z * x2 + bb.z;
  T[seg * 4 + 3][r] = a.w * x3 + bb.w;
  __syncthreads();
  float4 o = make_float4(T[r][seg * 4], T[r][seg * 4 + 1], T[r][seg * 4 + 2], T[r][seg * 4 + 3]);
  *(float4*)&out[((size_t)b * kO + c0 + r) * kN + n0 + seg * 4] = o;
}

}  // namespace

extern "C" void kernel_launch(void* const* d_in, const int* in_sizes, int n_in,
                              void* d_out, int out_size, void* d_ws, size_t ws_size,
                              hipStream_t stream) {
  const float* x     = (const float*)d_in[0];
  const float* dw_w  = (const float*)d_in[1];
  const float* bn1_g = (const float*)d_in[2];
  const float* bn1_b = (const float*)d_in[3];
  const float* se_w1 = (const float*)d_in[4];
  const float* se_b1 = (const float*)d_in[5];
  const float* se_w2 = (const float*)d_in[6];
  const float* se_b2 = (const float*)d_in[7];
  const float* q_w   = (const float*)d_in[8];
  const float* q_b   = (const float*)d_in[9];
  const float* k_w   = (const float*)d_in[10];
  const float* k_b   = (const float*)d_in[11];
  const float* v_w   = (const float*)d_in[12];
  const float* v_b   = (const float*)d_in[13];
  const float* pw_w  = (const float*)d_in[14];
  const float* bn2_g = (const float*)d_in[15];
  const float* bn2_b = (const float*)d_in[16];
  const float* m1_w  = (const float*)d_in[17];
  const float* bn3_g = (const float*)d_in[18];
  const float* bn3_b = (const float*)d_in[19];
  const float* m2_w  = (const float*)d_in[20];
  const float* bn4_g = (const float*)d_in[21];
  const float* bn4_b = (const float*)d_in[22];
  float* out = (float*)d_out;
  float* ws = (float*)d_ws;

  const size_t BCN = (size_t)kB * kC * kN;   // 3,211,264 floats (12.8 MB)
  const size_t E8 = BCN / 8;                 // 401,408 floats

  // ---- disjoint-in-time layout (float offsets; sizes in float units) ----
  // h0     [0, BCN)              fp32, live steps 1-3
  // hfT32  [BCN, 2BCN)           fp32, live steps 3-6
  // vA16   [2BCN, 2.5BCN)        bf16 kB*kN*128, live 5-6
  // qA16   [2.5BCN, +E8/2)       bf16 kB*kN*16,  live 4-6
  // kA16   [.., 2.625BCN)        bf16 kB*kN*16,  live 4-6
  // attT16 [2.625BCN, 3.125BCN)  bf16 kB*kN*128, live 6-7
  // p16    [3.125BCN, 4.125BCN)  bf16 kB*kN*256, live 7-9
  // m1o16  [4.125BCN, 6.125BCN)  bf16 kB*kN*512, live 9-11
  // g16    [0, 2BCN)             bf16 kB*kN*512, live 11-12 (h0,hfT dead)
  // m2o16  [2BCN, 3BCN)          bf16 kB*kN*256, live 12-13 (vA,qA,kA,attT dead)
  // weights/psum at [6.125BCN, ...)
  float* h0    = ws;
  float* hfT32 = ws + BCN;
  ushort* vA16   = (ushort*)(ws + 2 * BCN);
  ushort* qA16   = (ushort*)(ws + 2 * BCN + BCN / 2);
  ushort* kA16   = qA16 + (size_t)kB * kN * 16;
  ushort* attT16 = (ushort*)(ws + 2 * BCN + 5 * (BCN / 8));
  ushort* p16    = (ushort*)(ws + 3 * BCN + E8);
  ushort* m1o16  = (ushort*)(ws + 4 * BCN + E8);
  ushort* g16    = (ushort*)ws;
  ushort* m2o16  = (ushort*)(ws + 2 * BCN);
  float* wbase = ws + 6 * BCN + E8;
  ushort* wv16  = (ushort*)wbase;                       // 16384
  ushort* wpw16 = wv16 + 128 * 128;                     // 32768
  ushort* wm216 = wpw16 + 256 * 128;                    // 131072
  ushort* wm1f  = wm216 + 256 * 512;                    // 131072 (runtime-folded)
  float* psum  = wbase + 155648;                        // 256*512
  float* pssq  = psum + 131072;
  float* bias1 = pssq + 131072;                         // 512
  float* smal  = bias1 + 512;
  float* sums  = smal;
  float* ssqs  = smal + 1024;
  float* sc_bc = smal + 2048;
  float* bi_bc = smal + 3072;
  float* a2 = smal + 4096; float* b2 = a2 + kO;
  float* a3 = b2 + kO;     float* b3 = a3 + kHd;
  float* a4 = b3 + kHd;    float* b4 = a4 + kO;

  // 0. weight conversion (independent)
  wconv_kernel<<<512, 256, 0, stream>>>(v_w, pw_w, m2_w, wv16, wpw16, wm216);
  // 1. depthwise conv + BN1 partial stats
  dwconv_kernel<<<kB * kC, 256, 0, stream>>>(x, dw_w, h0, sums, ssqs);
  // 2. BN1 finalize + SE
  se_kernel<<<kB, 128, 0, stream>>>(sums, ssqs, bn1_g, bn1_b, se_w1, se_b1, se_w2, se_b2,
                                    sc_bc, bi_bc);
  // 3. hfT32 (token-major)
  scale_tm_kernel<<<dim3(98, 4, kB), 256, 0, stream>>>(h0, sc_bc, bi_bc, hfT32);
  // 4. q,k -> fragment-tiled bf16 qA/kA
  qk_kernel<<<dim3(49, kB), 256, 0, stream>>>(hfT32, q_w, q_b, k_w, k_b, qA16, kA16);
  // 5. v -> fragment-tiled bf16 vA (fp32 input)
  mfma_gemm_kernel<128, 128, 0, 1><<<dim3(25, 1, kB), 256, 0, stream>>>(
      wv16, hfT32, nullptr, vA16, v_b);
  // 6. attention + residual -> attT bf16 [n][128]
  attn_mfma32_kernel<<<dim3(kB, kN / 32), 256, 0, stream>>>(qA16, kA16, vA16, hfT32, attT16);
  // 7. pw -> p bf16 [n][256]
  mfma_gemm_kernel<256, 128, 1, 2><<<dim3(25, 2, kB), 256, 0, stream>>>(
      wpw16, nullptr, attT16, p16, nullptr);
  // 8. BN2 stats + fold into m1 weights
  stats_bf_kernel<256><<<256, 256, 0, stream>>>(p16, psum, pssq);
  bnfin_kernel<256><<<1, 256, 0, stream>>>(psum, pssq, bn2_g, bn2_b, a2, b2);
  foldm1_kernel<<<512, 256, 0, stream>>>(m1_w, a2, b2, wm1f, bias1);
  // 9. m1 (affine pre-folded) -> m1o bf16 [n][512]
  mfma_gemm_kernel<512, 256, 1, 2><<<dim3(25, 4, kB), 256, 0, stream>>>(
      wm1f, nullptr, p16, m1o16, bias1);
  // 10. BN3 stats
  stats_bf_kernel<512><<<256, 256, 0, stream>>>(m1o16, psum, pssq);
  bnfin_kernel<512><<<2, 256, 0, stream>>>(psum, pssq, bn3_g, bn3_b, a3, b3);
  // 11. BN3 affine + fast GELU -> g bf16
  gelupass_kernel<<<2048, 256, 0, stream>>>(m1o16, a3, b3, g16);
  // 12. m2 -> m2o bf16 [n][256]
  mfma_gemm_kernel<256, 512, 1, 2><<<dim3(25, 2, kB), 256, 0, stream>>>(
      wm216, nullptr, g16, m2o16, nullptr);
  // 13. BN4 stats + apply (transpose to ch-major fp32 out)
  stats_bf_kernel<256><<<256, 256, 0, stream>>>(m2o16, psum, pssq);
  bnfin_kernel<256><<<1, 256, 0, stream>>>(psum, pssq, bn4_g, bn4_b, a4, b4);
  bnout_t_kernel<<<dim3(98, 8, kB), 256, 0, stream>>>(m2o16, a4, b4, out);
}